// Round 10
// baseline (2609.299 us; speedup 1.0000x reference)
//
#include <hip/hip_runtime.h>
#include <hip/hip_bf16.h>

// Problem constants
#define S_LEN  1024
#define B_SZ   32
#define IN_DIM 3072
#define HID    256
#define NHEAD  16
#define HDIM   16
#define DFF    1024
#define NLAYER 4
#define NCLS   1623
#define EMB_D  10
#define MROWS  (S_LEN * B_SZ)   // 32768
#define QSTRIDE 52               // per-step qkvb stride in GLOBAL (16B aligned)
#define CH7    8                 // scan steps staged per LDS chunk (scan7)
#define RSTRIDE 56               // padded LDS row stride (floats) -> 7x64 slots, disjoint banks
#define WBUF   (4 * CH7 * RSTRIDE)  // floats per wave per buffer = 1792

using bf16   = __hip_bfloat16;
using short8 = __attribute__((ext_vector_type(8))) short;
using f32x4  = __attribute__((ext_vector_type(4))) float;

#define GLOAD16(g, l) __builtin_amdgcn_global_load_lds(                        \
    (const __attribute__((address_space(1))) void*)(g),                        \
    (__attribute__((address_space(3))) void*)(l), 16, 0, 0)

// ---------------------------------------------------------------------------
// bf16 MFMA GEMM: C[M,N] = A[M,K]@W[N,K]^T.  BM=BN=128, BK=32, 256 thr/4 waves,
// each wave a 64x64 quadrant (4x4 frags of 16x16x32). K multiple of 32.
// W buffers padded to 128-multiple rows. FLAGS: 1 bias, 2 relu, 4 residual(fp32),
// 8 bf16-out, 16 permuted qkvb store (fp32, (b,h,s,52) layout).
// ---------------------------------------------------------------------------
template<int FLAGS>
__global__ __launch_bounds__(256) void mgemm(
    const bf16* __restrict__ A, const bf16* __restrict__ W,
    const float* __restrict__ bias, const float* R, void* C,
    int N, int K, int Wld)
{
    __shared__ bf16 sA[2][128 * 32];
    __shared__ bf16 sB[2][128 * 32];
    const int t    = threadIdx.x;
    const int lane = t & 63;
    const int wid  = t >> 6;
    const int wr   = wid >> 1, wc = wid & 1;
    const long bm  = (long)blockIdx.x * 128;
    const int  bn  = blockIdx.y * 128;
    const int  fr  = lane & 15;        // frag row/col
    const int  fg  = lane >> 4;        // k-group
    const int  row0 = t >> 2;          // staging row (0..63), +64 for 2nd issue
    const int  kq0  = (t & 3) << 3;    // staging k offset (elems)

    f32x4 acc[4][4];
#pragma unroll
    for (int m = 0; m < 4; ++m)
#pragma unroll
        for (int n = 0; n < 4; ++n)
#pragma unroll
            for (int r = 0; r < 4; ++r) acc[m][n][r] = 0.f;

    const int nkt = K >> 5;

    auto stage = [&](int buf, int kt) {
        const int k0 = kt << 5;
        GLOAD16(A + (bm + row0)      * (long)K   + k0 + kq0, &sA[buf][(t      ) * 8]);
        GLOAD16(A + (bm + row0 + 64) * (long)K   + k0 + kq0, &sA[buf][(t + 256) * 8]);
        GLOAD16(W + (long)(bn + row0)      * Wld + k0 + kq0, &sB[buf][(t      ) * 8]);
        GLOAD16(W + (long)(bn + row0 + 64) * Wld + k0 + kq0, &sB[buf][(t + 256) * 8]);
    };

    stage(0, 0);
    __syncthreads();
    for (int kt = 0; kt < nkt; ++kt) {
        const int cur = kt & 1;
        if (kt + 1 < nkt) stage(cur ^ 1, kt + 1);
        short8 af[4], bg[4];
#pragma unroll
        for (int m = 0; m < 4; ++m)
            af[m] = *(const short8*)&sA[cur][(wr * 64 + m * 16 + fr) * 32 + fg * 8];
#pragma unroll
        for (int n = 0; n < 4; ++n)
            bg[n] = *(const short8*)&sB[cur][(wc * 64 + n * 16 + fr) * 32 + fg * 8];
#pragma unroll
        for (int m = 0; m < 4; ++m)
#pragma unroll
            for (int n = 0; n < 4; ++n)
                acc[m][n] = __builtin_amdgcn_mfma_f32_16x16x32_bf16(
                    af[m], bg[n], acc[m][n], 0, 0, 0);
        __syncthreads();
    }

    // Epilogue. C/D layout (HW-verified): col = lane&15, row = (lane>>4)*4+reg.
    float bs[4];
#pragma unroll
    for (int n = 0; n < 4; ++n) {
        const int c = bn + wc * 64 + n * 16 + fr;
        bs[n] = ((FLAGS & 1) && c < N) ? bias[c] : 0.f;
    }
#pragma unroll
    for (int m = 0; m < 4; ++m) {
#pragma unroll
        for (int n = 0; n < 4; ++n) {
            const int c = bn + wc * 64 + n * 16 + fr;
            if (c < N) {
#pragma unroll
                for (int r = 0; r < 4; ++r) {
                    const long rw = bm + wr * 64 + m * 16 + fg * 4 + r;
                    float v = acc[m][n][r] + bs[n];
                    if (FLAGS & 2) v = fmaxf(v, 0.f);
                    if (FLAGS & 4) v += R[rw * N + c];
                    if (FLAGS & 16) {
                        const int s = (int)(rw >> 5), b = (int)(rw & 31);
                        const int hh = c / 49, cc = c - hh * 49;
                        ((float*)C)[((long)(b * 16 + hh) * 1024 + s) * QSTRIDE + cc] = v;
                    } else if (FLAGS & 8) {
                        ((bf16*)C)[rw * N + c] = __float2bfloat16(v);
                    } else {
                        ((float*)C)[rw * N + c] = v;
                    }
                }
            }
        }
    }
}

// ---------------------------------------------------------------------------
// fp32 -> bf16 bulk convert, count divisible by 8.
// ---------------------------------------------------------------------------
__global__ __launch_bounds__(256) void cvt8(const float* __restrict__ s,
                                            bf16* __restrict__ d, long n8)
{
    for (long i = (long)blockIdx.x * 256 + threadIdx.x; i < n8;
         i += (long)gridDim.x * 256) {
        const float4 a = ((const float4*)s)[i * 2];
        const float4 b = ((const float4*)s)[i * 2 + 1];
        alignas(16) bf16 t[8];
        t[0] = __float2bfloat16(a.x); t[1] = __float2bfloat16(a.y);
        t[2] = __float2bfloat16(a.z); t[3] = __float2bfloat16(a.w);
        t[4] = __float2bfloat16(b.x); t[5] = __float2bfloat16(b.y);
        t[6] = __float2bfloat16(b.z); t[7] = __float2bfloat16(b.w);
        ((short8*)d)[i] = *(const short8*)t;
    }
}

// ---------------------------------------------------------------------------
// fp32 [rows][cols] -> bf16 [prows][pcols], zero-padded.
// ---------------------------------------------------------------------------
__global__ __launch_bounds__(256) void cvtpad(const float* __restrict__ s,
                                              bf16* __restrict__ d,
                                              int rows, int cols, int prows, int pcols)
{
    const long tot = (long)prows * pcols;
    for (long i = (long)blockIdx.x * 256 + threadIdx.x; i < tot;
         i += (long)gridDim.x * 256) {
        const int r = (int)(i / pcols), c = (int)(i - (long)r * pcols);
        d[i] = (r < rows && c < cols) ? __float2bfloat16(s[(long)r * cols + c])
                                      : __float2bfloat16(0.f);
    }
}

// ---------------------------------------------------------------------------
// LayerNorm(256) -> bf16. One wave per row, 4 rows/block.
// ---------------------------------------------------------------------------
__global__ __launch_bounds__(256) void ln_b(
    const float* __restrict__ x, const float* __restrict__ g,
    const float* __restrict__ b, bf16* __restrict__ y)
{
    const int wave = threadIdx.x >> 6, lane = threadIdx.x & 63;
    const long row = (long)(blockIdx.x << 2) + wave;
    const float4 v = ((const float4*)(x + row * HID))[lane];
    float s = v.x + v.y + v.z + v.w;
#pragma unroll
    for (int m = 32; m; m >>= 1) s += __shfl_xor(s, m);
    const float mean = s * (1.f / 256.f);
    const float d0 = v.x - mean, d1 = v.y - mean, d2 = v.z - mean, d3 = v.w - mean;
    float ss = d0 * d0 + d1 * d1 + d2 * d2 + d3 * d3;
#pragma unroll
    for (int m = 32; m; m >>= 1) ss += __shfl_xor(ss, m);
    const float inv = rsqrtf(ss * (1.f / 256.f) + 1e-5f);
    const float4 gg = ((const float4*)g)[lane];
    const float4 bb = ((const float4*)b)[lane];
    alignas(8) bf16 t[4];
    t[0] = __float2bfloat16(fmaf(d0 * inv, gg.x, bb.x));
    t[1] = __float2bfloat16(fmaf(d1 * inv, gg.y, bb.y));
    t[2] = __float2bfloat16(fmaf(d2 * inv, gg.z, bb.z));
    t[3] = __float2bfloat16(fmaf(d3 * inv, gg.w, bb.w));
    *(ushort4*)((unsigned short*)y + row * HID + lane * 4) = *(const ushort4*)t;
}

// ---------------------------------------------------------------------------
// Concat: hcat[row] = [abuf[row] (256 bf16), bf16(emb[fb[row]]) (10), 0 (22)]
// ---------------------------------------------------------------------------
__global__ __launch_bounds__(64) void concat_b(
    const bf16* __restrict__ ab, const float* __restrict__ emb,
    const int* __restrict__ fb, bf16* __restrict__ hcat)
{
    const long row = blockIdx.x;
    const int lane = threadIdx.x;
    const ushort4 v = ((const ushort4*)(ab + row * HID))[lane];
    ((ushort4*)(hcat + row * 288))[lane] = v;
    if (lane < 32) {
        bf16 val = (lane < EMB_D)
            ? __float2bfloat16(emb[(long)fb[row] * EMB_D + lane])
            : __float2bfloat16(0.f);
        hcat[row * 288 + 256 + lane] = val;
    }
}

// 16-element dot of W-column (per-lane regs) with a broadcast row in 4 float4s
#define RED16(dst, M, r0, r1, r2, r3) do {                                     \
    float _ra = fmaf((M)[3],  (r0).w, fmaf((M)[2],  (r0).z, fmaf((M)[1],  (r0).y, (M)[0]  * (r0).x))); \
    float _rb = fmaf((M)[7],  (r1).w, fmaf((M)[6],  (r1).z, fmaf((M)[5],  (r1).y, (M)[4]  * (r1).x))); \
    float _rc = fmaf((M)[11], (r2).w, fmaf((M)[10], (r2).z, fmaf((M)[9],  (r2).y, (M)[8]  * (r2).x))); \
    float _rd = fmaf((M)[15], (r3).w, fmaf((M)[14], (r3).z, fmaf((M)[13], (r3).y, (M)[12] * (r3).x))); \
    dst = (_ra + _rb) + (_rc + _rd);                                           \
} while (0)

// ---------------------------------------------------------------------------
// Delta-rule scan v7: TLP fix. Same math as scan3 (fastest passing variant),
// but 128 waves packed onto 16 CUs: 16 blocks x 512 threads = 8 independent
// waves/block (no barriers; per-wave LDS regions, per-wave vmcnt) -> 1
// block/CU (114.7KB LDS), 8 waves/CU = 2 waves/SIMD so LDS/issue stalls of
// one wave are covered by the other. CHUNK=8, LDS row stride 56 floats:
// staging = exactly 7x64 float4 slots; recurrence rows land on disjoint bank
// quads {0,24,16,8} (conflict-free). Global row is 52 floats: staging f4=13
// reads 4 floats into the next row's storage (harmless, lands in LDS pad).
// ---------------------------------------------------------------------------
__global__ __launch_bounds__(512, 1) void scan7(
    const float* __restrict__ qkvb, bf16* __restrict__ o)
{
    __shared__ float lds[8 * 2 * WBUF];   // 8 waves x dbuf = 114,688 B
    const int tid  = threadIdx.x;
    const int w    = tid >> 6;            // wave 0..7
    const int lane = tid & 63;
    const int c    = lane >> 4;           // chain within wave (0..3)
    const int vi   = lane & 15;           // v column
    const int bh0  = (blockIdx.x * 8 + w) * 4;   // 4 chains per wave
    const int chain = bh0 + c;
    const int b = chain >> 4, hh = chain & 15;
    float* wlds = lds + w * 2 * WBUF;     // this wave's private region

    bf16* po = o + (long)b * HID + hh * HDIM + vi;

    // stage chunk ch into wave buffer: 7 issues x 64 lanes x 16B (448 slots)
    auto stage = [&](int buf, int ch) {
#pragma unroll
        for (int i = 0; i < 7; ++i) {
            const int slot = i * 64 + lane;       // float4 slot, 0..447
            const int row  = slot / 14;           // 0..31 = s_local*4 + cc
            const int f4   = slot - row * 14;     // 0..13 (13 = pad, junk ok)
            const int cc   = row & 3, sl = row >> 2;
            const float* src = qkvb
                + (((long)(bh0 + cc) << 10) + ch * CH7 + sl) * QSTRIDE + f4 * 4;
            GLOAD16(src, &wlds[buf * WBUF + i * 256]);
        }
    };

    float W[16];
#pragma unroll
    for (int j = 0; j < 16; ++j) W[j] = 0.f;

    stage(0, 0);
    asm volatile("s_waitcnt vmcnt(0)" ::: "memory");
    const int nch = S_LEN / CH7;                  // 128
    for (int ch = 0; ch < nch; ++ch) {
        const int buf = ch & 1;
        // retire this chunk's 7 loads (oldest); <=8 output stores may remain
        asm volatile("s_waitcnt vmcnt(8)" ::: "memory");
        if (ch + 1 < nch) stage(buf ^ 1, ch + 1); // lands during prep+rec

        float* base = wlds + buf * WBUF;
        // ---- fused prep: 32 rows, one 16-float half per lane ----
        // half=0: softmax q (floats 0..15) + sigmoid beta(48);
        // half=1: softmax k (floats 16..31).
        {
            float* p = base + (lane >> 1) * RSTRIDE + ((lane & 1) << 4);
            float4 a0 = *(float4*)(p),     a1 = *(float4*)(p + 4);
            float4 a2 = *(float4*)(p + 8), a3 = *(float4*)(p + 12);
            float mx = fmaxf(fmaxf(fmaxf(a0.x, a0.y), fmaxf(a0.z, a0.w)),
                             fmaxf(fmaxf(a1.x, a1.y), fmaxf(a1.z, a1.w)));
            mx = fmaxf(mx, fmaxf(fmaxf(fmaxf(a2.x, a2.y), fmaxf(a2.z, a2.w)),
                                 fmaxf(fmaxf(a3.x, a3.y), fmaxf(a3.z, a3.w))));
            a0.x = __expf(a0.x - mx); a0.y = __expf(a0.y - mx);
            a0.z = __expf(a0.z - mx); a0.w = __expf(a0.w - mx);
            a1.x = __expf(a1.x - mx); a1.y = __expf(a1.y - mx);
            a1.z = __expf(a1.z - mx); a1.w = __expf(a1.w - mx);
            a2.x = __expf(a2.x - mx); a2.y = __expf(a2.y - mx);
            a2.z = __expf(a2.z - mx); a2.w = __expf(a2.w - mx);
            a3.x = __expf(a3.x - mx); a3.y = __expf(a3.y - mx);
            a3.z = __expf(a3.z - mx); a3.w = __expf(a3.w - mx);
            const float sum = ((a0.x + a0.y) + (a0.z + a0.w))
                            + ((a1.x + a1.y) + (a1.z + a1.w))
                            + ((a2.x + a2.y) + (a2.z + a2.w))
                            + ((a3.x + a3.y) + (a3.z + a3.w));
            const float inv = 1.f / sum;
            a0.x *= inv; a0.y *= inv; a0.z *= inv; a0.w *= inv;
            a1.x *= inv; a1.y *= inv; a1.z *= inv; a1.w *= inv;
            a2.x *= inv; a2.y *= inv; a2.z *= inv; a2.w *= inv;
            a3.x *= inv; a3.y *= inv; a3.z *= inv; a3.w *= inv;
            *(float4*)(p)      = a0; *(float4*)(p + 4)  = a1;
            *(float4*)(p + 8)  = a2; *(float4*)(p + 12) = a3;
            if (!(lane & 1)) p[48] = 1.f / (1.f + __expf(-p[48]));
        }
        asm volatile("s_waitcnt lgkmcnt(0)" ::: "memory"); // prep visible wave-wide

        // ---- recurrence over CH7 steps ----
        const int sg0 = ch * CH7;
        for (int sl = 0; sl < CH7; ++sl) {
            const float* p = base + (sl * 4 + c) * RSTRIDE;
            const float4 q0 = *(const float4*)(p);
            const float4 q1 = *(const float4*)(p + 4);
            const float4 q2 = *(const float4*)(p + 8);
            const float4 q3 = *(const float4*)(p + 12);
            const float4 k0 = *(const float4*)(p + 16);
            const float4 k1 = *(const float4*)(p + 20);
            const float4 k2 = *(const float4*)(p + 24);
            const float4 k3 = *(const float4*)(p + 28);
            const float vt = p[32 + vi];
            const float bt = p[48];

            float vold; RED16(vold, W, k0, k1, k2, k3);
            const float dv = bt * (vt - vold);
            W[0]  = fmaf(k0.x, dv, W[0]);  W[1]  = fmaf(k0.y, dv, W[1]);
            W[2]  = fmaf(k0.z, dv, W[2]);  W[3]  = fmaf(k0.w, dv, W[3]);
            W[4]  = fmaf(k1.x, dv, W[4]);  W[5]  = fmaf(k1.y, dv, W[5]);
            W[6]  = fmaf(k1.z, dv, W[6]);  W[7]  = fmaf(k1.w, dv, W[7]);
            W[8]  = fmaf(k2.x, dv, W[8]);  W[9]  = fmaf(k2.y, dv, W[9]);
            W[10] = fmaf(k2.z, dv, W[10]); W[11] = fmaf(k2.w, dv, W[11]);
            W[12] = fmaf(k3.x, dv, W[12]); W[13] = fmaf(k3.y, dv, W[13]);
            W[14] = fmaf(k3.z, dv, W[14]); W[15] = fmaf(k3.w, dv, W[15]);
            float ov; RED16(ov, W, q0, q1, q2, q3);
            po[(long)(sg0 + sl) * (B_SZ * HID)] = __float2bfloat16(ov);
        }
    }
}

// ---------------------------------------------------------------------------
extern "C" void kernel_launch(void* const* d_in, const int* in_sizes, int n_in,
                              void* d_out, int out_size, void* d_ws, size_t ws_size,
                              hipStream_t stream)
{
    const float* x      = (const float*)d_in[0];
    const int*   fb     = (const int*)  d_in[1];
    const float* fc1_w  = (const float*)d_in[2];
    const float* fc1_b  = (const float*)d_in[3];
    const float* emb    = (const float*)d_in[4];
    const float* proj_w = (const float*)d_in[5];
    const float* proj_b = (const float*)d_in[6];
    const float* ln1_g  = (const float*)d_in[7];
    const float* ln1_b  = (const float*)d_in[8];
    const float* slow_w = (const float*)d_in[9];
    const float* out_w  = (const float*)d_in[10];
    const float* ln2_g  = (const float*)d_in[11];
    const float* ln2_b  = (const float*)d_in[12];
    const float* ff1_w  = (const float*)d_in[13];
    const float* ff1_b  = (const float*)d_in[14];
    const float* ff2_w  = (const float*)d_in[15];
    const float* ff2_b  = (const float*)d_in[16];
    const float* outl_w = (const float*)d_in[17];
    const float* outl_b = (const float*)d_in[18];

    // ---- workspace layout (59.5 MB) ----
    char* wp = (char*)d_ws;
    float* h    = (float*)wp;                 wp += (size_t)MROWS * HID * 4;   // 33.5MB
    bf16*  abuf = (bf16*)wp;                  wp += (size_t)MROWS * HID * 2;   // 16.8MB
    bf16*  fc1b = (bf16*)wp;                  wp += (size_t)HID * IN_DIM * 2;
    bf16*  projb= (bf16*)wp;                  wp += (size_t)HID * 288 * 2;
    bf16*  slowb= (bf16*)wp;                  wp += (size_t)NLAYER * 896 * HID * 2;
    bf16*  outwb= (bf16*)wp;                  wp += (size_t)NLAYER * HID * HID * 2;
    bf16*  ff1b = (bf16*)wp;                  wp += (size_t)NLAYER * DFF * HID * 2;
    bf16*  ff2b = (bf16*)wp;                  wp += (size_t)NLAYER * HID * DFF * 2;
    bf16*  outlb= (bf16*)wp;                  wp += (size_t)1664 * HID * 2;

    // ---- d_out scratch (212.9 MB), sequentially reused ----
    bf16*  xb   = (bf16*)d_out;               // 201.3MB, dead after fc1
    bf16*  hcat = (bf16*)d_out;               // 18.9MB, dead after proj
    float* qkvb = (float*)d_out;              // 109.1MB, dead after scan
    bf16*  hff  = (bf16*)d_out;               // 67.1MB, dead after ff2

    const dim3 blk(256);

    // ---- weight/input conversions (re-done every launch; deterministic) ----
    cvt8<<<dim3(4096), blk, 0, stream>>>(x, xb, (long)MROWS * IN_DIM / 8);
    cvt8<<<dim3(384),  blk, 0, stream>>>(fc1_w, fc1b, (long)HID * IN_DIM / 8);
    cvtpad<<<dim3(288), blk, 0, stream>>>(proj_w, projb, HID, HID + EMB_D, HID, 288);
    for (int l = 0; l < NLAYER; ++l)
        cvtpad<<<dim3(896), blk, 0, stream>>>(slow_w + (size_t)l * 784 * HID,
                                              slowb + (size_t)l * 896 * HID,
                                              784, HID, 896, HID);
    cvt8<<<dim3(128), blk, 0, stream>>>(out_w, outwb, (long)NLAYER * HID * HID / 8);
    cvt8<<<dim3(512), blk, 0, stream>>>(ff1_w, ff1b, (long)NLAYER * DFF * HID / 8);
    cvt8<<<dim3(512), blk, 0, stream>>>(ff2_w, ff2b, (long)NLAYER * HID * DFF / 8);
    cvtpad<<<dim3(1664), blk, 0, stream>>>(outl_w, outlb, NCLS, HID, 1664, HID);

    // fc1: abuf = bf16(x @ fc1_w^T + b)    N=256 K=3072
    mgemm<9><<<dim3(256, 2), blk, 0, stream>>>(xb, fc1b, fc1_b, nullptr, abuf,
                                               HID, IN_DIM, IN_DIM);
    // hcat = [abuf, emb[fb], 0-pad]  (K padded to 288)
    concat_b<<<dim3(MROWS), dim3(64), 0, stream>>>(abuf, emb, fb, hcat);
    // proj: h = hcat @ proj_w^T + b        N=256 K=288(266+pad)
    mgemm<1><<<dim3(256, 2), blk, 0, stream>>>(hcat, projb, proj_b, nullptr, h,
                                               HID, 288, 288);

    for (int l = 0; l < NLAYER; ++l) {
        ln_b<<<dim3(MROWS / 4), blk, 0, stream>>>(h, ln1_g + l * HID, ln1_b + l * HID, abuf);
        // qkvb (permuted (b,h,s,52) fp32, RAW — softmax fused into scan7)
        mgemm<16><<<dim3(256, 7), blk, 0, stream>>>(abuf, slowb + (size_t)l * 896 * HID,
                                                    nullptr, nullptr, qkvb, 784, HID, HID);
        scan7<<<dim3(16), dim3(512), 0, stream>>>(qkvb, abuf);
        // h += o @ out_w^T                  N=256 K=256
        mgemm<4><<<dim3(256, 2), blk, 0, stream>>>(abuf, outwb + (size_t)l * HID * HID,
                                                   nullptr, h, h, HID, HID, HID);
        ln_b<<<dim3(MROWS / 4), blk, 0, stream>>>(h, ln2_g + l * HID, ln2_b + l * HID, abuf);
        // hff = bf16(relu(y @ ff1^T + b1))  N=1024 K=256
        mgemm<11><<<dim3(256, 8), blk, 0, stream>>>(abuf, ff1b + (size_t)l * DFF * HID,
                                                    ff1_b + l * DFF, nullptr, hff,
                                                    DFF, HID, HID);
        // h += hff @ ff2^T + b2             N=256 K=1024
        mgemm<5><<<dim3(256, 2), blk, 0, stream>>>(hff, ff2b + (size_t)l * HID * DFF,
                                                   ff2_b + l * HID, h, h, HID, DFF, DFF);
    }
    // final: abuf = bf16(h); out = abuf @ outl_w^T + b  (fp32, N=1623 K=256)
    cvt8<<<dim3(1024), blk, 0, stream>>>(h, abuf, (long)MROWS * HID / 8);
    mgemm<1><<<dim3(256, 13), blk, 0, stream>>>(abuf, outlb, outl_b, nullptr, d_out,
                                                NCLS, HID, HID);
}

// Round 11
// 1685.628 us; speedup vs baseline: 1.5480x; 1.5480x over previous
//
#include <hip/hip_runtime.h>
#include <hip/hip_bf16.h>

// Problem constants
#define S_LEN  1024
#define B_SZ   32
#define IN_DIM 3072
#define HID    256
#define NHEAD  16
#define HDIM   16
#define DFF    1024
#define NLAYER 4
#define NCLS   1623
#define EMB_D  10
#define MROWS  (S_LEN * B_SZ)   // 32768
#define QSTRIDE 52               // per-step qkvb stride (16B aligned rows)

using bf16   = __hip_bfloat16;
using short8 = __attribute__((ext_vector_type(8))) short;
using f32x4  = __attribute__((ext_vector_type(4))) float;

#define GLOAD16(g, l) __builtin_amdgcn_global_load_lds(                        \
    (const __attribute__((address_space(1))) void*)(g),                        \
    (__attribute__((address_space(3))) void*)(l), 16, 0, 0)

// ---------------------------------------------------------------------------
// bf16 MFMA GEMM: C[M,N] = A[M,K]@W[N,K]^T.  BM=BN=128, BK=32, 256 thr/4 waves,
// each wave a 64x64 quadrant (4x4 frags of 16x16x32). K multiple of 32.
// W buffers padded to 128-multiple rows. FLAGS: 1 bias, 2 relu, 4 residual(fp32),
// 8 bf16-out, 16 permuted qkvb store (fp32, (b,h,s,52) layout).
// ---------------------------------------------------------------------------
template<int FLAGS>
__global__ __launch_bounds__(256) void mgemm(
    const bf16* __restrict__ A, const bf16* __restrict__ W,
    const float* __restrict__ bias, const float* R, void* C,
    int N, int K, int Wld)
{
    __shared__ bf16 sA[2][128 * 32];
    __shared__ bf16 sB[2][128 * 32];
    const int t    = threadIdx.x;
    const int lane = t & 63;
    const int wid  = t >> 6;
    const int wr   = wid >> 1, wc = wid & 1;
    const long bm  = (long)blockIdx.x * 128;
    const int  bn  = blockIdx.y * 128;
    const int  fr  = lane & 15;        // frag row/col
    const int  fg  = lane >> 4;        // k-group
    const int  row0 = t >> 2;          // staging row (0..63), +64 for 2nd issue
    const int  kq0  = (t & 3) << 3;    // staging k offset (elems)

    f32x4 acc[4][4];
#pragma unroll
    for (int m = 0; m < 4; ++m)
#pragma unroll
        for (int n = 0; n < 4; ++n)
#pragma unroll
            for (int r = 0; r < 4; ++r) acc[m][n][r] = 0.f;

    const int nkt = K >> 5;

    auto stage = [&](int buf, int kt) {
        const int k0 = kt << 5;
        GLOAD16(A + (bm + row0)      * (long)K   + k0 + kq0, &sA[buf][(t      ) * 8]);
        GLOAD16(A + (bm + row0 + 64) * (long)K   + k0 + kq0, &sA[buf][(t + 256) * 8]);
        GLOAD16(W + (long)(bn + row0)      * Wld + k0 + kq0, &sB[buf][(t      ) * 8]);
        GLOAD16(W + (long)(bn + row0 + 64) * Wld + k0 + kq0, &sB[buf][(t + 256) * 8]);
    };

    stage(0, 0);
    __syncthreads();
    for (int kt = 0; kt < nkt; ++kt) {
        const int cur = kt & 1;
        if (kt + 1 < nkt) stage(cur ^ 1, kt + 1);
        short8 af[4], bg[4];
#pragma unroll
        for (int m = 0; m < 4; ++m)
            af[m] = *(const short8*)&sA[cur][(wr * 64 + m * 16 + fr) * 32 + fg * 8];
#pragma unroll
        for (int n = 0; n < 4; ++n)
            bg[n] = *(const short8*)&sB[cur][(wc * 64 + n * 16 + fr) * 32 + fg * 8];
#pragma unroll
        for (int m = 0; m < 4; ++m)
#pragma unroll
            for (int n = 0; n < 4; ++n)
                acc[m][n] = __builtin_amdgcn_mfma_f32_16x16x32_bf16(
                    af[m], bg[n], acc[m][n], 0, 0, 0);
        __syncthreads();
    }

    // Epilogue. C/D layout (HW-verified): col = lane&15, row = (lane>>4)*4+reg.
    float bs[4];
#pragma unroll
    for (int n = 0; n < 4; ++n) {
        const int c = bn + wc * 64 + n * 16 + fr;
        bs[n] = ((FLAGS & 1) && c < N) ? bias[c] : 0.f;
    }
#pragma unroll
    for (int m = 0; m < 4; ++m) {
#pragma unroll
        for (int n = 0; n < 4; ++n) {
            const int c = bn + wc * 64 + n * 16 + fr;
            if (c < N) {
#pragma unroll
                for (int r = 0; r < 4; ++r) {
                    const long rw = bm + wr * 64 + m * 16 + fg * 4 + r;
                    float v = acc[m][n][r] + bs[n];
                    if (FLAGS & 2) v = fmaxf(v, 0.f);
                    if (FLAGS & 4) v += R[rw * N + c];
                    if (FLAGS & 16) {
                        const int s = (int)(rw >> 5), b = (int)(rw & 31);
                        const int hh = c / 49, cc = c - hh * 49;
                        ((float*)C)[((long)(b * 16 + hh) * 1024 + s) * QSTRIDE + cc] = v;
                    } else if (FLAGS & 8) {
                        ((bf16*)C)[rw * N + c] = __float2bfloat16(v);
                    } else {
                        ((float*)C)[rw * N + c] = v;
                    }
                }
            }
        }
    }
}

// ---------------------------------------------------------------------------
// fp32 -> bf16 bulk convert, count divisible by 8.
// ---------------------------------------------------------------------------
__global__ __launch_bounds__(256) void cvt8(const float* __restrict__ s,
                                            bf16* __restrict__ d, long n8)
{
    for (long i = (long)blockIdx.x * 256 + threadIdx.x; i < n8;
         i += (long)gridDim.x * 256) {
        const float4 a = ((const float4*)s)[i * 2];
        const float4 b = ((const float4*)s)[i * 2 + 1];
        alignas(16) bf16 t[8];
        t[0] = __float2bfloat16(a.x); t[1] = __float2bfloat16(a.y);
        t[2] = __float2bfloat16(a.z); t[3] = __float2bfloat16(a.w);
        t[4] = __float2bfloat16(b.x); t[5] = __float2bfloat16(b.y);
        t[6] = __float2bfloat16(b.z); t[7] = __float2bfloat16(b.w);
        ((short8*)d)[i] = *(const short8*)t;
    }
}

// ---------------------------------------------------------------------------
// fp32 [rows][cols] -> bf16 [prows][pcols], zero-padded.
// ---------------------------------------------------------------------------
__global__ __launch_bounds__(256) void cvtpad(const float* __restrict__ s,
                                              bf16* __restrict__ d,
                                              int rows, int cols, int prows, int pcols)
{
    const long tot = (long)prows * pcols;
    for (long i = (long)blockIdx.x * 256 + threadIdx.x; i < tot;
         i += (long)gridDim.x * 256) {
        const int r = (int)(i / pcols), c = (int)(i - (long)r * pcols);
        d[i] = (r < rows && c < cols) ? __float2bfloat16(s[(long)r * cols + c])
                                      : __float2bfloat16(0.f);
    }
}

// ---------------------------------------------------------------------------
// LayerNorm(256) -> bf16. One wave per row, 4 rows/block.
// ---------------------------------------------------------------------------
__global__ __launch_bounds__(256) void ln_b(
    const float* __restrict__ x, const float* __restrict__ g,
    const float* __restrict__ b, bf16* __restrict__ y)
{
    const int wave = threadIdx.x >> 6, lane = threadIdx.x & 63;
    const long row = (long)(blockIdx.x << 2) + wave;
    const float4 v = ((const float4*)(x + row * HID))[lane];
    float s = v.x + v.y + v.z + v.w;
#pragma unroll
    for (int m = 32; m; m >>= 1) s += __shfl_xor(s, m);
    const float mean = s * (1.f / 256.f);
    const float d0 = v.x - mean, d1 = v.y - mean, d2 = v.z - mean, d3 = v.w - mean;
    float ss = d0 * d0 + d1 * d1 + d2 * d2 + d3 * d3;
#pragma unroll
    for (int m = 32; m; m >>= 1) ss += __shfl_xor(ss, m);
    const float inv = rsqrtf(ss * (1.f / 256.f) + 1e-5f);
    const float4 gg = ((const float4*)g)[lane];
    const float4 bb = ((const float4*)b)[lane];
    alignas(8) bf16 t[4];
    t[0] = __float2bfloat16(fmaf(d0 * inv, gg.x, bb.x));
    t[1] = __float2bfloat16(fmaf(d1 * inv, gg.y, bb.y));
    t[2] = __float2bfloat16(fmaf(d2 * inv, gg.z, bb.z));
    t[3] = __float2bfloat16(fmaf(d3 * inv, gg.w, bb.w));
    *(ushort4*)((unsigned short*)y + row * HID + lane * 4) = *(const ushort4*)t;
}

// ---------------------------------------------------------------------------
// Concat: hcat[row] = [abuf[row] (256 bf16), bf16(emb[fb[row]]) (10), 0 (22)]
// ---------------------------------------------------------------------------
__global__ __launch_bounds__(64) void concat_b(
    const bf16* __restrict__ ab, const float* __restrict__ emb,
    const int* __restrict__ fb, bf16* __restrict__ hcat)
{
    const long row = blockIdx.x;
    const int lane = threadIdx.x;
    const ushort4 v = ((const ushort4*)(ab + row * HID))[lane];
    ((ushort4*)(hcat + row * 288))[lane] = v;
    if (lane < 32) {
        bf16 val = (lane < EMB_D)
            ? __float2bfloat16(emb[(long)fb[row] * EMB_D + lane])
            : __float2bfloat16(0.f);
        hcat[row * 288 + 256 + lane] = val;
    }
}

// 16-dot of register array kr[16] with a row staged as 4 float4s
#define DOT16(dst, kr, s0, s1, s2, s3) do {                                    \
    float _pa = fmaf(kr[3],  (s0).w, fmaf(kr[2],  (s0).z, fmaf(kr[1],  (s0).y, kr[0]  * (s0).x))); \
    float _pb = fmaf(kr[7],  (s1).w, fmaf(kr[6],  (s1).z, fmaf(kr[5],  (s1).y, kr[4]  * (s1).x))); \
    float _pc = fmaf(kr[11], (s2).w, fmaf(kr[10], (s2).z, fmaf(kr[9],  (s2).y, kr[8]  * (s2).x))); \
    float _pd = fmaf(kr[15], (s3).w, fmaf(kr[14], (s3).z, fmaf(kr[13], (s3).y, kr[12] * (s3).x))); \
    dst = (_pa + _pb) + (_pc + _pd);                                           \
} while (0)

// ---------------------------------------------------------------------------
// Delta-rule scan v8: chunked WY reformulation (T=16). Per chunk:
//   dv_i = b_i(v_i - W0^T k_i) - sum_{s<i} b_i (k_i.k_s) dv_s   (forward subst)
//   o_i  = W0^T q_i + sum_{s<=i} (q_i.k_s) dv_s
//   W0  += K^T DV
// All phases are parallel 16-dots over 64 lanes (lane = (i=lane>>2, jq=lane&3),
// owning [i][jq*4..+3]); the only serial part is 15 shfl+fmaf substitution
// rounds. One wave per (b,h) chain (512 blocks). LDS: 2x 32-step staged qkvb
// buffers (linear global_load_lds, counted vmcnt), W0/G/QK/DV tables.
// ---------------------------------------------------------------------------
__global__ __launch_bounds__(64) void scan8(
    const float* __restrict__ qkvb, bf16* __restrict__ o)
{
    __shared__ float sbuf[2][1792];      // 2 x 32 steps x 52 (+pad for over-read)
    __shared__ float W0l[16 * 20];       // W0[x][j], row stride 20 (b128-aligned)
    __shared__ float Gm[16 * 17];        // -beta_i*(k_i.k_s), 0 for s>=i
    __shared__ float QKm[16 * 17];       // q_i.k_s, 0 for s>i
    __shared__ float DVl[16 * 20];       // dv[i][j], row stride 20
    const int lane = threadIdx.x;
    const int i4 = lane >> 2;            // step-in-chunk / x-row (phase H)
    const int jq = lane & 3;             // j quartet
    const int chain = blockIdx.x;        // b*16 + h
    const int b = chain >> 4, hh = chain & 15;
    const float* cb = qkvb + (long)chain * S_LEN * QSTRIDE;
    bf16* po = o + (long)b * HID + hh * HDIM + jq * 4;

    for (int z = lane; z < 320; z += 64) W0l[z] = 0.f;

    // stage one 32-step buffer: 7 x 64 lanes x 16B, fully linear
    auto stage = [&](int buf, int nb2) {
#pragma unroll
        for (int iss = 0; iss < 7; ++iss) {
            const float* src = cb + (long)nb2 * 1664 + iss * 256 + lane * 4;
            GLOAD16(src, &sbuf[buf][iss * 256 + lane * 4]);
        }
    };

    stage(0, 0);
    asm volatile("s_waitcnt vmcnt(0)" ::: "memory");
    for (int nb = 0; nb < 32; ++nb) {
        const int buf = nb & 1;
        // retire this buffer's 7 loads; <=2 newest o-stores may stay in flight
        asm volatile("s_waitcnt vmcnt(2)" ::: "memory");
        if (nb + 1 < 32) stage(buf ^ 1, nb + 1);

        float* sb = sbuf[buf];
        // ---- prep: softmax q|k half-row per lane (32 rows), sigmoid beta ----
        {
            float* p = sb + (lane >> 1) * 52 + ((lane & 1) << 4);
            float4 a0 = *(float4*)(p),     a1 = *(float4*)(p + 4);
            float4 a2 = *(float4*)(p + 8), a3 = *(float4*)(p + 12);
            float mx = fmaxf(fmaxf(fmaxf(a0.x, a0.y), fmaxf(a0.z, a0.w)),
                             fmaxf(fmaxf(a1.x, a1.y), fmaxf(a1.z, a1.w)));
            mx = fmaxf(mx, fmaxf(fmaxf(fmaxf(a2.x, a2.y), fmaxf(a2.z, a2.w)),
                                 fmaxf(fmaxf(a3.x, a3.y), fmaxf(a3.z, a3.w))));
            a0.x = __expf(a0.x - mx); a0.y = __expf(a0.y - mx);
            a0.z = __expf(a0.z - mx); a0.w = __expf(a0.w - mx);
            a1.x = __expf(a1.x - mx); a1.y = __expf(a1.y - mx);
            a1.z = __expf(a1.z - mx); a1.w = __expf(a1.w - mx);
            a2.x = __expf(a2.x - mx); a2.y = __expf(a2.y - mx);
            a2.z = __expf(a2.z - mx); a2.w = __expf(a2.w - mx);
            a3.x = __expf(a3.x - mx); a3.y = __expf(a3.y - mx);
            a3.z = __expf(a3.z - mx); a3.w = __expf(a3.w - mx);
            const float sum = ((a0.x + a0.y) + (a0.z + a0.w))
                            + ((a1.x + a1.y) + (a1.z + a1.w))
                            + ((a2.x + a2.y) + (a2.z + a2.w))
                            + ((a3.x + a3.y) + (a3.z + a3.w));
            const float inv = 1.f / sum;
            a0.x *= inv; a0.y *= inv; a0.z *= inv; a0.w *= inv;
            a1.x *= inv; a1.y *= inv; a1.z *= inv; a1.w *= inv;
            a2.x *= inv; a2.y *= inv; a2.z *= inv; a2.w *= inv;
            a3.x *= inv; a3.y *= inv; a3.z *= inv; a3.w *= inv;
            *(float4*)(p)      = a0; *(float4*)(p + 4)  = a1;
            *(float4*)(p + 8)  = a2; *(float4*)(p + 12) = a3;
            if (!(lane & 1)) p[48] = 1.f / (1.f + __expf(-p[48]));
        }
        asm volatile("s_waitcnt lgkmcnt(0)" ::: "memory");

        // ---- two chunks of T=16 per staged buffer ----
#pragma unroll
        for (int t = 0; t < 2; ++t) {
            const float* rb = sb + t * 16 * 52;
            const float* myrow = rb + i4 * 52;
            // cache this lane's k_i, q_i rows in registers
            float ki[16], qi[16];
            {
                const float4 kA = *(const float4*)(myrow + 16);
                const float4 kB = *(const float4*)(myrow + 20);
                const float4 kC = *(const float4*)(myrow + 24);
                const float4 kD = *(const float4*)(myrow + 28);
                ki[0]=kA.x; ki[1]=kA.y; ki[2]=kA.z; ki[3]=kA.w;
                ki[4]=kB.x; ki[5]=kB.y; ki[6]=kB.z; ki[7]=kB.w;
                ki[8]=kC.x; ki[9]=kC.y; ki[10]=kC.z; ki[11]=kC.w;
                ki[12]=kD.x; ki[13]=kD.y; ki[14]=kD.z; ki[15]=kD.w;
                const float4 qA = *(const float4*)(myrow);
                const float4 qB = *(const float4*)(myrow + 4);
                const float4 qC = *(const float4*)(myrow + 8);
                const float4 qD = *(const float4*)(myrow + 12);
                qi[0]=qA.x; qi[1]=qA.y; qi[2]=qA.z; qi[3]=qA.w;
                qi[4]=qB.x; qi[5]=qB.y; qi[6]=qB.z; qi[7]=qB.w;
                qi[8]=qC.x; qi[9]=qC.y; qi[10]=qC.z; qi[11]=qC.w;
                qi[12]=qD.x; qi[13]=qD.y; qi[14]=qD.z; qi[15]=qD.w;
            }
            const float beta = myrow[48];
            // G/QK: lane computes G[i][s], QK[i][s] for s = jq*4+m
#pragma unroll
            for (int m = 0; m < 4; ++m) {
                const int s = jq * 4 + m;
                const float* sr = rb + s * 52 + 16;
                const float4 s0 = *(const float4*)(sr);
                const float4 s1 = *(const float4*)(sr + 4);
                const float4 s2 = *(const float4*)(sr + 8);
                const float4 s3 = *(const float4*)(sr + 12);
                float g, qk;
                DOT16(g, ki, s0, s1, s2, s3);
                DOT16(qk, qi, s0, s1, s2, s3);
                Gm[i4 * 17 + s]  = (s < i4)  ? -beta * g : 0.f;
                QKm[i4 * 17 + s] = (s <= i4) ? qk : 0.f;
            }
            // P = W0^T k_i, O1 = W0^T q_i  (shared W0 reads)
            float P0=0,P1=0,P2=0,P3=0, O0=0,O1=0,O2=0,O3=0;
#pragma unroll
            for (int x = 0; x < 16; ++x) {
                const float4 w = *(const float4*)&W0l[x * 20 + jq * 4];
                P0 = fmaf(ki[x], w.x, P0); P1 = fmaf(ki[x], w.y, P1);
                P2 = fmaf(ki[x], w.z, P2); P3 = fmaf(ki[x], w.w, P3);
                O0 = fmaf(qi[x], w.x, O0); O1 = fmaf(qi[x], w.y, O1);
                O2 = fmaf(qi[x], w.z, O2); O3 = fmaf(qi[x], w.w, O3);
            }
            // e = beta*(v - P)
            const float4 vv = *(const float4*)(myrow + 32 + jq * 4);
            float d0 = beta * (vv.x - P0), d1 = beta * (vv.y - P1);
            float d2 = beta * (vv.z - P2), d3 = beta * (vv.w - P3);
            asm volatile("s_waitcnt lgkmcnt(0)" ::: "memory");
            // forward substitution: 15 rounds (coef 0 for lanes i<=s)
#pragma unroll
            for (int s = 0; s < 15; ++s) {
                const float cf = Gm[i4 * 17 + s];
                const float e0 = __shfl(d0, s * 4 + jq);
                const float e1 = __shfl(d1, s * 4 + jq);
                const float e2 = __shfl(d2, s * 4 + jq);
                const float e3 = __shfl(d3, s * 4 + jq);
                d0 = fmaf(cf, e0, d0); d1 = fmaf(cf, e1, d1);
                d2 = fmaf(cf, e2, d2); d3 = fmaf(cf, e3, d3);
            }
            // publish DV
            f32x4 dvv; dvv[0]=d0; dvv[1]=d1; dvv[2]=d2; dvv[3]=d3;
            *(f32x4*)&DVl[i4 * 20 + jq * 4] = dvv;
            asm volatile("s_waitcnt lgkmcnt(0)" ::: "memory");
            // O += tril(QK) DV
#pragma unroll
            for (int s = 0; s < 16; ++s) {
                const float c = QKm[i4 * 17 + s];
                const float4 dvs = *(const float4*)&DVl[s * 20 + jq * 4];
                O0 = fmaf(c, dvs.x, O0); O1 = fmaf(c, dvs.y, O1);
                O2 = fmaf(c, dvs.z, O2); O3 = fmaf(c, dvs.w, O3);
            }
            // store o (bf16, layout (s, b, h*16+j))
            {
                const int sg = nb * 32 + t * 16 + i4;
                alignas(8) bf16 tb[4];
                tb[0] = __float2bfloat16(O0); tb[1] = __float2bfloat16(O1);
                tb[2] = __float2bfloat16(O2); tb[3] = __float2bfloat16(O3);
                *(ushort4*)((unsigned short*)(po + (long)sg * (B_SZ * HID))) =
                    *(const ushort4*)tb;
            }
            // W0 += K^T DV   (lane role: x = i4)
            float a0=0,a1=0,a2=0,a3=0;
#pragma unroll
            for (int ii = 0; ii < 16; ++ii) {
                const float kx = rb[ii * 52 + 16 + i4];
                const float4 dvs = *(const float4*)&DVl[ii * 20 + jq * 4];
                a0 = fmaf(kx, dvs.x, a0); a1 = fmaf(kx, dvs.y, a1);
                a2 = fmaf(kx, dvs.z, a2); a3 = fmaf(kx, dvs.w, a3);
            }
            {
                float4 w = *(const float4*)&W0l[i4 * 20 + jq * 4];
                w.x += a0; w.y += a1; w.z += a2; w.w += a3;
                *(float4*)&W0l[i4 * 20 + jq * 4] = w;
            }
            asm volatile("s_waitcnt lgkmcnt(0)" ::: "memory");
        }
    }
}

// ---------------------------------------------------------------------------
extern "C" void kernel_launch(void* const* d_in, const int* in_sizes, int n_in,
                              void* d_out, int out_size, void* d_ws, size_t ws_size,
                              hipStream_t stream)
{
    const float* x      = (const float*)d_in[0];
    const int*   fb     = (const int*)  d_in[1];
    const float* fc1_w  = (const float*)d_in[2];
    const float* fc1_b  = (const float*)d_in[3];
    const float* emb    = (const float*)d_in[4];
    const float* proj_w = (const float*)d_in[5];
    const float* proj_b = (const float*)d_in[6];
    const float* ln1_g  = (const float*)d_in[7];
    const float* ln1_b  = (const float*)d_in[8];
    const float* slow_w = (const float*)d_in[9];
    const float* out_w  = (const float*)d_in[10];
    const float* ln2_g  = (const float*)d_in[11];
    const float* ln2_b  = (const float*)d_in[12];
    const float* ff1_w  = (const float*)d_in[13];
    const float* ff1_b  = (const float*)d_in[14];
    const float* ff2_w  = (const float*)d_in[15];
    const float* ff2_b  = (const float*)d_in[16];
    const float* outl_w = (const float*)d_in[17];
    const float* outl_b = (const float*)d_in[18];

    // ---- workspace layout (59.5 MB) ----
    char* wp = (char*)d_ws;
    float* h    = (float*)wp;                 wp += (size_t)MROWS * HID * 4;   // 33.5MB
    bf16*  abuf = (bf16*)wp;                  wp += (size_t)MROWS * HID * 2;   // 16.8MB
    bf16*  fc1b = (bf16*)wp;                  wp += (size_t)HID * IN_DIM * 2;
    bf16*  projb= (bf16*)wp;                  wp += (size_t)HID * 288 * 2;
    bf16*  slowb= (bf16*)wp;                  wp += (size_t)NLAYER * 896 * HID * 2;
    bf16*  outwb= (bf16*)wp;                  wp += (size_t)NLAYER * HID * HID * 2;
    bf16*  ff1b = (bf16*)wp;                  wp += (size_t)NLAYER * DFF * HID * 2;
    bf16*  ff2b = (bf16*)wp;                  wp += (size_t)NLAYER * HID * DFF * 2;
    bf16*  outlb= (bf16*)wp;                  wp += (size_t)1664 * HID * 2;

    // ---- d_out scratch (212.9 MB), sequentially reused ----
    bf16*  xb   = (bf16*)d_out;               // 201.3MB, dead after fc1
    bf16*  hcat = (bf16*)d_out;               // 18.9MB, dead after proj
    float* qkvb = (float*)d_out;              // 109.1MB, dead after scan
    bf16*  hff  = (bf16*)d_out;               // 67.1MB, dead after ff2

    const dim3 blk(256);

    // ---- weight/input conversions (re-done every launch; deterministic) ----
    cvt8<<<dim3(4096), blk, 0, stream>>>(x, xb, (long)MROWS * IN_DIM / 8);
    cvt8<<<dim3(384),  blk, 0, stream>>>(fc1_w, fc1b, (long)HID * IN_DIM / 8);
    cvtpad<<<dim3(288), blk, 0, stream>>>(proj_w, projb, HID, HID + EMB_D, HID, 288);
    for (int l = 0; l < NLAYER; ++l)
        cvtpad<<<dim3(896), blk, 0, stream>>>(slow_w + (size_t)l * 784 * HID,
                                              slowb + (size_t)l * 896 * HID,
                                              784, HID, 896, HID);
    cvt8<<<dim3(128), blk, 0, stream>>>(out_w, outwb, (long)NLAYER * HID * HID / 8);
    cvt8<<<dim3(512), blk, 0, stream>>>(ff1_w, ff1b, (long)NLAYER * DFF * HID / 8);
    cvt8<<<dim3(512), blk, 0, stream>>>(ff2_w, ff2b, (long)NLAYER * HID * DFF / 8);
    cvtpad<<<dim3(1664), blk, 0, stream>>>(outl_w, outlb, NCLS, HID, 1664, HID);

    // fc1: abuf = bf16(x @ fc1_w^T + b)    N=256 K=3072
    mgemm<9><<<dim3(256, 2), blk, 0, stream>>>(xb, fc1b, fc1_b, nullptr, abuf,
                                               HID, IN_DIM, IN_DIM);
    // hcat = [abuf, emb[fb], 0-pad]  (K padded to 288)
    concat_b<<<dim3(MROWS), dim3(64), 0, stream>>>(abuf, emb, fb, hcat);
    // proj: h = hcat @ proj_w^T + b        N=256 K=288(266+pad)
    mgemm<1><<<dim3(256, 2), blk, 0, stream>>>(hcat, projb, proj_b, nullptr, h,
                                               HID, 288, 288);

    for (int l = 0; l < NLAYER; ++l) {
        ln_b<<<dim3(MROWS / 4), blk, 0, stream>>>(h, ln1_g + l * HID, ln1_b + l * HID, abuf);
        // qkvb (permuted (b,h,s,52) fp32, RAW — softmax fused into scan8)
        mgemm<16><<<dim3(256, 7), blk, 0, stream>>>(abuf, slowb + (size_t)l * 896 * HID,
                                                    nullptr, nullptr, qkvb, 784, HID, HID);
        scan8<<<dim3(B_SZ * NHEAD), dim3(64), 0, stream>>>(qkvb, abuf);
        // h += o @ out_w^T                  N=256 K=256
        mgemm<4><<<dim3(256, 2), blk, 0, stream>>>(abuf, outwb + (size_t)l * HID * HID,
                                                   nullptr, h, h, HID, HID, HID);
        ln_b<<<dim3(MROWS / 4), blk, 0, stream>>>(h, ln2_g + l * HID, ln2_b + l * HID, abuf);
        // hff = bf16(relu(y @ ff1^T + b1))  N=1024 K=256
        mgemm<11><<<dim3(256, 8), blk, 0, stream>>>(abuf, ff1b + (size_t)l * DFF * HID,
                                                    ff1_b + l * DFF, nullptr, hff,
                                                    DFF, HID, HID);
        // h += hff @ ff2^T + b2             N=256 K=1024
        mgemm<5><<<dim3(256, 2), blk, 0, stream>>>(hff, ff2b + (size_t)l * HID * DFF,
                                                   ff2_b + l * HID, h, h, HID, DFF, DFF);
    }
    // final: abuf = bf16(h); out = abuf @ outl_w^T + b  (fp32, N=1623 K=256)
    cvt8<<<dim3(1024), blk, 0, stream>>>(h, abuf, (long)MROWS * HID / 8);
    mgemm<1><<<dim3(256, 13), blk, 0, stream>>>(abuf, outlb, outl_b, nullptr, d_out,
                                                NCLS, HID, HID);
}

// Round 12
// 1664.802 us; speedup vs baseline: 1.5673x; 1.0125x over previous
//
#include <hip/hip_runtime.h>
#include <hip/hip_bf16.h>

// Problem constants
#define S_LEN  1024
#define B_SZ   32
#define IN_DIM 3072
#define HID    256
#define NHEAD  16
#define HDIM   16
#define DFF    1024
#define NLAYER 4
#define NCLS   1623
#define EMB_D  10
#define MROWS  (S_LEN * B_SZ)   // 32768
#define QSTRIDE 52               // per-step qkvb stride (16B aligned rows)

using bf16   = __hip_bfloat16;
using short8 = __attribute__((ext_vector_type(8))) short;
using f32x4  = __attribute__((ext_vector_type(4))) float;

#define GLOAD16(g, l) __builtin_amdgcn_global_load_lds(                        \
    (const __attribute__((address_space(1))) void*)(g),                        \
    (__attribute__((address_space(3))) void*)(l), 16, 0, 0)

// ---------------------------------------------------------------------------
// bf16 MFMA GEMM: C[M,N] = A[M,K]@W[N,K]^T.  BM=BN=128, BK=32, 256 thr/4 waves.
// FLAGS: 1 bias, 2 relu, 4 residual(fp32), 8 bf16-out, 16 permuted qkvb store.
// ---------------------------------------------------------------------------
template<int FLAGS>
__global__ __launch_bounds__(256) void mgemm(
    const bf16* __restrict__ A, const bf16* __restrict__ W,
    const float* __restrict__ bias, const float* R, void* C,
    int N, int K, int Wld)
{
    __shared__ bf16 sA[2][128 * 32];
    __shared__ bf16 sB[2][128 * 32];
    const int t    = threadIdx.x;
    const int lane = t & 63;
    const int wid  = t >> 6;
    const int wr   = wid >> 1, wc = wid & 1;
    const long bm  = (long)blockIdx.x * 128;
    const int  bn  = blockIdx.y * 128;
    const int  fr  = lane & 15;
    const int  fg  = lane >> 4;
    const int  row0 = t >> 2;
    const int  kq0  = (t & 3) << 3;

    f32x4 acc[4][4];
#pragma unroll
    for (int m = 0; m < 4; ++m)
#pragma unroll
        for (int n = 0; n < 4; ++n)
#pragma unroll
            for (int r = 0; r < 4; ++r) acc[m][n][r] = 0.f;

    const int nkt = K >> 5;

    auto stage = [&](int buf, int kt) {
        const int k0 = kt << 5;
        GLOAD16(A + (bm + row0)      * (long)K   + k0 + kq0, &sA[buf][(t      ) * 8]);
        GLOAD16(A + (bm + row0 + 64) * (long)K   + k0 + kq0, &sA[buf][(t + 256) * 8]);
        GLOAD16(W + (long)(bn + row0)      * Wld + k0 + kq0, &sB[buf][(t      ) * 8]);
        GLOAD16(W + (long)(bn + row0 + 64) * Wld + k0 + kq0, &sB[buf][(t + 256) * 8]);
    };

    stage(0, 0);
    __syncthreads();
    for (int kt = 0; kt < nkt; ++kt) {
        const int cur = kt & 1;
        if (kt + 1 < nkt) stage(cur ^ 1, kt + 1);
        short8 af[4], bg[4];
#pragma unroll
        for (int m = 0; m < 4; ++m)
            af[m] = *(const short8*)&sA[cur][(wr * 64 + m * 16 + fr) * 32 + fg * 8];
#pragma unroll
        for (int n = 0; n < 4; ++n)
            bg[n] = *(const short8*)&sB[cur][(wc * 64 + n * 16 + fr) * 32 + fg * 8];
#pragma unroll
        for (int m = 0; m < 4; ++m)
#pragma unroll
            for (int n = 0; n < 4; ++n)
                acc[m][n] = __builtin_amdgcn_mfma_f32_16x16x32_bf16(
                    af[m], bg[n], acc[m][n], 0, 0, 0);
        __syncthreads();
    }

    float bs[4];
#pragma unroll
    for (int n = 0; n < 4; ++n) {
        const int c = bn + wc * 64 + n * 16 + fr;
        bs[n] = ((FLAGS & 1) && c < N) ? bias[c] : 0.f;
    }
#pragma unroll
    for (int m = 0; m < 4; ++m) {
#pragma unroll
        for (int n = 0; n < 4; ++n) {
            const int c = bn + wc * 64 + n * 16 + fr;
            if (c < N) {
#pragma unroll
                for (int r = 0; r < 4; ++r) {
                    const long rw = bm + wr * 64 + m * 16 + fg * 4 + r;
                    float v = acc[m][n][r] + bs[n];
                    if (FLAGS & 2) v = fmaxf(v, 0.f);
                    if (FLAGS & 4) v += R[rw * N + c];
                    if (FLAGS & 16) {
                        const int s = (int)(rw >> 5), b = (int)(rw & 31);
                        const int hh = c / 49, cc = c - hh * 49;
                        ((float*)C)[((long)(b * 16 + hh) * 1024 + s) * QSTRIDE + cc] = v;
                    } else if (FLAGS & 8) {
                        ((bf16*)C)[rw * N + c] = __float2bfloat16(v);
                    } else {
                        ((float*)C)[rw * N + c] = v;
                    }
                }
            }
        }
    }
}

// ---------------------------------------------------------------------------
// fc1 GEMM with fused fp32->bf16 A-staging (kills the cvt8(x) round trip).
// A fp32 [M][3072] reg-staged + converted; W bf16 via global_load_lds.
// Epilogue: +bias, bf16 store. N=256 fixed, K=3072 (96 K-steps).
// ---------------------------------------------------------------------------
__global__ __launch_bounds__(256) void fc1_k(
    const float* __restrict__ A, const bf16* __restrict__ W,
    const float* __restrict__ bias, bf16* __restrict__ C)
{
    __shared__ bf16 sA[2][128 * 32];
    __shared__ bf16 sB[2][128 * 32];
    const int t    = threadIdx.x;
    const int lane = t & 63;
    const int wid  = t >> 6;
    const int wr   = wid >> 1, wc = wid & 1;
    const long bm  = (long)blockIdx.x * 128;
    const int  bn  = blockIdx.y * 128;
    const int  fr  = lane & 15;
    const int  fg  = lane >> 4;
    const int  row0 = t >> 2;
    const int  kq0  = (t & 3) << 3;
    const int  arow = t >> 3;            // 0..31 (+rep*32)
    const int  ac4  = (t & 7) << 2;      // 0,4,..,28

    f32x4 acc[4][4];
#pragma unroll
    for (int m = 0; m < 4; ++m)
#pragma unroll
        for (int n = 0; n < 4; ++n)
#pragma unroll
            for (int r = 0; r < 4; ++r) acc[m][n][r] = 0.f;

    auto stageB = [&](int buf, int kt) {
        const int k0 = kt << 5;
        GLOAD16(W + (long)(bn + row0)      * IN_DIM + k0 + kq0, &sB[buf][(t      ) * 8]);
        GLOAD16(W + (long)(bn + row0 + 64) * IN_DIM + k0 + kq0, &sB[buf][(t + 256) * 8]);
    };
    float4 va[4];
    auto loadA = [&](int kt) {
        const int k0 = kt << 5;
#pragma unroll
        for (int rep = 0; rep < 4; ++rep)
            va[rep] = *(const float4*)(A + (bm + arow + rep * 32) * (long)IN_DIM + k0 + ac4);
    };
    auto writeA = [&](int buf) {
#pragma unroll
        for (int rep = 0; rep < 4; ++rep) {
            alignas(8) bf16 tb[4];
            tb[0] = __float2bfloat16(va[rep].x);
            tb[1] = __float2bfloat16(va[rep].y);
            tb[2] = __float2bfloat16(va[rep].z);
            tb[3] = __float2bfloat16(va[rep].w);
            *(ushort4*)&sA[buf][(arow + rep * 32) * 32 + ac4] = *(const ushort4*)tb;
        }
    };

    loadA(0);
    stageB(0, 0);
    writeA(0);
    __syncthreads();
    const int nkt = IN_DIM >> 5;   // 96
    for (int kt = 0; kt < nkt; ++kt) {
        const int cur = kt & 1;
        if (kt + 1 < nkt) { stageB(cur ^ 1, kt + 1); loadA(kt + 1); }
        short8 af[4], bg[4];
#pragma unroll
        for (int m = 0; m < 4; ++m)
            af[m] = *(const short8*)&sA[cur][(wr * 64 + m * 16 + fr) * 32 + fg * 8];
#pragma unroll
        for (int n = 0; n < 4; ++n)
            bg[n] = *(const short8*)&sB[cur][(wc * 64 + n * 16 + fr) * 32 + fg * 8];
#pragma unroll
        for (int m = 0; m < 4; ++m)
#pragma unroll
            for (int n = 0; n < 4; ++n)
                acc[m][n] = __builtin_amdgcn_mfma_f32_16x16x32_bf16(
                    af[m], bg[n], acc[m][n], 0, 0, 0);
        if (kt + 1 < nkt) writeA(cur ^ 1);
        __syncthreads();
    }

#pragma unroll
    for (int n = 0; n < 4; ++n) {
        const int c = bn + wc * 64 + n * 16 + fr;
        const float bsn = bias[c];
#pragma unroll
        for (int m = 0; m < 4; ++m)
#pragma unroll
            for (int r = 0; r < 4; ++r) {
                const long rw = bm + wr * 64 + m * 16 + fg * 4 + r;
                C[rw * HID + c] = __float2bfloat16(acc[m][n][r] + bsn);
            }
    }
}

// ---------------------------------------------------------------------------
// fp32 -> bf16 bulk convert, count divisible by 8.
// ---------------------------------------------------------------------------
__global__ __launch_bounds__(256) void cvt8(const float* __restrict__ s,
                                            bf16* __restrict__ d, long n8)
{
    for (long i = (long)blockIdx.x * 256 + threadIdx.x; i < n8;
         i += (long)gridDim.x * 256) {
        const float4 a = ((const float4*)s)[i * 2];
        const float4 b = ((const float4*)s)[i * 2 + 1];
        alignas(16) bf16 t[8];
        t[0] = __float2bfloat16(a.x); t[1] = __float2bfloat16(a.y);
        t[2] = __float2bfloat16(a.z); t[3] = __float2bfloat16(a.w);
        t[4] = __float2bfloat16(b.x); t[5] = __float2bfloat16(b.y);
        t[6] = __float2bfloat16(b.z); t[7] = __float2bfloat16(b.w);
        ((short8*)d)[i] = *(const short8*)t;
    }
}

// ---------------------------------------------------------------------------
// fp32 [rows][cols] -> bf16 [prows][pcols], zero-padded.
// ---------------------------------------------------------------------------
__global__ __launch_bounds__(256) void cvtpad(const float* __restrict__ s,
                                              bf16* __restrict__ d,
                                              int rows, int cols, int prows, int pcols)
{
    const long tot = (long)prows * pcols;
    for (long i = (long)blockIdx.x * 256 + threadIdx.x; i < tot;
         i += (long)gridDim.x * 256) {
        const int r = (int)(i / pcols), c = (int)(i - (long)r * pcols);
        d[i] = (r < rows && c < cols) ? __float2bfloat16(s[(long)r * cols + c])
                                      : __float2bfloat16(0.f);
    }
}

// slow_w: 4 layers of [784][256] -> [896][256] padded, blockIdx.y = layer
__global__ __launch_bounds__(256) void cvtpad_slow(const float* __restrict__ s,
                                                   bf16* __restrict__ d)
{
    const int l = blockIdx.y;
    const float* src = s + (size_t)l * 784 * HID;
    bf16* dst = d + (size_t)l * 896 * HID;
    const long tot = (long)896 * HID;
    for (long i = (long)blockIdx.x * 256 + threadIdx.x; i < tot;
         i += (long)gridDim.x * 256) {
        const int r = (int)(i / HID), c = (int)(i - (long)r * HID);
        dst[i] = (r < 784) ? __float2bfloat16(src[(long)r * HID + c])
                           : __float2bfloat16(0.f);
    }
}

// ---------------------------------------------------------------------------
// LayerNorm(256) -> bf16. One wave per row, 4 rows/block.
// ---------------------------------------------------------------------------
__global__ __launch_bounds__(256) void ln_b(
    const float* __restrict__ x, const float* __restrict__ g,
    const float* __restrict__ b, bf16* __restrict__ y)
{
    const int wave = threadIdx.x >> 6, lane = threadIdx.x & 63;
    const long row = (long)(blockIdx.x << 2) + wave;
    const float4 v = ((const float4*)(x + row * HID))[lane];
    float s = v.x + v.y + v.z + v.w;
#pragma unroll
    for (int m = 32; m; m >>= 1) s += __shfl_xor(s, m);
    const float mean = s * (1.f / 256.f);
    const float d0 = v.x - mean, d1 = v.y - mean, d2 = v.z - mean, d3 = v.w - mean;
    float ss = d0 * d0 + d1 * d1 + d2 * d2 + d3 * d3;
#pragma unroll
    for (int m = 32; m; m >>= 1) ss += __shfl_xor(ss, m);
    const float inv = rsqrtf(ss * (1.f / 256.f) + 1e-5f);
    const float4 gg = ((const float4*)g)[lane];
    const float4 bb = ((const float4*)b)[lane];
    alignas(8) bf16 t[4];
    t[0] = __float2bfloat16(fmaf(d0 * inv, gg.x, bb.x));
    t[1] = __float2bfloat16(fmaf(d1 * inv, gg.y, bb.y));
    t[2] = __float2bfloat16(fmaf(d2 * inv, gg.z, bb.z));
    t[3] = __float2bfloat16(fmaf(d3 * inv, gg.w, bb.w));
    *(ushort4*)((unsigned short*)y + row * HID + lane * 4) = *(const ushort4*)t;
}

// ---------------------------------------------------------------------------
// Concat: hcat[row] = [abuf[row] (256 bf16), bf16(emb[fb[row]]) (10), 0 (22)]
// ---------------------------------------------------------------------------
__global__ __launch_bounds__(64) void concat_b(
    const bf16* __restrict__ ab, const float* __restrict__ emb,
    const int* __restrict__ fb, bf16* __restrict__ hcat)
{
    const long row = blockIdx.x;
    const int lane = threadIdx.x;
    const ushort4 v = ((const ushort4*)(ab + row * HID))[lane];
    ((ushort4*)(hcat + row * 288))[lane] = v;
    if (lane < 32) {
        bf16 val = (lane < EMB_D)
            ? __float2bfloat16(emb[(long)fb[row] * EMB_D + lane])
            : __float2bfloat16(0.f);
        hcat[row * 288 + 256 + lane] = val;
    }
}

// 16-dot of register array kr[16] with a row staged as 4 float4s
#define DOT16(dst, kr, s0, s1, s2, s3) do {                                    \
    float _pa = fmaf(kr[3],  (s0).w, fmaf(kr[2],  (s0).z, fmaf(kr[1],  (s0).y, kr[0]  * (s0).x))); \
    float _pb = fmaf(kr[7],  (s1).w, fmaf(kr[6],  (s1).z, fmaf(kr[5],  (s1).y, kr[4]  * (s1).x))); \
    float _pc = fmaf(kr[11], (s2).w, fmaf(kr[10], (s2).z, fmaf(kr[9],  (s2).y, kr[8]  * (s2).x))); \
    float _pd = fmaf(kr[15], (s3).w, fmaf(kr[14], (s3).z, fmaf(kr[13], (s3).y, kr[12] * (s3).x))); \
    dst = (_pa + _pb) + (_pc + _pd);                                           \
} while (0)

// ---------------------------------------------------------------------------
// Delta-rule scan v9: WY chunked (T=16), refined from v8:
//  - G/QK coefficients stay in REGISTERS; distributed in subst/O2 loops via
//    __shfl(reg[s&3], i4*4+(s>>2)) (static reg index; source lane owns A[i4][s])
//    -> Gm/QKm LDS tables, their writes/reads, and one full drain are gone.
//  - O2 and dW merged into one loop sharing the 16 DV b128 reads.
//  - 2 lgkmcnt(0) drains per chunk (DV publish; W0 RMW), 1 per buffer (prep).
// Lane layout: (i4 = lane>>2 step row, jq = lane&3 v-quartet). One wave per
// (b,h) chain (512 blocks). Double-buffered 32-step LDS staging, counted vmcnt.
// ---------------------------------------------------------------------------
__global__ __launch_bounds__(64) void scan9(
    const float* __restrict__ qkvb, bf16* __restrict__ o)
{
    __shared__ float sbuf[2][1792];      // 2 x 32 steps x 52 (+pad)
    __shared__ float W0l[16 * 20];       // W0[x][j], row stride 20
    __shared__ float DVl[16 * 20];       // dv[i][j], row stride 20
    const int lane = threadIdx.x;
    const int i4 = lane >> 2;
    const int jq = lane & 3;
    const int chain = blockIdx.x;        // b*16 + h
    const int b = chain >> 4, hh = chain & 15;
    const float* cb = qkvb + (long)chain * S_LEN * QSTRIDE;
    bf16* po = o + (long)b * HID + hh * HDIM + jq * 4;

    for (int z = lane; z < 320; z += 64) W0l[z] = 0.f;

    auto stage = [&](int buf, int nb2) {
#pragma unroll
        for (int iss = 0; iss < 7; ++iss) {
            const float* src = cb + (long)nb2 * 1664 + iss * 256 + lane * 4;
            GLOAD16(src, &sbuf[buf][iss * 256 + lane * 4]);
        }
    };

    stage(0, 0);
    asm volatile("s_waitcnt vmcnt(0)" ::: "memory");
    for (int nb = 0; nb < 32; ++nb) {
        const int buf = nb & 1;
        asm volatile("s_waitcnt vmcnt(2)" ::: "memory");
        if (nb + 1 < 32) stage(buf ^ 1, nb + 1);

        float* sb = sbuf[buf];
        // ---- prep: softmax q|k half-row per lane (32 rows), sigmoid beta ----
        {
            float* p = sb + (lane >> 1) * 52 + ((lane & 1) << 4);
            float4 a0 = *(float4*)(p),     a1 = *(float4*)(p + 4);
            float4 a2 = *(float4*)(p + 8), a3 = *(float4*)(p + 12);
            float mx = fmaxf(fmaxf(fmaxf(a0.x, a0.y), fmaxf(a0.z, a0.w)),
                             fmaxf(fmaxf(a1.x, a1.y), fmaxf(a1.z, a1.w)));
            mx = fmaxf(mx, fmaxf(fmaxf(fmaxf(a2.x, a2.y), fmaxf(a2.z, a2.w)),
                                 fmaxf(fmaxf(a3.x, a3.y), fmaxf(a3.z, a3.w))));
            a0.x = __expf(a0.x - mx); a0.y = __expf(a0.y - mx);
            a0.z = __expf(a0.z - mx); a0.w = __expf(a0.w - mx);
            a1.x = __expf(a1.x - mx); a1.y = __expf(a1.y - mx);
            a1.z = __expf(a1.z - mx); a1.w = __expf(a1.w - mx);
            a2.x = __expf(a2.x - mx); a2.y = __expf(a2.y - mx);
            a2.z = __expf(a2.z - mx); a2.w = __expf(a2.w - mx);
            a3.x = __expf(a3.x - mx); a3.y = __expf(a3.y - mx);
            a3.z = __expf(a3.z - mx); a3.w = __expf(a3.w - mx);
            const float sum = ((a0.x + a0.y) + (a0.z + a0.w))
                            + ((a1.x + a1.y) + (a1.z + a1.w))
                            + ((a2.x + a2.y) + (a2.z + a2.w))
                            + ((a3.x + a3.y) + (a3.z + a3.w));
            const float inv = 1.f / sum;
            a0.x *= inv; a0.y *= inv; a0.z *= inv; a0.w *= inv;
            a1.x *= inv; a1.y *= inv; a1.z *= inv; a1.w *= inv;
            a2.x *= inv; a2.y *= inv; a2.z *= inv; a2.w *= inv;
            a3.x *= inv; a3.y *= inv; a3.z *= inv; a3.w *= inv;
            *(float4*)(p)      = a0; *(float4*)(p + 4)  = a1;
            *(float4*)(p + 8)  = a2; *(float4*)(p + 12) = a3;
            if (!(lane & 1)) p[48] = 1.f / (1.f + __expf(-p[48]));
        }
        asm volatile("s_waitcnt lgkmcnt(0)" ::: "memory");

        // ---- two chunks of T=16 per staged buffer ----
#pragma unroll
        for (int t = 0; t < 2; ++t) {
            const float* rb = sb + t * 16 * 52;
            const float* myrow = rb + i4 * 52;
            float ki[16], qi[16];
            {
                const float4 kA = *(const float4*)(myrow + 16);
                const float4 kB = *(const float4*)(myrow + 20);
                const float4 kC = *(const float4*)(myrow + 24);
                const float4 kD = *(const float4*)(myrow + 28);
                ki[0]=kA.x; ki[1]=kA.y; ki[2]=kA.z; ki[3]=kA.w;
                ki[4]=kB.x; ki[5]=kB.y; ki[6]=kB.z; ki[7]=kB.w;
                ki[8]=kC.x; ki[9]=kC.y; ki[10]=kC.z; ki[11]=kC.w;
                ki[12]=kD.x; ki[13]=kD.y; ki[14]=kD.z; ki[15]=kD.w;
                const float4 qA = *(const float4*)(myrow);
                const float4 qB = *(const float4*)(myrow + 4);
                const float4 qC = *(const float4*)(myrow + 8);
                const float4 qD = *(const float4*)(myrow + 12);
                qi[0]=qA.x; qi[1]=qA.y; qi[2]=qA.z; qi[3]=qA.w;
                qi[4]=qB.x; qi[5]=qB.y; qi[6]=qB.z; qi[7]=qB.w;
                qi[8]=qC.x; qi[9]=qC.y; qi[10]=qC.z; qi[11]=qC.w;
                qi[12]=qD.x; qi[13]=qD.y; qi[14]=qD.z; qi[15]=qD.w;
            }
            const float beta = myrow[48];
            // G/QK coefficients, kept in registers:
            //  gcf[m] = -beta*(k_i4 . k_s), s=jq*4+m, zero for s>=i4
            //  qkc[m] =        (q_i4 . k_s),            zero for s> i4
            float gcf[4], qkc[4];
#pragma unroll
            for (int m = 0; m < 4; ++m) {
                const int s = jq * 4 + m;
                const float* sr = rb + s * 52 + 16;
                const float4 s0 = *(const float4*)(sr);
                const float4 s1 = *(const float4*)(sr + 4);
                const float4 s2 = *(const float4*)(sr + 8);
                const float4 s3 = *(const float4*)(sr + 12);
                float g, qk;
                DOT16(g, ki, s0, s1, s2, s3);
                DOT16(qk, qi, s0, s1, s2, s3);
                gcf[m] = (s < i4)  ? -beta * g : 0.f;
                qkc[m] = (s <= i4) ? qk : 0.f;
            }
            // P = W0^T k_i, O1 = W0^T q_i
            float P0=0,P1=0,P2=0,P3=0, O0=0,O1=0,O2=0,O3=0;
#pragma unroll
            for (int x = 0; x < 16; ++x) {
                const float4 w = *(const float4*)&W0l[x * 20 + jq * 4];
                P0 = fmaf(ki[x], w.x, P0); P1 = fmaf(ki[x], w.y, P1);
                P2 = fmaf(ki[x], w.z, P2); P3 = fmaf(ki[x], w.w, P3);
                O0 = fmaf(qi[x], w.x, O0); O1 = fmaf(qi[x], w.y, O1);
                O2 = fmaf(qi[x], w.z, O2); O3 = fmaf(qi[x], w.w, O3);
            }
            // e = beta*(v - P)
            const float4 vv = *(const float4*)(myrow + 32 + jq * 4);
            float d0 = beta * (vv.x - P0), d1 = beta * (vv.y - P1);
            float d2 = beta * (vv.z - P2), d3 = beta * (vv.w - P3);
            // forward substitution: 15 rounds, coefficients via shfl (no LDS)
#pragma unroll
            for (int s = 0; s < 15; ++s) {
                const float cf = __shfl(gcf[s & 3], i4 * 4 + (s >> 2));
                const float e0 = __shfl(d0, s * 4 + jq);
                const float e1 = __shfl(d1, s * 4 + jq);
                const float e2 = __shfl(d2, s * 4 + jq);
                const float e3 = __shfl(d3, s * 4 + jq);
                d0 = fmaf(cf, e0, d0); d1 = fmaf(cf, e1, d1);
                d2 = fmaf(cf, e2, d2); d3 = fmaf(cf, e3, d3);
            }
            // publish DV
            f32x4 dvv; dvv[0]=d0; dvv[1]=d1; dvv[2]=d2; dvv[3]=d3;
            *(f32x4*)&DVl[i4 * 20 + jq * 4] = dvv;
            asm volatile("s_waitcnt lgkmcnt(0)" ::: "memory");
            // merged: O += tril(QK) DV  and  dW = K^T DV  (shared DV reads)
            float a0=0,a1=0,a2=0,a3=0;
#pragma unroll
            for (int s = 0; s < 16; ++s) {
                const float4 dvs = *(const float4*)&DVl[s * 20 + jq * 4];
                if (s < 15 || true) {
                    const float c = (s == 15)
                        ? ((15 <= i4) ? qkc[3] * 0.f + __shfl(qkc[3], i4 * 4 + 3) * ((i4 == 15) ? 1.f : 0.f) + ((15 < i4) ? 0.f : 0.f) : 0.f)
                        : 0.f;
                    (void)c;
                }
                const float cqk = __shfl(qkc[s & 3], i4 * 4 + (s >> 2));
                O0 = fmaf(cqk, dvs.x, O0); O1 = fmaf(cqk, dvs.y, O1);
                O2 = fmaf(cqk, dvs.z, O2); O3 = fmaf(cqk, dvs.w, O3);
                const float kx = rb[s * 52 + 16 + i4];
                a0 = fmaf(kx, dvs.x, a0); a1 = fmaf(kx, dvs.y, a1);
                a2 = fmaf(kx, dvs.z, a2); a3 = fmaf(kx, dvs.w, a3);
            }
            // store o (bf16, layout (s, b, h*16+j))
            {
                const int sg = nb * 32 + t * 16 + i4;
                alignas(8) bf16 tb[4];
                tb[0] = __float2bfloat16(O0); tb[1] = __float2bfloat16(O1);
                tb[2] = __float2bfloat16(O2); tb[3] = __float2bfloat16(O3);
                *(ushort4*)((unsigned short*)(po + (long)sg * (B_SZ * HID))) =
                    *(const ushort4*)tb;
            }
            // W0 += dW
            {
                float4 w = *(const float4*)&W0l[i4 * 20 + jq * 4];
                w.x += a0; w.y += a1; w.z += a2; w.w += a3;
                *(float4*)&W0l[i4 * 20 + jq * 4] = w;
            }
            asm volatile("s_waitcnt lgkmcnt(0)" ::: "memory");
        }
    }
}

// ---------------------------------------------------------------------------
extern "C" void kernel_launch(void* const* d_in, const int* in_sizes, int n_in,
                              void* d_out, int out_size, void* d_ws, size_t ws_size,
                              hipStream_t stream)
{
    const float* x      = (const float*)d_in[0];
    const int*   fb     = (const int*)  d_in[1];
    const float* fc1_w  = (const float*)d_in[2];
    const float* fc1_b  = (const float*)d_in[3];
    const float* emb    = (const float*)d_in[4];
    const float* proj_w = (const float*)d_in[5];
    const float* proj_b = (const float*)d_in[6];
    const float* ln1_g  = (const float*)d_in[7];
    const float* ln1_b  = (const float*)d_in[8];
    const float* slow_w = (const float*)d_in[9];
    const float* out_w  = (const float*)d_in[10];
    const float* ln2_g  = (const float*)d_in[11];
    const float* ln2_b  = (const float*)d_in[12];
    const float* ff1_w  = (const float*)d_in[13];
    const float* ff1_b  = (const float*)d_in[14];
    const float* ff2_w  = (const float*)d_in[15];
    const float* ff2_b  = (const float*)d_in[16];
    const float* outl_w = (const float*)d_in[17];
    const float* outl_b = (const float*)d_in[18];

    // ---- workspace layout (59.5 MB) ----
    char* wp = (char*)d_ws;
    float* h    = (float*)wp;                 wp += (size_t)MROWS * HID * 4;
    bf16*  abuf = (bf16*)wp;                  wp += (size_t)MROWS * HID * 2;
    bf16*  fc1b = (bf16*)wp;                  wp += (size_t)HID * IN_DIM * 2;
    bf16*  projb= (bf16*)wp;                  wp += (size_t)HID * 288 * 2;
    bf16*  slowb= (bf16*)wp;                  wp += (size_t)NLAYER * 896 * HID * 2;
    bf16*  outwb= (bf16*)wp;                  wp += (size_t)NLAYER * HID * HID * 2;
    bf16*  ff1b = (bf16*)wp;                  wp += (size_t)NLAYER * DFF * HID * 2;
    bf16*  ff2b = (bf16*)wp;                  wp += (size_t)NLAYER * HID * DFF * 2;
    bf16*  outlb= (bf16*)wp;                  wp += (size_t)1664 * HID * 2;

    // ---- d_out scratch (212.9 MB), sequentially reused ----
    bf16*  hcat = (bf16*)d_out;               // 18.9MB, dead after proj
    float* qkvb = (float*)d_out;              // 109.1MB, dead after scan
    bf16*  hff  = (bf16*)d_out;               // 67.1MB, dead after ff2

    const dim3 blk(256);

    // ---- weight conversions ----
    cvt8<<<dim3(384),  blk, 0, stream>>>(fc1_w, fc1b, (long)HID * IN_DIM / 8);
    cvtpad<<<dim3(288), blk, 0, stream>>>(proj_w, projb, HID, HID + EMB_D, HID, 288);
    cvtpad_slow<<<dim3(896, 4), blk, 0, stream>>>(slow_w, slowb);
    cvt8<<<dim3(128), blk, 0, stream>>>(out_w, outwb, (long)NLAYER * HID * HID / 8);
    cvt8<<<dim3(512), blk, 0, stream>>>(ff1_w, ff1b, (long)NLAYER * DFF * HID / 8);
    cvt8<<<dim3(512), blk, 0, stream>>>(ff2_w, ff2b, (long)NLAYER * HID * DFF / 8);
    cvtpad<<<dim3(1664), blk, 0, stream>>>(outl_w, outlb, NCLS, HID, 1664, HID);

    // fc1 (fused fp32-A conversion): abuf = bf16(x @ fc1_w^T + b)
    fc1_k<<<dim3(256, 2), blk, 0, stream>>>(x, fc1b, fc1_b, abuf);
    // hcat = [abuf, emb[fb], 0-pad]  (K padded to 288)
    concat_b<<<dim3(MROWS), dim3(64), 0, stream>>>(abuf, emb, fb, hcat);
    // proj: h = hcat @ proj_w^T + b        N=256 K=288
    mgemm<1><<<dim3(256, 2), blk, 0, stream>>>(hcat, projb, proj_b, nullptr, h,
                                               HID, 288, 288);

    for (int l = 0; l < NLAYER; ++l) {
        ln_b<<<dim3(MROWS / 4), blk, 0, stream>>>(h, ln1_g + l * HID, ln1_b + l * HID, abuf);
        // qkvb (permuted (b,h,s,52) fp32, RAW — softmax fused into scan9)
        mgemm<16><<<dim3(256, 7), blk, 0, stream>>>(abuf, slowb + (size_t)l * 896 * HID,
                                                    nullptr, nullptr, qkvb, 784, HID, HID);
        scan9<<<dim3(B_SZ * NHEAD), dim3(64), 0, stream>>>(qkvb, abuf);
        // h += o @ out_w^T                  N=256 K=256
        mgemm<4><<<dim3(256, 2), blk, 0, stream>>>(abuf, outwb + (size_t)l * HID * HID,
                                                   nullptr, h, h, HID, HID, HID);
        ln_b<<<dim3(MROWS / 4), blk, 0, stream>>>(h, ln2_g + l * HID, ln2_b + l * HID, abuf);
        // hff = bf16(relu(y @ ff1^T + b1))  N=1024 K=256
        mgemm<11><<<dim3(256, 8), blk, 0, stream>>>(abuf, ff1b + (size_t)l * DFF * HID,
                                                    ff1_b + l * DFF, nullptr, hff,
                                                    DFF, HID, HID);
        // h += hff @ ff2^T + b2             N=256 K=1024
        mgemm<5><<<dim3(256, 2), blk, 0, stream>>>(hff, ff2b + (size_t)l * HID * DFF,
                                                   ff2_b + l * HID, h, h, HID, DFF, DFF);
    }
    // final: abuf = bf16(h); out = abuf @ outl_w^T + b  (fp32, N=1623 K=256)
    cvt8<<<dim3(1024), blk, 0, stream>>>(h, abuf, (long)MROWS * HID / 8);
    mgemm<1><<<dim3(256, 13), blk, 0, stream>>>(abuf, outlb, outl_b, nullptr, d_out,
                                                NCLS, HID, HID);
}

// Round 13
// 1626.032 us; speedup vs baseline: 1.6047x; 1.0238x over previous
//
#include <hip/hip_runtime.h>
#include <hip/hip_bf16.h>

// Problem constants
#define S_LEN  1024
#define B_SZ   32
#define IN_DIM 3072
#define HID    256
#define NHEAD  16
#define HDIM   16
#define DFF    1024
#define NLAYER 4
#define NCLS   1623
#define EMB_D  10
#define MROWS  (S_LEN * B_SZ)   // 32768
#define QSTRIDE 52               // per-step qkvb stride (16B aligned rows)

using bf16   = __hip_bfloat16;
using short8 = __attribute__((ext_vector_type(8))) short;
using f32x4  = __attribute__((ext_vector_type(4))) float;

#define GLOAD16(g, l) __builtin_amdgcn_global_load_lds(                        \
    (const __attribute__((address_space(1))) void*)(g),                        \
    (__attribute__((address_space(3))) void*)(l), 16, 0, 0)

// ---------------------------------------------------------------------------
// bf16 MFMA GEMM: C[M,N] = A[M,K]@W[N,K]^T.  BM=BN=128, BK=32, 256 thr/4 waves.
// FLAGS: 1 bias, 2 relu, 8 bf16-out, 16 permuted qkvb store (fp32 (b,h,s,52)).
// Used for qkvb (16), ff1 (11), outl (1).
// ---------------------------------------------------------------------------
template<int FLAGS>
__global__ __launch_bounds__(256) void mgemm(
    const bf16* __restrict__ A, const bf16* __restrict__ W,
    const float* __restrict__ bias, void* C, int N, int K, int Wld)
{
    __shared__ bf16 sA[2][128 * 32];
    __shared__ bf16 sB[2][128 * 32];
    const int t    = threadIdx.x;
    const int lane = t & 63;
    const int wid  = t >> 6;
    const int wr   = wid >> 1, wc = wid & 1;
    const long bm  = (long)blockIdx.x * 128;
    const int  bn  = blockIdx.y * 128;
    const int  fr  = lane & 15;
    const int  fg  = lane >> 4;
    const int  row0 = t >> 2;
    const int  kq0  = (t & 3) << 3;

    f32x4 acc[4][4];
#pragma unroll
    for (int m = 0; m < 4; ++m)
#pragma unroll
        for (int n = 0; n < 4; ++n)
#pragma unroll
            for (int r = 0; r < 4; ++r) acc[m][n][r] = 0.f;

    const int nkt = K >> 5;

    auto stage = [&](int buf, int kt) {
        const int k0 = kt << 5;
        GLOAD16(A + (bm + row0)      * (long)K   + k0 + kq0, &sA[buf][(t      ) * 8]);
        GLOAD16(A + (bm + row0 + 64) * (long)K   + k0 + kq0, &sA[buf][(t + 256) * 8]);
        GLOAD16(W + (long)(bn + row0)      * Wld + k0 + kq0, &sB[buf][(t      ) * 8]);
        GLOAD16(W + (long)(bn + row0 + 64) * Wld + k0 + kq0, &sB[buf][(t + 256) * 8]);
    };

    stage(0, 0);
    __syncthreads();
    for (int kt = 0; kt < nkt; ++kt) {
        const int cur = kt & 1;
        if (kt + 1 < nkt) stage(cur ^ 1, kt + 1);
        short8 af[4], bg[4];
#pragma unroll
        for (int m = 0; m < 4; ++m)
            af[m] = *(const short8*)&sA[cur][(wr * 64 + m * 16 + fr) * 32 + fg * 8];
#pragma unroll
        for (int n = 0; n < 4; ++n)
            bg[n] = *(const short8*)&sB[cur][(wc * 64 + n * 16 + fr) * 32 + fg * 8];
#pragma unroll
        for (int m = 0; m < 4; ++m)
#pragma unroll
            for (int n = 0; n < 4; ++n)
                acc[m][n] = __builtin_amdgcn_mfma_f32_16x16x32_bf16(
                    af[m], bg[n], acc[m][n], 0, 0, 0);
        __syncthreads();
    }

    float bs[4];
#pragma unroll
    for (int n = 0; n < 4; ++n) {
        const int c = bn + wc * 64 + n * 16 + fr;
        bs[n] = ((FLAGS & 1) && c < N) ? bias[c] : 0.f;
    }
#pragma unroll
    for (int m = 0; m < 4; ++m) {
#pragma unroll
        for (int n = 0; n < 4; ++n) {
            const int c = bn + wc * 64 + n * 16 + fr;
            if (c < N) {
#pragma unroll
                for (int r = 0; r < 4; ++r) {
                    const long rw = bm + wr * 64 + m * 16 + fg * 4 + r;
                    float v = acc[m][n][r] + bs[n];
                    if (FLAGS & 2) v = fmaxf(v, 0.f);
                    if (FLAGS & 16) {
                        const int s = (int)(rw >> 5), b = (int)(rw & 31);
                        const int hh = c / 49, cc = c - hh * 49;
                        ((float*)C)[((long)(b * 16 + hh) * 1024 + s) * QSTRIDE + cc] = v;
                    } else if (FLAGS & 8) {
                        ((bf16*)C)[rw * N + c] = __float2bfloat16(v);
                    } else {
                        ((float*)C)[rw * N + c] = v;
                    }
                }
            }
        }
    }
}

// ---------------------------------------------------------------------------
// gemm_ln: C = A[M,K]@W[256,K]^T (+bias)(+residual via H), writes H (fp32) and
// Y (bf16) where Y = LayerNorm(row)(g,b) unless FLAGS&8 (plain bf16).
// BM=64, BN=256 (full rows in one block) -> LN in epilogue.
// FLAGS: 1 bias, 4 residual (H += ), 8 plain bf16 out (no LN).
// ---------------------------------------------------------------------------
template<int FLAGS>
__global__ __launch_bounds__(256) void gemm_ln(
    const bf16* __restrict__ A, const bf16* __restrict__ W,
    const float* __restrict__ bias, const float* __restrict__ lg,
    const float* __restrict__ lb, float* H, bf16* __restrict__ Y, int K)
{
    __shared__ bf16 sA[2][64 * 32];
    __shared__ bf16 sB[2][256 * 32];
    __shared__ float rsum[64][4];
    __shared__ float rsq[64][4];
    const int t    = threadIdx.x;
    const int lane = t & 63;
    const int w    = t >> 6;           // wave = N-quadrant
    const int fr   = lane & 15;
    const int fg   = lane >> 4;
    const long bm  = (long)blockIdx.x * 64;

    f32x4 acc[4][4];
#pragma unroll
    for (int m = 0; m < 4; ++m)
#pragma unroll
        for (int n = 0; n < 4; ++n)
#pragma unroll
            for (int r = 0; r < 4; ++r) acc[m][n][r] = 0.f;

    const int nkt = K >> 5;
    auto stage = [&](int buf, int kt) {
        const int k0 = kt << 5;
        GLOAD16(A + (bm + (t >> 2)) * (long)K + k0 + ((t & 3) << 3),
                &sA[buf][t * 8]);
#pragma unroll
        for (int i = 0; i < 4; ++i)
            GLOAD16(W + (long)((i << 6) + (t >> 2)) * K + k0 + ((t & 3) << 3),
                    &sB[buf][(i * 256 + t) * 8]);
    };

    stage(0, 0);
    __syncthreads();
    for (int kt = 0; kt < nkt; ++kt) {
        const int cur = kt & 1;
        if (kt + 1 < nkt) stage(cur ^ 1, kt + 1);
        short8 af[4], bg[4];
#pragma unroll
        for (int m = 0; m < 4; ++m)
            af[m] = *(const short8*)&sA[cur][(m * 16 + fr) * 32 + fg * 8];
#pragma unroll
        for (int n = 0; n < 4; ++n)
            bg[n] = *(const short8*)&sB[cur][(w * 64 + n * 16 + fr) * 32 + fg * 8];
#pragma unroll
        for (int m = 0; m < 4; ++m)
#pragma unroll
            for (int n = 0; n < 4; ++n)
                acc[m][n] = __builtin_amdgcn_mfma_f32_16x16x32_bf16(
                    af[m], bg[n], acc[m][n], 0, 0, 0);
        __syncthreads();
    }

    // ---- epilogue: finalize v, write H, row sums ----
    float bs[4];
#pragma unroll
    for (int n = 0; n < 4; ++n) {
        const int c = w * 64 + n * 16 + fr;
        bs[n] = (FLAGS & 1) ? bias[c] : 0.f;
    }
    float ps[4][4], pq[4][4];
#pragma unroll
    for (int m = 0; m < 4; ++m)
#pragma unroll
        for (int r = 0; r < 4; ++r) { ps[m][r] = 0.f; pq[m][r] = 0.f; }
#pragma unroll
    for (int m = 0; m < 4; ++m)
#pragma unroll
        for (int n = 0; n < 4; ++n)
#pragma unroll
            for (int r = 0; r < 4; ++r) {
                const long rw = bm + m * 16 + fg * 4 + r;
                const int c = w * 64 + n * 16 + fr;
                float v = acc[m][n][r] + bs[n];
                if (FLAGS & 4) v += H[rw * HID + c];
                H[rw * HID + c] = v;
                acc[m][n][r] = v;
                ps[m][r] += v;
                pq[m][r] += v * v;
            }
    if (FLAGS & 8) {
#pragma unroll
        for (int m = 0; m < 4; ++m)
#pragma unroll
            for (int n = 0; n < 4; ++n)
#pragma unroll
                for (int r = 0; r < 4; ++r) {
                    const long rw = bm + m * 16 + fg * 4 + r;
                    const int c = w * 64 + n * 16 + fr;
                    Y[rw * HID + c] = __float2bfloat16(acc[m][n][r]);
                }
    } else {
        // reduce over the 16 fr-lanes of this fg group
#pragma unroll
        for (int m = 0; m < 4; ++m)
#pragma unroll
            for (int r = 0; r < 4; ++r) {
                float s = ps[m][r], q = pq[m][r];
                s += __shfl_xor(s, 1); q += __shfl_xor(q, 1);
                s += __shfl_xor(s, 2); q += __shfl_xor(q, 2);
                s += __shfl_xor(s, 4); q += __shfl_xor(q, 4);
                s += __shfl_xor(s, 8); q += __shfl_xor(q, 8);
                ps[m][r] = s; pq[m][r] = q;
            }
        if (fr == 0) {
#pragma unroll
            for (int m = 0; m < 4; ++m)
#pragma unroll
                for (int r = 0; r < 4; ++r) {
                    const int row = m * 16 + fg * 4 + r;
                    rsum[row][w] = ps[m][r];
                    rsq[row][w]  = pq[m][r];
                }
        }
        __syncthreads();
#pragma unroll
        for (int m = 0; m < 4; ++m)
#pragma unroll
            for (int r = 0; r < 4; ++r) {
                const int row = m * 16 + fg * 4 + r;
                const float4 s4 = *(const float4*)&rsum[row][0];
                const float4 q4 = *(const float4*)&rsq[row][0];
                const float S = (s4.x + s4.y) + (s4.z + s4.w);
                const float Q = (q4.x + q4.y) + (q4.z + q4.w);
                const float mean = S * (1.f / 256.f);
                const float inv  = rsqrtf(Q * (1.f / 256.f) - mean * mean + 1e-5f);
                const long rw = bm + row;
#pragma unroll
                for (int n = 0; n < 4; ++n) {
                    const int c = w * 64 + n * 16 + fr;
                    const float y = (acc[m][n][r] - mean) * inv * lg[c] + lb[c];
                    Y[rw * HID + c] = __float2bfloat16(y);
                }
            }
    }
}

// ---------------------------------------------------------------------------
// fc1 GEMM, fused fp32->bf16 A-staging; epilogue writes DIRECTLY into hcat
// (row stride 288). N=256 fixed, K=3072.
// ---------------------------------------------------------------------------
__global__ __launch_bounds__(256) void fc1_k(
    const float* __restrict__ A, const bf16* __restrict__ W,
    const float* __restrict__ bias, bf16* __restrict__ hcat)
{
    __shared__ bf16 sA[2][128 * 32];
    __shared__ bf16 sB[2][128 * 32];
    const int t    = threadIdx.x;
    const int lane = t & 63;
    const int wid  = t >> 6;
    const int wr   = wid >> 1, wc = wid & 1;
    const long bm  = (long)blockIdx.x * 128;
    const int  bn  = blockIdx.y * 128;
    const int  fr  = lane & 15;
    const int  fg  = lane >> 4;
    const int  row0 = t >> 2;
    const int  kq0  = (t & 3) << 3;
    const int  arow = t >> 3;
    const int  ac4  = (t & 7) << 2;

    f32x4 acc[4][4];
#pragma unroll
    for (int m = 0; m < 4; ++m)
#pragma unroll
        for (int n = 0; n < 4; ++n)
#pragma unroll
            for (int r = 0; r < 4; ++r) acc[m][n][r] = 0.f;

    auto stageB = [&](int buf, int kt) {
        const int k0 = kt << 5;
        GLOAD16(W + (long)(bn + row0)      * IN_DIM + k0 + kq0, &sB[buf][(t      ) * 8]);
        GLOAD16(W + (long)(bn + row0 + 64) * IN_DIM + k0 + kq0, &sB[buf][(t + 256) * 8]);
    };
    float4 va[4];
    auto loadA = [&](int kt) {
        const int k0 = kt << 5;
#pragma unroll
        for (int rep = 0; rep < 4; ++rep)
            va[rep] = *(const float4*)(A + (bm + arow + rep * 32) * (long)IN_DIM + k0 + ac4);
    };
    auto writeA = [&](int buf) {
#pragma unroll
        for (int rep = 0; rep < 4; ++rep) {
            alignas(8) bf16 tb[4];
            tb[0] = __float2bfloat16(va[rep].x);
            tb[1] = __float2bfloat16(va[rep].y);
            tb[2] = __float2bfloat16(va[rep].z);
            tb[3] = __float2bfloat16(va[rep].w);
            *(ushort4*)&sA[buf][(arow + rep * 32) * 32 + ac4] = *(const ushort4*)tb;
        }
    };

    loadA(0);
    stageB(0, 0);
    writeA(0);
    __syncthreads();
    const int nkt = IN_DIM >> 5;   // 96
    for (int kt = 0; kt < nkt; ++kt) {
        const int cur = kt & 1;
        if (kt + 1 < nkt) { stageB(cur ^ 1, kt + 1); loadA(kt + 1); }
        short8 af[4], bg[4];
#pragma unroll
        for (int m = 0; m < 4; ++m)
            af[m] = *(const short8*)&sA[cur][(wr * 64 + m * 16 + fr) * 32 + fg * 8];
#pragma unroll
        for (int n = 0; n < 4; ++n)
            bg[n] = *(const short8*)&sB[cur][(wc * 64 + n * 16 + fr) * 32 + fg * 8];
#pragma unroll
        for (int m = 0; m < 4; ++m)
#pragma unroll
            for (int n = 0; n < 4; ++n)
                acc[m][n] = __builtin_amdgcn_mfma_f32_16x16x32_bf16(
                    af[m], bg[n], acc[m][n], 0, 0, 0);
        if (kt + 1 < nkt) writeA(cur ^ 1);
        __syncthreads();
    }

#pragma unroll
    for (int n = 0; n < 4; ++n) {
        const int c = bn + wc * 64 + n * 16 + fr;
        const float bsn = bias[c];
#pragma unroll
        for (int m = 0; m < 4; ++m)
#pragma unroll
            for (int r = 0; r < 4; ++r) {
                const long rw = bm + wr * 64 + m * 16 + fg * 4 + r;
                hcat[rw * 288 + c] = __float2bfloat16(acc[m][n][r] + bsn);
            }
    }
}

// fill hcat cols 256..287 with bf16(emb[fb]) + zero pad; 8 rows/block
__global__ __launch_bounds__(256) void fillemb(
    const float* __restrict__ emb, const int* __restrict__ fb,
    bf16* __restrict__ hcat)
{
    const long row = (long)blockIdx.x * 8 + (threadIdx.x >> 5);
    const int c = threadIdx.x & 31;
    bf16 v = (c < EMB_D) ? __float2bfloat16(emb[(long)fb[row] * EMB_D + c])
                         : __float2bfloat16(0.f);
    hcat[row * 288 + 256 + c] = v;
}

// ---------------------------------------------------------------------------
// fp32 -> bf16 bulk convert, count divisible by 8.
// ---------------------------------------------------------------------------
__global__ __launch_bounds__(256) void cvt8(const float* __restrict__ s,
                                            bf16* __restrict__ d, long n8)
{
    for (long i = (long)blockIdx.x * 256 + threadIdx.x; i < n8;
         i += (long)gridDim.x * 256) {
        const float4 a = ((const float4*)s)[i * 2];
        const float4 b = ((const float4*)s)[i * 2 + 1];
        alignas(16) bf16 t[8];
        t[0] = __float2bfloat16(a.x); t[1] = __float2bfloat16(a.y);
        t[2] = __float2bfloat16(a.z); t[3] = __float2bfloat16(a.w);
        t[4] = __float2bfloat16(b.x); t[5] = __float2bfloat16(b.y);
        t[6] = __float2bfloat16(b.z); t[7] = __float2bfloat16(b.w);
        ((short8*)d)[i] = *(const short8*)t;
    }
}

// ---------------------------------------------------------------------------
// fp32 [rows][cols] -> bf16 [prows][pcols], zero-padded.
// ---------------------------------------------------------------------------
__global__ __launch_bounds__(256) void cvtpad(const float* __restrict__ s,
                                              bf16* __restrict__ d,
                                              int rows, int cols, int prows, int pcols)
{
    const long tot = (long)prows * pcols;
    for (long i = (long)blockIdx.x * 256 + threadIdx.x; i < tot;
         i += (long)gridDim.x * 256) {
        const int r = (int)(i / pcols), c = (int)(i - (long)r * pcols);
        d[i] = (r < rows && c < cols) ? __float2bfloat16(s[(long)r * cols + c])
                                      : __float2bfloat16(0.f);
    }
}

// slow_w: 4 layers of [784][256] -> [896][256] padded, blockIdx.y = layer
__global__ __launch_bounds__(256) void cvtpad_slow(const float* __restrict__ s,
                                                   bf16* __restrict__ d)
{
    const int l = blockIdx.y;
    const float* src = s + (size_t)l * 784 * HID;
    bf16* dst = d + (size_t)l * 896 * HID;
    const long tot = (long)896 * HID;
    for (long i = (long)blockIdx.x * 256 + threadIdx.x; i < tot;
         i += (long)gridDim.x * 256) {
        const int r = (int)(i / HID), c = (int)(i - (long)r * HID);
        dst[i] = (r < 784) ? __float2bfloat16(src[(long)r * HID + c])
                           : __float2bfloat16(0.f);
    }
}

// 16-dot of register array kr[16] with a row staged as 4 float4s
#define DOT16(dst, kr, s0, s1, s2, s3) do {                                    \
    float _pa = fmaf(kr[3],  (s0).w, fmaf(kr[2],  (s0).z, fmaf(kr[1],  (s0).y, kr[0]  * (s0).x))); \
    float _pb = fmaf(kr[7],  (s1).w, fmaf(kr[6],  (s1).z, fmaf(kr[5],  (s1).y, kr[4]  * (s1).x))); \
    float _pc = fmaf(kr[11], (s2).w, fmaf(kr[10], (s2).z, fmaf(kr[9],  (s2).y, kr[8]  * (s2).x))); \
    float _pd = fmaf(kr[15], (s3).w, fmaf(kr[14], (s3).z, fmaf(kr[13], (s3).y, kr[12] * (s3).x))); \
    dst = (_pa + _pb) + (_pc + _pd);                                           \
} while (0)

// ---------------------------------------------------------------------------
// Delta-rule scan v9 (cleaned): WY chunked (T=16), coefficients in registers
// distributed via shfl, merged O2+dW loop sharing DV reads.
// ---------------------------------------------------------------------------
__global__ __launch_bounds__(64) void scan9(
    const float* __restrict__ qkvb, bf16* __restrict__ o)
{
    __shared__ float sbuf[2][1792];
    __shared__ float W0l[16 * 20];
    __shared__ float DVl[16 * 20];
    const int lane = threadIdx.x;
    const int i4 = lane >> 2;
    const int jq = lane & 3;
    const int chain = blockIdx.x;
    const int b = chain >> 4, hh = chain & 15;
    const float* cb = qkvb + (long)chain * S_LEN * QSTRIDE;
    bf16* po = o + (long)b * HID + hh * HDIM + jq * 4;

    for (int z = lane; z < 320; z += 64) W0l[z] = 0.f;

    auto stage = [&](int buf, int nb2) {
#pragma unroll
        for (int iss = 0; iss < 7; ++iss) {
            const float* src = cb + (long)nb2 * 1664 + iss * 256 + lane * 4;
            GLOAD16(src, &sbuf[buf][iss * 256 + lane * 4]);
        }
    };

    stage(0, 0);
    asm volatile("s_waitcnt vmcnt(0)" ::: "memory");
    for (int nb = 0; nb < 32; ++nb) {
        const int buf = nb & 1;
        asm volatile("s_waitcnt vmcnt(2)" ::: "memory");
        if (nb + 1 < 32) stage(buf ^ 1, nb + 1);

        float* sb = sbuf[buf];
        // prep: softmax q|k half-row per lane (32 rows), sigmoid beta
        {
            float* p = sb + (lane >> 1) * 52 + ((lane & 1) << 4);
            float4 a0 = *(float4*)(p),     a1 = *(float4*)(p + 4);
            float4 a2 = *(float4*)(p + 8), a3 = *(float4*)(p + 12);
            float mx = fmaxf(fmaxf(fmaxf(a0.x, a0.y), fmaxf(a0.z, a0.w)),
                             fmaxf(fmaxf(a1.x, a1.y), fmaxf(a1.z, a1.w)));
            mx = fmaxf(mx, fmaxf(fmaxf(fmaxf(a2.x, a2.y), fmaxf(a2.z, a2.w)),
                                 fmaxf(fmaxf(a3.x, a3.y), fmaxf(a3.z, a3.w))));
            a0.x = __expf(a0.x - mx); a0.y = __expf(a0.y - mx);
            a0.z = __expf(a0.z - mx); a0.w = __expf(a0.w - mx);
            a1.x = __expf(a1.x - mx); a1.y = __expf(a1.y - mx);
            a1.z = __expf(a1.z - mx); a1.w = __expf(a1.w - mx);
            a2.x = __expf(a2.x - mx); a2.y = __expf(a2.y - mx);
            a2.z = __expf(a2.z - mx); a2.w = __expf(a2.w - mx);
            a3.x = __expf(a3.x - mx); a3.y = __expf(a3.y - mx);
            a3.z = __expf(a3.z - mx); a3.w = __expf(a3.w - mx);
            const float sum = ((a0.x + a0.y) + (a0.z + a0.w))
                            + ((a1.x + a1.y) + (a1.z + a1.w))
                            + ((a2.x + a2.y) + (a2.z + a2.w))
                            + ((a3.x + a3.y) + (a3.z + a3.w));
            const float inv = 1.f / sum;
            a0.x *= inv; a0.y *= inv; a0.z *= inv; a0.w *= inv;
            a1.x *= inv; a1.y *= inv; a1.z *= inv; a1.w *= inv;
            a2.x *= inv; a2.y *= inv; a2.z *= inv; a2.w *= inv;
            a3.x *= inv; a3.y *= inv; a3.z *= inv; a3.w *= inv;
            *(float4*)(p)      = a0; *(float4*)(p + 4)  = a1;
            *(float4*)(p + 8)  = a2; *(float4*)(p + 12) = a3;
            if (!(lane & 1)) p[48] = 1.f / (1.f + __expf(-p[48]));
        }
        asm volatile("s_waitcnt lgkmcnt(0)" ::: "memory");

#pragma unroll
        for (int t = 0; t < 2; ++t) {
            const float* rb = sb + t * 16 * 52;
            const float* myrow = rb + i4 * 52;
            float ki[16], qi[16];
            {
                const float4 kA = *(const float4*)(myrow + 16);
                const float4 kB = *(const float4*)(myrow + 20);
                const float4 kC = *(const float4*)(myrow + 24);
                const float4 kD = *(const float4*)(myrow + 28);
                ki[0]=kA.x; ki[1]=kA.y; ki[2]=kA.z; ki[3]=kA.w;
                ki[4]=kB.x; ki[5]=kB.y; ki[6]=kB.z; ki[7]=kB.w;
                ki[8]=kC.x; ki[9]=kC.y; ki[10]=kC.z; ki[11]=kC.w;
                ki[12]=kD.x; ki[13]=kD.y; ki[14]=kD.z; ki[15]=kD.w;
                const float4 qA = *(const float4*)(myrow);
                const float4 qB = *(const float4*)(myrow + 4);
                const float4 qC = *(const float4*)(myrow + 8);
                const float4 qD = *(const float4*)(myrow + 12);
                qi[0]=qA.x; qi[1]=qA.y; qi[2]=qA.z; qi[3]=qA.w;
                qi[4]=qB.x; qi[5]=qB.y; qi[6]=qB.z; qi[7]=qB.w;
                qi[8]=qC.x; qi[9]=qC.y; qi[10]=qC.z; qi[11]=qC.w;
                qi[12]=qD.x; qi[13]=qD.y; qi[14]=qD.z; qi[15]=qD.w;
            }
            const float beta = myrow[48];
            float gcf[4], qkc[4];
#pragma unroll
            for (int m = 0; m < 4; ++m) {
                const int s = jq * 4 + m;
                const float* sr = rb + s * 52 + 16;
                const float4 s0 = *(const float4*)(sr);
                const float4 s1 = *(const float4*)(sr + 4);
                const float4 s2 = *(const float4*)(sr + 8);
                const float4 s3 = *(const float4*)(sr + 12);
                float g, qk;
                DOT16(g, ki, s0, s1, s2, s3);
                DOT16(qk, qi, s0, s1, s2, s3);
                gcf[m] = (s < i4)  ? -beta * g : 0.f;
                qkc[m] = (s <= i4) ? qk : 0.f;
            }
            float P0=0,P1=0,P2=0,P3=0, O0=0,O1=0,O2=0,O3=0;
#pragma unroll
            for (int x = 0; x < 16; ++x) {
                const float4 w = *(const float4*)&W0l[x * 20 + jq * 4];
                P0 = fmaf(ki[x], w.x, P0); P1 = fmaf(ki[x], w.y, P1);
                P2 = fmaf(ki[x], w.z, P2); P3 = fmaf(ki[x], w.w, P3);
                O0 = fmaf(qi[x], w.x, O0); O1 = fmaf(qi[x], w.y, O1);
                O2 = fmaf(qi[x], w.z, O2); O3 = fmaf(qi[x], w.w, O3);
            }
            const float4 vv = *(const float4*)(myrow + 32 + jq * 4);
            float d0 = beta * (vv.x - P0), d1 = beta * (vv.y - P1);
            float d2 = beta * (vv.z - P2), d3 = beta * (vv.w - P3);
#pragma unroll
            for (int s = 0; s < 15; ++s) {
                const float cf = __shfl(gcf[s & 3], i4 * 4 + (s >> 2));
                const float e0 = __shfl(d0, s * 4 + jq);
                const float e1 = __shfl(d1, s * 4 + jq);
                const float e2 = __shfl(d2, s * 4 + jq);
                const float e3 = __shfl(d3, s * 4 + jq);
                d0 = fmaf(cf, e0, d0); d1 = fmaf(cf, e1, d1);
                d2 = fmaf(cf, e2, d2); d3 = fmaf(cf, e3, d3);
            }
            f32x4 dvv; dvv[0]=d0; dvv[1]=d1; dvv[2]=d2; dvv[3]=d3;
            *(f32x4*)&DVl[i4 * 20 + jq * 4] = dvv;
            asm volatile("s_waitcnt lgkmcnt(0)" ::: "memory");
            float a0=0,a1=0,a2=0,a3=0;
#pragma unroll
            for (int s = 0; s < 16; ++s) {
                const float4 dvs = *(const float4*)&DVl[s * 20 + jq * 4];
                const float cqk = __shfl(qkc[s & 3], i4 * 4 + (s >> 2));
                O0 = fmaf(cqk, dvs.x, O0); O1 = fmaf(cqk, dvs.y, O1);
                O2 = fmaf(cqk, dvs.z, O2); O3 = fmaf(cqk, dvs.w, O3);
                const float kx = rb[s * 52 + 16 + i4];
                a0 = fmaf(kx, dvs.x, a0); a1 = fmaf(kx, dvs.y, a1);
                a2 = fmaf(kx, dvs.z, a2); a3 = fmaf(kx, dvs.w, a3);
            }
            {
                const int sg = nb * 32 + t * 16 + i4;
                alignas(8) bf16 tb[4];
                tb[0] = __float2bfloat16(O0); tb[1] = __float2bfloat16(O1);
                tb[2] = __float2bfloat16(O2); tb[3] = __float2bfloat16(O3);
                *(ushort4*)((unsigned short*)(po + (long)sg * (B_SZ * HID))) =
                    *(const ushort4*)tb;
            }
            {
                float4 w = *(const float4*)&W0l[i4 * 20 + jq * 4];
                w.x += a0; w.y += a1; w.z += a2; w.w += a3;
                *(float4*)&W0l[i4 * 20 + jq * 4] = w;
            }
            asm volatile("s_waitcnt lgkmcnt(0)" ::: "memory");
        }
    }
}

// ---------------------------------------------------------------------------
extern "C" void kernel_launch(void* const* d_in, const int* in_sizes, int n_in,
                              void* d_out, int out_size, void* d_ws, size_t ws_size,
                              hipStream_t stream)
{
    const float* x      = (const float*)d_in[0];
    const int*   fb     = (const int*)  d_in[1];
    const float* fc1_w  = (const float*)d_in[2];
    const float* fc1_b  = (const float*)d_in[3];
    const float* emb    = (const float*)d_in[4];
    const float* proj_w = (const float*)d_in[5];
    const float* proj_b = (const float*)d_in[6];
    const float* ln1_g  = (const float*)d_in[7];
    const float* ln1_b  = (const float*)d_in[8];
    const float* slow_w = (const float*)d_in[9];
    const float* out_w  = (const float*)d_in[10];
    const float* ln2_g  = (const float*)d_in[11];
    const float* ln2_b  = (const float*)d_in[12];
    const float* ff1_w  = (const float*)d_in[13];
    const float* ff1_b  = (const float*)d_in[14];
    const float* ff2_w  = (const float*)d_in[15];
    const float* ff2_b  = (const float*)d_in[16];
    const float* outl_w = (const float*)d_in[17];
    const float* outl_b = (const float*)d_in[18];

    // ---- workspace layout ----
    char* wp = (char*)d_ws;
    float* h    = (float*)wp;                 wp += (size_t)MROWS * HID * 4;
    bf16*  abuf = (bf16*)wp;                  wp += (size_t)MROWS * HID * 2;
    bf16*  fc1b = (bf16*)wp;                  wp += (size_t)HID * IN_DIM * 2;
    bf16*  projb= (bf16*)wp;                  wp += (size_t)HID * 288 * 2;
    bf16*  slowb= (bf16*)wp;                  wp += (size_t)NLAYER * 896 * HID * 2;
    bf16*  outwb= (bf16*)wp;                  wp += (size_t)NLAYER * HID * HID * 2;
    bf16*  ff1b = (bf16*)wp;                  wp += (size_t)NLAYER * DFF * HID * 2;
    bf16*  ff2b = (bf16*)wp;                  wp += (size_t)NLAYER * HID * DFF * 2;
    bf16*  outlb= (bf16*)wp;                  wp += (size_t)1664 * HID * 2;

    // ---- d_out scratch, sequentially reused ----
    bf16*  hcat = (bf16*)d_out;               // 18.9MB, dead after proj
    float* qkvb = (float*)d_out;              // 109.1MB, dead after scan
    bf16*  hff  = (bf16*)d_out;               // 67.1MB, dead after ff2

    const dim3 blk(256);

    // ---- weight conversions ----
    cvt8<<<dim3(384),  blk, 0, stream>>>(fc1_w, fc1b, (long)HID * IN_DIM / 8);
    cvtpad<<<dim3(288), blk, 0, stream>>>(proj_w, projb, HID, HID + EMB_D, HID, 288);
    cvtpad_slow<<<dim3(896, 4), blk, 0, stream>>>(slow_w, slowb);
    cvt8<<<dim3(128), blk, 0, stream>>>(out_w, outwb, (long)NLAYER * HID * HID / 8);
    cvt8<<<dim3(512), blk, 0, stream>>>(ff1_w, ff1b, (long)NLAYER * DFF * HID / 8);
    cvt8<<<dim3(512), blk, 0, stream>>>(ff2_w, ff2b, (long)NLAYER * HID * DFF / 8);
    cvtpad<<<dim3(1664), blk, 0, stream>>>(outl_w, outlb, NCLS, HID, 1664, HID);

    // fc1 writes directly into hcat (cols 0..255); fillemb fills 256..287
    fc1_k<<<dim3(256, 2), blk, 0, stream>>>(x, fc1b, fc1_b, hcat);
    fillemb<<<dim3(MROWS / 8), blk, 0, stream>>>(emb, fb, hcat);
    // proj + fused LN1_0: h = hcat@proj^T + b; abuf = LN(h)
    gemm_ln<1><<<dim3(512), blk, 0, stream>>>(hcat, projb, proj_b,
                                              ln1_g, ln1_b, h, abuf, 288);

    for (int l = 0; l < NLAYER; ++l) {
        // qkvb (permuted (b,h,s,52) fp32, RAW — softmax fused into scan9)
        mgemm<16><<<dim3(256, 7), blk, 0, stream>>>(abuf, slowb + (size_t)l * 896 * HID,
                                                    nullptr, qkvb, 784, HID, HID);
        scan9<<<dim3(B_SZ * NHEAD), dim3(64), 0, stream>>>(qkvb, abuf);
        // out-GEMM + residual + fused LN2: h += o@out^T; abuf = LN2(h)
        gemm_ln<4><<<dim3(512), blk, 0, stream>>>(abuf, outwb + (size_t)l * HID * HID,
                                                  nullptr, ln2_g + l * HID,
                                                  ln2_b + l * HID, h, abuf, HID);
        // hff = bf16(relu(abuf @ ff1^T + b1))  N=1024 K=256
        mgemm<11><<<dim3(256, 8), blk, 0, stream>>>(abuf, ff1b + (size_t)l * DFF * HID,
                                                    ff1_b + l * DFF, hff, DFF, HID, HID);
        // ff2 + residual + bias; abuf = LN1_{l+1}(h) or plain bf16(h) on last
        if (l + 1 < NLAYER)
            gemm_ln<5><<<dim3(512), blk, 0, stream>>>(hff, ff2b + (size_t)l * HID * DFF,
                                                      ff2_b + l * HID,
                                                      ln1_g + (l + 1) * HID,
                                                      ln1_b + (l + 1) * HID, h, abuf, DFF);
        else
            gemm_ln<13><<<dim3(512), blk, 0, stream>>>(hff, ff2b + (size_t)l * HID * DFF,
                                                       ff2_b + l * HID,
                                                       nullptr, nullptr, h, abuf, DFF);
    }
    // final: out = abuf @ outl_w^T + b  (fp32, N=1623 K=256)
    mgemm<1><<<dim3(256, 13), blk, 0, stream>>>(abuf, outlb, outl_b, d_out,
                                                NCLS, HID, HID);
}

// Round 14
// 1620.451 us; speedup vs baseline: 1.6102x; 1.0034x over previous
//
#include <hip/hip_runtime.h>
#include <hip/hip_bf16.h>

// Problem constants
#define S_LEN  1024
#define B_SZ   32
#define IN_DIM 3072
#define HID    256
#define NHEAD  16
#define HDIM   16
#define DFF    1024
#define NLAYER 4
#define NCLS   1623
#define EMB_D  10
#define MROWS  (S_LEN * B_SZ)   // 32768
#define QROW   56                // bf16 elems per qkvb row (112 B, 16B-aligned)

using bf16   = __hip_bfloat16;
using short8 = __attribute__((ext_vector_type(8))) short;
using f32x4  = __attribute__((ext_vector_type(4))) float;

#define GLOAD16(g, l) __builtin_amdgcn_global_load_lds(                        \
    (const __attribute__((address_space(1))) void*)(g),                        \
    (__attribute__((address_space(3))) void*)(l), 16, 0, 0)

__device__ __forceinline__ float b2f(short s) {
    union { float f; unsigned u; } x;
    x.u = ((unsigned)(unsigned short)s) << 16;
    return x.f;
}

// ---------------------------------------------------------------------------
// bf16 MFMA GEMM: C[M,N] = A[M,K]@W[N,K]^T.  BM=BN=128, BK=32, 256 thr/4 waves.
// FLAGS: 1 bias, 2 relu, 8 bf16-out, 16 permuted bf16 qkvb store (sigmoid on
// col 48 of each 49-group). Used for qkvb (16), ff1 (11), outl (1).
// ---------------------------------------------------------------------------
template<int FLAGS>
__global__ __launch_bounds__(256) void mgemm(
    const bf16* __restrict__ A, const bf16* __restrict__ W,
    const float* __restrict__ bias, void* C, int N, int K, int Wld)
{
    __shared__ bf16 sA[2][128 * 32];
    __shared__ bf16 sB[2][128 * 32];
    const int t    = threadIdx.x;
    const int lane = t & 63;
    const int wid  = t >> 6;
    const int wr   = wid >> 1, wc = wid & 1;
    const long bm  = (long)blockIdx.x * 128;
    const int  bn  = blockIdx.y * 128;
    const int  fr  = lane & 15;
    const int  fg  = lane >> 4;
    const int  row0 = t >> 2;
    const int  kq0  = (t & 3) << 3;

    f32x4 acc[4][4];
#pragma unroll
    for (int m = 0; m < 4; ++m)
#pragma unroll
        for (int n = 0; n < 4; ++n)
#pragma unroll
            for (int r = 0; r < 4; ++r) acc[m][n][r] = 0.f;

    const int nkt = K >> 5;

    auto stage = [&](int buf, int kt) {
        const int k0 = kt << 5;
        GLOAD16(A + (bm + row0)      * (long)K   + k0 + kq0, &sA[buf][(t      ) * 8]);
        GLOAD16(A + (bm + row0 + 64) * (long)K   + k0 + kq0, &sA[buf][(t + 256) * 8]);
        GLOAD16(W + (long)(bn + row0)      * Wld + k0 + kq0, &sB[buf][(t      ) * 8]);
        GLOAD16(W + (long)(bn + row0 + 64) * Wld + k0 + kq0, &sB[buf][(t + 256) * 8]);
    };

    stage(0, 0);
    __syncthreads();
    for (int kt = 0; kt < nkt; ++kt) {
        const int cur = kt & 1;
        if (kt + 1 < nkt) stage(cur ^ 1, kt + 1);
        short8 af[4], bg[4];
#pragma unroll
        for (int m = 0; m < 4; ++m)
            af[m] = *(const short8*)&sA[cur][(wr * 64 + m * 16 + fr) * 32 + fg * 8];
#pragma unroll
        for (int n = 0; n < 4; ++n)
            bg[n] = *(const short8*)&sB[cur][(wc * 64 + n * 16 + fr) * 32 + fg * 8];
#pragma unroll
        for (int m = 0; m < 4; ++m)
#pragma unroll
            for (int n = 0; n < 4; ++n)
                acc[m][n] = __builtin_amdgcn_mfma_f32_16x16x32_bf16(
                    af[m], bg[n], acc[m][n], 0, 0, 0);
        __syncthreads();
    }

    float bs[4];
#pragma unroll
    for (int n = 0; n < 4; ++n) {
        const int c = bn + wc * 64 + n * 16 + fr;
        bs[n] = ((FLAGS & 1) && c < N) ? bias[c] : 0.f;
    }
#pragma unroll
    for (int m = 0; m < 4; ++m) {
#pragma unroll
        for (int n = 0; n < 4; ++n) {
            const int c = bn + wc * 64 + n * 16 + fr;
            if (c < N) {
#pragma unroll
                for (int r = 0; r < 4; ++r) {
                    const long rw = bm + wr * 64 + m * 16 + fg * 4 + r;
                    float v = acc[m][n][r] + bs[n];
                    if (FLAGS & 2) v = fmaxf(v, 0.f);
                    if (FLAGS & 16) {
                        const int s = (int)(rw >> 5), b = (int)(rw & 31);
                        const int hh = c / 49, cc = c - hh * 49;
                        if (cc == 48) v = 1.f / (1.f + __expf(-v));   // sigmoid(beta)
                        ((bf16*)C)[((long)(b * 16 + hh) * 1024 + s) * QROW + cc] =
                            __float2bfloat16(v);
                    } else if (FLAGS & 8) {
                        ((bf16*)C)[rw * N + c] = __float2bfloat16(v);
                    } else {
                        ((float*)C)[rw * N + c] = v;
                    }
                }
            }
        }
    }
}

// ---------------------------------------------------------------------------
// gemm_ln: C = A[M,K]@W[256,K]^T (+bias)(+residual via H), writes H (fp32) and
// Y (bf16) where Y = LayerNorm(row)(g,b) unless FLAGS&8 (plain bf16).
// BM=64, BN=256 (full rows in one block) -> LN in epilogue.
// FLAGS: 1 bias, 4 residual (H += ), 8 plain bf16 out (no LN).
// ---------------------------------------------------------------------------
template<int FLAGS>
__global__ __launch_bounds__(256) void gemm_ln(
    const bf16* __restrict__ A, const bf16* __restrict__ W,
    const float* __restrict__ bias, const float* __restrict__ lg,
    const float* __restrict__ lb, float* H, bf16* __restrict__ Y, int K)
{
    __shared__ bf16 sA[2][64 * 32];
    __shared__ bf16 sB[2][256 * 32];
    __shared__ float rsum[64][4];
    __shared__ float rsq[64][4];
    const int t    = threadIdx.x;
    const int lane = t & 63;
    const int w    = t >> 6;
    const int fr   = lane & 15;
    const int fg   = lane >> 4;
    const long bm  = (long)blockIdx.x * 64;

    f32x4 acc[4][4];
#pragma unroll
    for (int m = 0; m < 4; ++m)
#pragma unroll
        for (int n = 0; n < 4; ++n)
#pragma unroll
            for (int r = 0; r < 4; ++r) acc[m][n][r] = 0.f;

    const int nkt = K >> 5;
    auto stage = [&](int buf, int kt) {
        const int k0 = kt << 5;
        GLOAD16(A + (bm + (t >> 2)) * (long)K + k0 + ((t & 3) << 3),
                &sA[buf][t * 8]);
#pragma unroll
        for (int i = 0; i < 4; ++i)
            GLOAD16(W + (long)((i << 6) + (t >> 2)) * K + k0 + ((t & 3) << 3),
                    &sB[buf][(i * 256 + t) * 8]);
    };

    stage(0, 0);
    __syncthreads();
    for (int kt = 0; kt < nkt; ++kt) {
        const int cur = kt & 1;
        if (kt + 1 < nkt) stage(cur ^ 1, kt + 1);
        short8 af[4], bg[4];
#pragma unroll
        for (int m = 0; m < 4; ++m)
            af[m] = *(const short8*)&sA[cur][(m * 16 + fr) * 32 + fg * 8];
#pragma unroll
        for (int n = 0; n < 4; ++n)
            bg[n] = *(const short8*)&sB[cur][(w * 64 + n * 16 + fr) * 32 + fg * 8];
#pragma unroll
        for (int m = 0; m < 4; ++m)
#pragma unroll
            for (int n = 0; n < 4; ++n)
                acc[m][n] = __builtin_amdgcn_mfma_f32_16x16x32_bf16(
                    af[m], bg[n], acc[m][n], 0, 0, 0);
        __syncthreads();
    }

    float bs[4];
#pragma unroll
    for (int n = 0; n < 4; ++n) {
        const int c = w * 64 + n * 16 + fr;
        bs[n] = (FLAGS & 1) ? bias[c] : 0.f;
    }
    float ps[4][4], pq[4][4];
#pragma unroll
    for (int m = 0; m < 4; ++m)
#pragma unroll
        for (int r = 0; r < 4; ++r) { ps[m][r] = 0.f; pq[m][r] = 0.f; }
#pragma unroll
    for (int m = 0; m < 4; ++m)
#pragma unroll
        for (int n = 0; n < 4; ++n)
#pragma unroll
            for (int r = 0; r < 4; ++r) {
                const long rw = bm + m * 16 + fg * 4 + r;
                const int c = w * 64 + n * 16 + fr;
                float v = acc[m][n][r] + bs[n];
                if (FLAGS & 4) v += H[rw * HID + c];
                H[rw * HID + c] = v;
                acc[m][n][r] = v;
                ps[m][r] += v;
                pq[m][r] += v * v;
            }
    if (FLAGS & 8) {
#pragma unroll
        for (int m = 0; m < 4; ++m)
#pragma unroll
            for (int n = 0; n < 4; ++n)
#pragma unroll
                for (int r = 0; r < 4; ++r) {
                    const long rw = bm + m * 16 + fg * 4 + r;
                    const int c = w * 64 + n * 16 + fr;
                    Y[rw * HID + c] = __float2bfloat16(acc[m][n][r]);
                }
    } else {
#pragma unroll
        for (int m = 0; m < 4; ++m)
#pragma unroll
            for (int r = 0; r < 4; ++r) {
                float s = ps[m][r], q = pq[m][r];
                s += __shfl_xor(s, 1); q += __shfl_xor(q, 1);
                s += __shfl_xor(s, 2); q += __shfl_xor(q, 2);
                s += __shfl_xor(s, 4); q += __shfl_xor(q, 4);
                s += __shfl_xor(s, 8); q += __shfl_xor(q, 8);
                ps[m][r] = s; pq[m][r] = q;
            }
        if (fr == 0) {
#pragma unroll
            for (int m = 0; m < 4; ++m)
#pragma unroll
                for (int r = 0; r < 4; ++r) {
                    const int row = m * 16 + fg * 4 + r;
                    rsum[row][w] = ps[m][r];
                    rsq[row][w]  = pq[m][r];
                }
        }
        __syncthreads();
#pragma unroll
        for (int m = 0; m < 4; ++m)
#pragma unroll
            for (int r = 0; r < 4; ++r) {
                const int row = m * 16 + fg * 4 + r;
                const float4 s4 = *(const float4*)&rsum[row][0];
                const float4 q4 = *(const float4*)&rsq[row][0];
                const float S = (s4.x + s4.y) + (s4.z + s4.w);
                const float Q = (q4.x + q4.y) + (q4.z + q4.w);
                const float mean = S * (1.f / 256.f);
                const float inv  = rsqrtf(Q * (1.f / 256.f) - mean * mean + 1e-5f);
                const long rw = bm + row;
#pragma unroll
                for (int n = 0; n < 4; ++n) {
                    const int c = w * 64 + n * 16 + fr;
                    const float y = (acc[m][n][r] - mean) * inv * lg[c] + lb[c];
                    Y[rw * HID + c] = __float2bfloat16(y);
                }
            }
    }
}

// ---------------------------------------------------------------------------
// fc1 GEMM, fused fp32->bf16 A-staging; epilogue writes DIRECTLY into hcat
// (row stride 288). N=256 fixed, K=3072.
// ---------------------------------------------------------------------------
__global__ __launch_bounds__(256) void fc1_k(
    const float* __restrict__ A, const bf16* __restrict__ W,
    const float* __restrict__ bias, bf16* __restrict__ hcat)
{
    __shared__ bf16 sA[2][128 * 32];
    __shared__ bf16 sB[2][128 * 32];
    const int t    = threadIdx.x;
    const int lane = t & 63;
    const int wid  = t >> 6;
    const int wr   = wid >> 1, wc = wid & 1;
    const long bm  = (long)blockIdx.x * 128;
    const int  bn  = blockIdx.y * 128;
    const int  fr  = lane & 15;
    const int  fg  = lane >> 4;
    const int  row0 = t >> 2;
    const int  kq0  = (t & 3) << 3;
    const int  arow = t >> 3;
    const int  ac4  = (t & 7) << 2;

    f32x4 acc[4][4];
#pragma unroll
    for (int m = 0; m < 4; ++m)
#pragma unroll
        for (int n = 0; n < 4; ++n)
#pragma unroll
            for (int r = 0; r < 4; ++r) acc[m][n][r] = 0.f;

    auto stageB = [&](int buf, int kt) {
        const int k0 = kt << 5;
        GLOAD16(W + (long)(bn + row0)      * IN_DIM + k0 + kq0, &sB[buf][(t      ) * 8]);
        GLOAD16(W + (long)(bn + row0 + 64) * IN_DIM + k0 + kq0, &sB[buf][(t + 256) * 8]);
    };
    float4 va[4];
    auto loadA = [&](int kt) {
        const int k0 = kt << 5;
#pragma unroll
        for (int rep = 0; rep < 4; ++rep)
            va[rep] = *(const float4*)(A + (bm + arow + rep * 32) * (long)IN_DIM + k0 + ac4);
    };
    auto writeA = [&](int buf) {
#pragma unroll
        for (int rep = 0; rep < 4; ++rep) {
            alignas(8) bf16 tb[4];
            tb[0] = __float2bfloat16(va[rep].x);
            tb[1] = __float2bfloat16(va[rep].y);
            tb[2] = __float2bfloat16(va[rep].z);
            tb[3] = __float2bfloat16(va[rep].w);
            *(ushort4*)&sA[buf][(arow + rep * 32) * 32 + ac4] = *(const ushort4*)tb;
        }
    };

    loadA(0);
    stageB(0, 0);
    writeA(0);
    __syncthreads();
    const int nkt = IN_DIM >> 5;   // 96
    for (int kt = 0; kt < nkt; ++kt) {
        const int cur = kt & 1;
        if (kt + 1 < nkt) { stageB(cur ^ 1, kt + 1); loadA(kt + 1); }
        short8 af[4], bg[4];
#pragma unroll
        for (int m = 0; m < 4; ++m)
            af[m] = *(const short8*)&sA[cur][(wr * 64 + m * 16 + fr) * 32 + fg * 8];
#pragma unroll
        for (int n = 0; n < 4; ++n)
            bg[n] = *(const short8*)&sB[cur][(wc * 64 + n * 16 + fr) * 32 + fg * 8];
#pragma unroll
        for (int m = 0; m < 4; ++m)
#pragma unroll
            for (int n = 0; n < 4; ++n)
                acc[m][n] = __builtin_amdgcn_mfma_f32_16x16x32_bf16(
                    af[m], bg[n], acc[m][n], 0, 0, 0);
        if (kt + 1 < nkt) writeA(cur ^ 1);
        __syncthreads();
    }

#pragma unroll
    for (int n = 0; n < 4; ++n) {
        const int c = bn + wc * 64 + n * 16 + fr;
        const float bsn = bias[c];
#pragma unroll
        for (int m = 0; m < 4; ++m)
#pragma unroll
            for (int r = 0; r < 4; ++r) {
                const long rw = bm + wr * 64 + m * 16 + fg * 4 + r;
                hcat[rw * 288 + c] = __float2bfloat16(acc[m][n][r] + bsn);
            }
    }
}

// fill hcat cols 256..287 with bf16(emb[fb]) + zero pad; 8 rows/block
__global__ __launch_bounds__(256) void fillemb(
    const float* __restrict__ emb, const int* __restrict__ fb,
    bf16* __restrict__ hcat)
{
    const long row = (long)blockIdx.x * 8 + (threadIdx.x >> 5);
    const int c = threadIdx.x & 31;
    bf16 v = (c < EMB_D) ? __float2bfloat16(emb[(long)fb[row] * EMB_D + c])
                         : __float2bfloat16(0.f);
    hcat[row * 288 + 256 + c] = v;
}

// ---------------------------------------------------------------------------
// cvtall: all weight conversions in ONE kernel. Destinations are contiguous
// in ws starting at fc1b. Compile-time region table (cumulative dst offsets):
//   fc1b    786432 copy        [0,       786432)
//   projb   73728  pad 266->288 [786432,  860160)
//   slowb   917504 row-pad 784->896, 4 layers [860160, 1777664)
//   outwb   262144 copy        [1777664, 2039808)
//   ff1b    1048576 copy       [2039808, 3088384)
//   ff2b    1048576 copy       [3088384, 4136960)
//   outlb   425984 row-pad 1623->1664 [4136960, 4562944)
// ---------------------------------------------------------------------------
__global__ __launch_bounds__(256) void cvtall(
    const float* __restrict__ fc1_w, const float* __restrict__ proj_w,
    const float* __restrict__ slow_w, const float* __restrict__ out_w,
    const float* __restrict__ ff1_w, const float* __restrict__ ff2_w,
    const float* __restrict__ outl_w, bf16* __restrict__ dst)
{
    for (long i = (long)blockIdx.x * 256 + threadIdx.x; i < 4562944L;
         i += (long)gridDim.x * 256) {
        float v;
        if (i < 786432L) {
            v = fc1_w[i];
        } else if (i < 860160L) {
            const long j = i - 786432L;
            const int r = (int)(j / 288), c = (int)(j - (long)r * 288);
            v = (c < 266) ? proj_w[(long)r * 266 + c] : 0.f;
        } else if (i < 1777664L) {
            const long j = i - 860160L;
            const int l = (int)(j / 229376);
            const long m = j - (long)l * 229376;
            const int r = (int)(m >> 8), c = (int)(m & 255);
            v = (r < 784) ? slow_w[(long)l * 200704 + (long)r * 256 + c] : 0.f;
        } else if (i < 2039808L) {
            v = out_w[i - 1777664L];
        } else if (i < 3088384L) {
            v = ff1_w[i - 2039808L];
        } else if (i < 4136960L) {
            v = ff2_w[i - 3088384L];
        } else {
            const long j = i - 4136960L;
            const int r = (int)(j >> 8), c = (int)(j & 255);
            v = (r < 1623) ? outl_w[(long)r * 256 + c] : 0.f;
        }
        dst[i] = __float2bfloat16(v);
    }
}

// 16-dot of register array kr[16] with a row staged as 4 float4s
#define DOT16(dst, kr, s0, s1, s2, s3) do {                                    \
    float _pa = fmaf(kr[3],  (s0).w, fmaf(kr[2],  (s0).z, fmaf(kr[1],  (s0).y, kr[0]  * (s0).x))); \
    float _pb = fmaf(kr[7],  (s1).w, fmaf(kr[6],  (s1).z, fmaf(kr[5],  (s1).y, kr[4]  * (s1).x))); \
    float _pc = fmaf(kr[11], (s2).w, fmaf(kr[10], (s2).z, fmaf(kr[9],  (s2).y, kr[8]  * (s2).x))); \
    float _pd = fmaf(kr[15], (s3).w, fmaf(kr[14], (s3).z, fmaf(kr[13], (s3).y, kr[12] * (s3).x))); \
    dst = (_pa + _pb) + (_pc + _pd);                                           \
} while (0)

// ---------------------------------------------------------------------------
// Delta-rule scan v10: WY chunked (T=16), same chunk math as v9, but qkvb is
// now bf16 rows of QROW=56 (112B). Staging: 4 x global_load_lds per 32-step
// buffer (was 7); prep converts bf16 -> fp32 into a 52-stride working region
// (softmax q,k; v cvt; beta cvt — sigmoid pre-applied in mgemm<16>).
// ---------------------------------------------------------------------------
__global__ __launch_bounds__(64) void scan10(
    const bf16* __restrict__ qkvb, bf16* __restrict__ o)
{
    __shared__ short sbf[2][2048];       // staged bf16: 32 rows x 56 (+pad) = 4KB/buf
    __shared__ float wrk[32 * 52];       // fp32 working rows (both chunks of buffer)
    __shared__ float W0l[16 * 20];
    __shared__ float DVl[16 * 20];
    const int lane = threadIdx.x;
    const int i4 = lane >> 2;
    const int jq = lane & 3;
    const int chain = blockIdx.x;
    const int b = chain >> 4, hh = chain & 15;
    const char* cbb = (const char*)(qkvb + (long)chain * S_LEN * QROW);
    bf16* po = o + (long)b * HID + hh * HDIM + jq * 4;

    for (int z = lane; z < 320; z += 64) W0l[z] = 0.f;

    // stage one 32-step buffer: 4 issues x 64 lanes x 16B (3584B data + pad)
    auto stage = [&](int buf, int nb2) {
#pragma unroll
        for (int iss = 0; iss < 4; ++iss) {
            const char* src = cbb + (long)nb2 * 3584 + (iss * 64 + lane) * 16;
            GLOAD16(src, &sbf[buf][(iss * 64 + lane) * 8]);
        }
    };

    stage(0, 0);
    asm volatile("s_waitcnt vmcnt(0)" ::: "memory");
    for (int nb = 0; nb < 32; ++nb) {
        const int buf = nb & 1;
        // retire this buffer's 4 loads (oldest); <=2 newest o-stores may remain
        asm volatile("s_waitcnt vmcnt(2)" ::: "memory");
        if (nb + 1 < 32) stage(buf ^ 1, nb + 1);

        // ---- prep: cvt + softmax(q|k half-row per lane), v cvt, beta cvt ----
        {
            const int row = lane >> 1, hf = lane & 1;
            const short* ps = &sbf[buf][row * QROW + hf * 16];
            const short8 r0 = *(const short8*)(ps);
            const short8 r1 = *(const short8*)(ps + 8);
            float f[16];
#pragma unroll
            for (int j = 0; j < 8; ++j) { f[j] = b2f(r0[j]); f[8 + j] = b2f(r1[j]); }
            float mx = f[0];
#pragma unroll
            for (int j = 1; j < 16; ++j) mx = fmaxf(mx, f[j]);
            float sum = 0.f;
#pragma unroll
            for (int j = 0; j < 16; ++j) { f[j] = __expf(f[j] - mx); sum += f[j]; }
            const float inv = 1.f / sum;
            float* pw = wrk + row * 52 + hf * 16;
#pragma unroll
            for (int j = 0; j < 16; ++j) pw[j] = f[j] * inv;
            // v: 8 vals per lane
            const short8 rv = *(const short8*)(&sbf[buf][row * QROW + 32 + hf * 8]);
            float* pv = wrk + row * 52 + 32 + hf * 8;
#pragma unroll
            for (int j = 0; j < 8; ++j) pv[j] = b2f(rv[j]);
            // beta (already sigmoided): one lane per row
            if (hf == 0)
                wrk[row * 52 + 48] = b2f(sbf[buf][row * QROW + 48]);
        }
        asm volatile("s_waitcnt lgkmcnt(0)" ::: "memory");

        // ---- two chunks of T=16 per staged buffer (identical to scan9) ----
#pragma unroll
        for (int t = 0; t < 2; ++t) {
            const float* rb = wrk + t * 16 * 52;
            const float* myrow = rb + i4 * 52;
            float ki[16], qi[16];
            {
                const float4 kA = *(const float4*)(myrow + 16);
                const float4 kB = *(const float4*)(myrow + 20);
                const float4 kC = *(const float4*)(myrow + 24);
                const float4 kD = *(const float4*)(myrow + 28);
                ki[0]=kA.x; ki[1]=kA.y; ki[2]=kA.z; ki[3]=kA.w;
                ki[4]=kB.x; ki[5]=kB.y; ki[6]=kB.z; ki[7]=kB.w;
                ki[8]=kC.x; ki[9]=kC.y; ki[10]=kC.z; ki[11]=kC.w;
                ki[12]=kD.x; ki[13]=kD.y; ki[14]=kD.z; ki[15]=kD.w;
                const float4 qA = *(const float4*)(myrow);
                const float4 qB = *(const float4*)(myrow + 4);
                const float4 qC = *(const float4*)(myrow + 8);
                const float4 qD = *(const float4*)(myrow + 12);
                qi[0]=qA.x; qi[1]=qA.y; qi[2]=qA.z; qi[3]=qA.w;
                qi[4]=qB.x; qi[5]=qB.y; qi[6]=qB.z; qi[7]=qB.w;
                qi[8]=qC.x; qi[9]=qC.y; qi[10]=qC.z; qi[11]=qC.w;
                qi[12]=qD.x; qi[13]=qD.y; qi[14]=qD.z; qi[15]=qD.w;
            }
            const float beta = myrow[48];
            float gcf[4], qkc[4];
#pragma unroll
            for (int m = 0; m < 4; ++m) {
                const int s = jq * 4 + m;
                const float* sr = rb + s * 52 + 16;
                const float4 s0 = *(const float4*)(sr);
                const float4 s1 = *(const float4*)(sr + 4);
                const float4 s2 = *(const float4*)(sr + 8);
                const float4 s3 = *(const float4*)(sr + 12);
                float g, qk;
                DOT16(g, ki, s0, s1, s2, s3);
                DOT16(qk, qi, s0, s1, s2, s3);
                gcf[m] = (s < i4)  ? -beta * g : 0.f;
                qkc[m] = (s <= i4) ? qk : 0.f;
            }
            float P0=0,P1=0,P2=0,P3=0, O0=0,O1=0,O2=0,O3=0;
#pragma unroll
            for (int x = 0; x < 16; ++x) {
                const float4 w = *(const float4*)&W0l[x * 20 + jq * 4];
                P0 = fmaf(ki[x], w.x, P0); P1 = fmaf(ki[x], w.y, P1);
                P2 = fmaf(ki[x], w.z, P2); P3 = fmaf(ki[x], w.w, P3);
                O0 = fmaf(qi[x], w.x, O0); O1 = fmaf(qi[x], w.y, O1);
                O2 = fmaf(qi[x], w.z, O2); O3 = fmaf(qi[x], w.w, O3);
            }
            const float4 vv = *(const float4*)(myrow + 32 + jq * 4);
            float d0 = beta * (vv.x - P0), d1 = beta * (vv.y - P1);
            float d2 = beta * (vv.z - P2), d3 = beta * (vv.w - P3);
#pragma unroll
            for (int s = 0; s < 15; ++s) {
                const float cf = __shfl(gcf[s & 3], i4 * 4 + (s >> 2));
                const float e0 = __shfl(d0, s * 4 + jq);
                const float e1 = __shfl(d1, s * 4 + jq);
                const float e2 = __shfl(d2, s * 4 + jq);
                const float e3 = __shfl(d3, s * 4 + jq);
                d0 = fmaf(cf, e0, d0); d1 = fmaf(cf, e1, d1);
                d2 = fmaf(cf, e2, d2); d3 = fmaf(cf, e3, d3);
            }
            f32x4 dvv; dvv[0]=d0; dvv[1]=d1; dvv[2]=d2; dvv[3]=d3;
            *(f32x4*)&DVl[i4 * 20 + jq * 4] = dvv;
            asm volatile("s_waitcnt lgkmcnt(0)" ::: "memory");
            float a0=0,a1=0,a2=0,a3=0;
#pragma unroll
            for (int s = 0; s < 16; ++s) {
                const float4 dvs = *(const float4*)&DVl[s * 20 + jq * 4];
                const float cqk = __shfl(qkc[s & 3], i4 * 4 + (s >> 2));
                O0 = fmaf(cqk, dvs.x, O0); O1 = fmaf(cqk, dvs.y, O1);
                O2 = fmaf(cqk, dvs.z, O2); O3 = fmaf(cqk, dvs.w, O3);
                const float kx = rb[s * 52 + 16 + i4];
                a0 = fmaf(kx, dvs.x, a0); a1 = fmaf(kx, dvs.y, a1);
                a2 = fmaf(kx, dvs.z, a2); a3 = fmaf(kx, dvs.w, a3);
            }
            {
                const int sg = nb * 32 + t * 16 + i4;
                alignas(8) bf16 tb[4];
                tb[0] = __float2bfloat16(O0); tb[1] = __float2bfloat16(O1);
                tb[2] = __float2bfloat16(O2); tb[3] = __float2bfloat16(O3);
                *(ushort4*)((unsigned short*)(po + (long)sg * (B_SZ * HID))) =
                    *(const ushort4*)tb;
            }
            {
                float4 w = *(const float4*)&W0l[i4 * 20 + jq * 4];
                w.x += a0; w.y += a1; w.z += a2; w.w += a3;
                *(float4*)&W0l[i4 * 20 + jq * 4] = w;
            }
            asm volatile("s_waitcnt lgkmcnt(0)" ::: "memory");
        }
    }
}

// ---------------------------------------------------------------------------
extern "C" void kernel_launch(void* const* d_in, const int* in_sizes, int n_in,
                              void* d_out, int out_size, void* d_ws, size_t ws_size,
                              hipStream_t stream)
{
    const float* x      = (const float*)d_in[0];
    const int*   fb     = (const int*)  d_in[1];
    const float* fc1_w  = (const float*)d_in[2];
    const float* fc1_b  = (const float*)d_in[3];
    const float* emb    = (const float*)d_in[4];
    const float* proj_w = (const float*)d_in[5];
    const float* proj_b = (const float*)d_in[6];
    const float* ln1_g  = (const float*)d_in[7];
    const float* ln1_b  = (const float*)d_in[8];
    const float* slow_w = (const float*)d_in[9];
    const float* out_w  = (const float*)d_in[10];
    const float* ln2_g  = (const float*)d_in[11];
    const float* ln2_b  = (const float*)d_in[12];
    const float* ff1_w  = (const float*)d_in[13];
    const float* ff1_b  = (const float*)d_in[14];
    const float* ff2_w  = (const float*)d_in[15];
    const float* ff2_b  = (const float*)d_in[16];
    const float* outl_w = (const float*)d_in[17];
    const float* outl_b = (const float*)d_in[18];

    // ---- workspace layout (bf16 weight buffers CONTIGUOUS from fc1b) ----
    char* wp = (char*)d_ws;
    float* h    = (float*)wp;                 wp += (size_t)MROWS * HID * 4;
    bf16*  abuf = (bf16*)wp;                  wp += (size_t)MROWS * HID * 2;
    bf16*  fc1b = (bf16*)wp;                  wp += (size_t)HID * IN_DIM * 2;
    bf16*  projb= (bf16*)wp;                  wp += (size_t)HID * 288 * 2;
    bf16*  slowb= (bf16*)wp;                  wp += (size_t)NLAYER * 896 * HID * 2;
    bf16*  outwb= (bf16*)wp;                  wp += (size_t)NLAYER * HID * HID * 2;
    bf16*  ff1b = (bf16*)wp;                  wp += (size_t)NLAYER * DFF * HID * 2;
    bf16*  ff2b = (bf16*)wp;                  wp += (size_t)NLAYER * HID * DFF * 2;
    bf16*  outlb= (bf16*)wp;                  wp += (size_t)1664 * HID * 2;

    // ---- d_out scratch, sequentially reused ----
    bf16*  hcat = (bf16*)d_out;               // 18.9MB, dead after proj
    bf16*  qkvb = (bf16*)d_out;               // 58.7MB, dead after scan
    bf16*  hff  = (bf16*)d_out;               // 67.1MB, dead after ff2

    const dim3 blk(256);

    // ---- all weight conversions in one dispatch ----
    cvtall<<<dim3(1024), blk, 0, stream>>>(fc1_w, proj_w, slow_w, out_w,
                                           ff1_w, ff2_w, outl_w, fc1b);

    // fc1 writes directly into hcat (cols 0..255); fillemb fills 256..287
    fc1_k<<<dim3(256, 2), blk, 0, stream>>>(x, fc1b, fc1_b, hcat);
    fillemb<<<dim3(MROWS / 8), blk, 0, stream>>>(emb, fb, hcat);
    // proj + fused LN1_0: h = hcat@proj^T + b; abuf = LN(h)
    gemm_ln<1><<<dim3(512), blk, 0, stream>>>(hcat, projb, proj_b,
                                              ln1_g, ln1_b, h, abuf, 288);

    for (int l = 0; l < NLAYER; ++l) {
        // qkvb (permuted (b,h,s,56) bf16, sigmoid(beta) fused; softmax in scan)
        mgemm<16><<<dim3(256, 7), blk, 0, stream>>>(abuf, slowb + (size_t)l * 896 * HID,
                                                    nullptr, qkvb, 784, HID, HID);
        scan10<<<dim3(B_SZ * NHEAD), dim3(64), 0, stream>>>(qkvb, abuf);
        // out-GEMM + residual + fused LN2: h += o@out^T; abuf = LN2(h)
        gemm_ln<4><<<dim3(512), blk, 0, stream>>>(abuf, outwb + (size_t)l * HID * HID,
                                                  nullptr, ln2_g + l * HID,
                                                  ln2_b + l * HID, h, abuf, HID);
        // hff = bf16(relu(abuf @ ff1^T + b1))  N=1024 K=256
        mgemm<11><<<dim3(256, 8), blk, 0, stream>>>(abuf, ff1b + (size_t)l * DFF * HID,
                                                    ff1_b + l * DFF, hff, DFF, HID, HID);
        // ff2 + residual + bias; abuf = LN1_{l+1}(h) or plain bf16(h) on last
        if (l + 1 < NLAYER)
            gemm_ln<5><<<dim3(512), blk, 0, stream>>>(hff, ff2b + (size_t)l * HID * DFF,
                                                      ff2_b + l * HID,
                                                      ln1_g + (l + 1) * HID,
                                                      ln1_b + (l + 1) * HID, h, abuf, DFF);
        else
            gemm_ln<13><<<dim3(512), blk, 0, stream>>>(hff, ff2b + (size_t)l * HID * DFF,
                                                       ff2_b + l * HID,
                                                       nullptr, nullptr, h, abuf, DFF);
    }
    // final: out = abuf @ outl_w^T + b  (fp32, N=1623 K=256)
    mgemm<1><<<dim3(256, 13), blk, 0, stream>>>(abuf, outlb, outl_b, d_out,
                                                NCLS, HID, HID);
}

// Round 15
// 1571.378 us; speedup vs baseline: 1.6605x; 1.0312x over previous
//
#include <hip/hip_runtime.h>
#include <hip/hip_bf16.h>

// Problem constants
#define S_LEN  1024
#define B_SZ   32
#define IN_DIM 3072
#define HID    256
#define NHEAD  16
#define HDIM   16
#define DFF    1024
#define NLAYER 4
#define NCLS   1623
#define EMB_D  10
#define MROWS  (S_LEN * B_SZ)   // 32768
#define QROW   56                // bf16 elems per qkvb row (112 B, 16B-aligned)

using bf16   = __hip_bfloat16;
using short8 = __attribute__((ext_vector_type(8))) short;
using f32x4  = __attribute__((ext_vector_type(4))) float;

#define GLOAD16(g, l) __builtin_amdgcn_global_load_lds(                        \
    (const __attribute__((address_space(1))) void*)(g),                        \
    (__attribute__((address_space(3))) void*)(l), 16, 0, 0)

__device__ __forceinline__ float b2f(short s) {
    union { float f; unsigned u; } x;
    x.u = ((unsigned)(unsigned short)s) << 16;
    return x.f;
}

// ---------------------------------------------------------------------------
// bf16 MFMA GEMM: C[M,N] = A[M,K]@W[N,K]^T.  BM=BN=128, BK=32, 256 thr/4 waves.
// FLAGS: 1 bias, 2 relu, 8 bf16-out, 16 permuted bf16 qkvb store (sigmoid on
// col 48 of each 49-group). Used for qkvb (16), ff1 (11), outl (1).
// ---------------------------------------------------------------------------
template<int FLAGS>
__global__ __launch_bounds__(256) void mgemm(
    const bf16* __restrict__ A, const bf16* __restrict__ W,
    const float* __restrict__ bias, void* C, int N, int K, int Wld)
{
    __shared__ bf16 sA[2][128 * 32];
    __shared__ bf16 sB[2][128 * 32];
    const int t    = threadIdx.x;
    const int lane = t & 63;
    const int wid  = t >> 6;
    const int wr   = wid >> 1, wc = wid & 1;
    const long bm  = (long)blockIdx.x * 128;
    const int  bn  = blockIdx.y * 128;
    const int  fr  = lane & 15;
    const int  fg  = lane >> 4;
    const int  row0 = t >> 2;
    const int  kq0  = (t & 3) << 3;

    f32x4 acc[4][4];
#pragma unroll
    for (int m = 0; m < 4; ++m)
#pragma unroll
        for (int n = 0; n < 4; ++n)
#pragma unroll
            for (int r = 0; r < 4; ++r) acc[m][n][r] = 0.f;

    const int nkt = K >> 5;

    auto stage = [&](int buf, int kt) {
        const int k0 = kt << 5;
        GLOAD16(A + (bm + row0)      * (long)K   + k0 + kq0, &sA[buf][(t      ) * 8]);
        GLOAD16(A + (bm + row0 + 64) * (long)K   + k0 + kq0, &sA[buf][(t + 256) * 8]);
        GLOAD16(W + (long)(bn + row0)      * Wld + k0 + kq0, &sB[buf][(t      ) * 8]);
        GLOAD16(W + (long)(bn + row0 + 64) * Wld + k0 + kq0, &sB[buf][(t + 256) * 8]);
    };

    stage(0, 0);
    __syncthreads();
    for (int kt = 0; kt < nkt; ++kt) {
        const int cur = kt & 1;
        if (kt + 1 < nkt) stage(cur ^ 1, kt + 1);
        short8 af[4], bg[4];
#pragma unroll
        for (int m = 0; m < 4; ++m)
            af[m] = *(const short8*)&sA[cur][(wr * 64 + m * 16 + fr) * 32 + fg * 8];
#pragma unroll
        for (int n = 0; n < 4; ++n)
            bg[n] = *(const short8*)&sB[cur][(wc * 64 + n * 16 + fr) * 32 + fg * 8];
#pragma unroll
        for (int m = 0; m < 4; ++m)
#pragma unroll
            for (int n = 0; n < 4; ++n)
                acc[m][n] = __builtin_amdgcn_mfma_f32_16x16x32_bf16(
                    af[m], bg[n], acc[m][n], 0, 0, 0);
        __syncthreads();
    }

    float bs[4];
#pragma unroll
    for (int n = 0; n < 4; ++n) {
        const int c = bn + wc * 64 + n * 16 + fr;
        bs[n] = ((FLAGS & 1) && c < N) ? bias[c] : 0.f;
    }
#pragma unroll
    for (int m = 0; m < 4; ++m) {
#pragma unroll
        for (int n = 0; n < 4; ++n) {
            const int c = bn + wc * 64 + n * 16 + fr;
            if (c < N) {
#pragma unroll
                for (int r = 0; r < 4; ++r) {
                    const long rw = bm + wr * 64 + m * 16 + fg * 4 + r;
                    float v = acc[m][n][r] + bs[n];
                    if (FLAGS & 2) v = fmaxf(v, 0.f);
                    if (FLAGS & 16) {
                        const int s = (int)(rw >> 5), b = (int)(rw & 31);
                        const int hh = c / 49, cc = c - hh * 49;
                        if (cc == 48) v = 1.f / (1.f + __expf(-v));   // sigmoid(beta)
                        ((bf16*)C)[((long)(b * 16 + hh) * 1024 + s) * QROW + cc] =
                            __float2bfloat16(v);
                    } else if (FLAGS & 8) {
                        ((bf16*)C)[rw * N + c] = __float2bfloat16(v);
                    } else {
                        ((float*)C)[rw * N + c] = v;
                    }
                }
            }
        }
    }
}

// ---------------------------------------------------------------------------
// gemm_ln: C = A[M,K]@W[256,K]^T (+bias)(+residual via H), writes H (fp32) and
// Y (bf16) where Y = LayerNorm(row)(g,b) unless FLAGS&8 (plain bf16).
// BM=64, BN=256 (full rows in one block) -> LN in epilogue.
// FLAGS: 1 bias, 4 residual (H += ), 8 plain bf16 out (no LN).
// ---------------------------------------------------------------------------
template<int FLAGS>
__global__ __launch_bounds__(256) void gemm_ln(
    const bf16* __restrict__ A, const bf16* __restrict__ W,
    const float* __restrict__ bias, const float* __restrict__ lg,
    const float* __restrict__ lb, float* H, bf16* __restrict__ Y, int K)
{
    __shared__ bf16 sA[2][64 * 32];
    __shared__ bf16 sB[2][256 * 32];
    __shared__ float rsum[64][4];
    __shared__ float rsq[64][4];
    const int t    = threadIdx.x;
    const int lane = t & 63;
    const int w    = t >> 6;
    const int fr   = lane & 15;
    const int fg   = lane >> 4;
    const long bm  = (long)blockIdx.x * 64;

    f32x4 acc[4][4];
#pragma unroll
    for (int m = 0; m < 4; ++m)
#pragma unroll
        for (int n = 0; n < 4; ++n)
#pragma unroll
            for (int r = 0; r < 4; ++r) acc[m][n][r] = 0.f;

    const int nkt = K >> 5;
    auto stage = [&](int buf, int kt) {
        const int k0 = kt << 5;
        GLOAD16(A + (bm + (t >> 2)) * (long)K + k0 + ((t & 3) << 3),
                &sA[buf][t * 8]);
#pragma unroll
        for (int i = 0; i < 4; ++i)
            GLOAD16(W + (long)((i << 6) + (t >> 2)) * K + k0 + ((t & 3) << 3),
                    &sB[buf][(i * 256 + t) * 8]);
    };

    stage(0, 0);
    __syncthreads();
    for (int kt = 0; kt < nkt; ++kt) {
        const int cur = kt & 1;
        if (kt + 1 < nkt) stage(cur ^ 1, kt + 1);
        short8 af[4], bg[4];
#pragma unroll
        for (int m = 0; m < 4; ++m)
            af[m] = *(const short8*)&sA[cur][(m * 16 + fr) * 32 + fg * 8];
#pragma unroll
        for (int n = 0; n < 4; ++n)
            bg[n] = *(const short8*)&sB[cur][(w * 64 + n * 16 + fr) * 32 + fg * 8];
#pragma unroll
        for (int m = 0; m < 4; ++m)
#pragma unroll
            for (int n = 0; n < 4; ++n)
                acc[m][n] = __builtin_amdgcn_mfma_f32_16x16x32_bf16(
                    af[m], bg[n], acc[m][n], 0, 0, 0);
        __syncthreads();
    }

    float bs[4];
#pragma unroll
    for (int n = 0; n < 4; ++n) {
        const int c = w * 64 + n * 16 + fr;
        bs[n] = (FLAGS & 1) ? bias[c] : 0.f;
    }
    float ps[4][4], pq[4][4];
#pragma unroll
    for (int m = 0; m < 4; ++m)
#pragma unroll
        for (int r = 0; r < 4; ++r) { ps[m][r] = 0.f; pq[m][r] = 0.f; }
#pragma unroll
    for (int m = 0; m < 4; ++m)
#pragma unroll
        for (int n = 0; n < 4; ++n)
#pragma unroll
            for (int r = 0; r < 4; ++r) {
                const long rw = bm + m * 16 + fg * 4 + r;
                const int c = w * 64 + n * 16 + fr;
                float v = acc[m][n][r] + bs[n];
                if (FLAGS & 4) v += H[rw * HID + c];
                H[rw * HID + c] = v;
                acc[m][n][r] = v;
                ps[m][r] += v;
                pq[m][r] += v * v;
            }
    if (FLAGS & 8) {
#pragma unroll
        for (int m = 0; m < 4; ++m)
#pragma unroll
            for (int n = 0; n < 4; ++n)
#pragma unroll
                for (int r = 0; r < 4; ++r) {
                    const long rw = bm + m * 16 + fg * 4 + r;
                    const int c = w * 64 + n * 16 + fr;
                    Y[rw * HID + c] = __float2bfloat16(acc[m][n][r]);
                }
    } else {
#pragma unroll
        for (int m = 0; m < 4; ++m)
#pragma unroll
            for (int r = 0; r < 4; ++r) {
                float s = ps[m][r], q = pq[m][r];
                s += __shfl_xor(s, 1); q += __shfl_xor(q, 1);
                s += __shfl_xor(s, 2); q += __shfl_xor(q, 2);
                s += __shfl_xor(s, 4); q += __shfl_xor(q, 4);
                s += __shfl_xor(s, 8); q += __shfl_xor(q, 8);
                ps[m][r] = s; pq[m][r] = q;
            }
        if (fr == 0) {
#pragma unroll
            for (int m = 0; m < 4; ++m)
#pragma unroll
                for (int r = 0; r < 4; ++r) {
                    const int row = m * 16 + fg * 4 + r;
                    rsum[row][w] = ps[m][r];
                    rsq[row][w]  = pq[m][r];
                }
        }
        __syncthreads();
#pragma unroll
        for (int m = 0; m < 4; ++m)
#pragma unroll
            for (int r = 0; r < 4; ++r) {
                const int row = m * 16 + fg * 4 + r;
                const float4 s4 = *(const float4*)&rsum[row][0];
                const float4 q4 = *(const float4*)&rsq[row][0];
                const float S = (s4.x + s4.y) + (s4.z + s4.w);
                const float Q = (q4.x + q4.y) + (q4.z + q4.w);
                const float mean = S * (1.f / 256.f);
                const float inv  = rsqrtf(Q * (1.f / 256.f) - mean * mean + 1e-5f);
                const long rw = bm + row;
#pragma unroll
                for (int n = 0; n < 4; ++n) {
                    const int c = w * 64 + n * 16 + fr;
                    const float y = (acc[m][n][r] - mean) * inv * lg[c] + lb[c];
                    Y[rw * HID + c] = __float2bfloat16(y);
                }
            }
    }
}

// ---------------------------------------------------------------------------
// fc1 GEMM, fused fp32->bf16 A-staging; epilogue writes DIRECTLY into hcat
// (row stride 288). N=256 fixed, K=3072.
// ---------------------------------------------------------------------------
__global__ __launch_bounds__(256) void fc1_k(
    const float* __restrict__ A, const bf16* __restrict__ W,
    const float* __restrict__ bias, bf16* __restrict__ hcat)
{
    __shared__ bf16 sA[2][128 * 32];
    __shared__ bf16 sB[2][128 * 32];
    const int t    = threadIdx.x;
    const int lane = t & 63;
    const int wid  = t >> 6;
    const int wr   = wid >> 1, wc = wid & 1;
    const long bm  = (long)blockIdx.x * 128;
    const int  bn  = blockIdx.y * 128;
    const int  fr  = lane & 15;
    const int  fg  = lane >> 4;
    const int  row0 = t >> 2;
    const int  kq0  = (t & 3) << 3;
    const int  arow = t >> 3;
    const int  ac4  = (t & 7) << 2;

    f32x4 acc[4][4];
#pragma unroll
    for (int m = 0; m < 4; ++m)
#pragma unroll
        for (int n = 0; n < 4; ++n)
#pragma unroll
            for (int r = 0; r < 4; ++r) acc[m][n][r] = 0.f;

    auto stageB = [&](int buf, int kt) {
        const int k0 = kt << 5;
        GLOAD16(W + (long)(bn + row0)      * IN_DIM + k0 + kq0, &sB[buf][(t      ) * 8]);
        GLOAD16(W + (long)(bn + row0 + 64) * IN_DIM + k0 + kq0, &sB[buf][(t + 256) * 8]);
    };
    float4 va[4];
    auto loadA = [&](int kt) {
        const int k0 = kt << 5;
#pragma unroll
        for (int rep = 0; rep < 4; ++rep)
            va[rep] = *(const float4*)(A + (bm + arow + rep * 32) * (long)IN_DIM + k0 + ac4);
    };
    auto writeA = [&](int buf) {
#pragma unroll
        for (int rep = 0; rep < 4; ++rep) {
            alignas(8) bf16 tb[4];
            tb[0] = __float2bfloat16(va[rep].x);
            tb[1] = __float2bfloat16(va[rep].y);
            tb[2] = __float2bfloat16(va[rep].z);
            tb[3] = __float2bfloat16(va[rep].w);
            *(ushort4*)&sA[buf][(arow + rep * 32) * 32 + ac4] = *(const ushort4*)tb;
        }
    };

    loadA(0);
    stageB(0, 0);
    writeA(0);
    __syncthreads();
    const int nkt = IN_DIM >> 5;   // 96
    for (int kt = 0; kt < nkt; ++kt) {
        const int cur = kt & 1;
        if (kt + 1 < nkt) { stageB(cur ^ 1, kt + 1); loadA(kt + 1); }
        short8 af[4], bg[4];
#pragma unroll
        for (int m = 0; m < 4; ++m)
            af[m] = *(const short8*)&sA[cur][(wr * 64 + m * 16 + fr) * 32 + fg * 8];
#pragma unroll
        for (int n = 0; n < 4; ++n)
            bg[n] = *(const short8*)&sB[cur][(wc * 64 + n * 16 + fr) * 32 + fg * 8];
#pragma unroll
        for (int m = 0; m < 4; ++m)
#pragma unroll
            for (int n = 0; n < 4; ++n)
                acc[m][n] = __builtin_amdgcn_mfma_f32_16x16x32_bf16(
                    af[m], bg[n], acc[m][n], 0, 0, 0);
        if (kt + 1 < nkt) writeA(cur ^ 1);
        __syncthreads();
    }

#pragma unroll
    for (int n = 0; n < 4; ++n) {
        const int c = bn + wc * 64 + n * 16 + fr;
        const float bsn = bias[c];
#pragma unroll
        for (int m = 0; m < 4; ++m)
#pragma unroll
            for (int r = 0; r < 4; ++r) {
                const long rw = bm + wr * 64 + m * 16 + fg * 4 + r;
                hcat[rw * 288 + c] = __float2bfloat16(acc[m][n][r] + bsn);
            }
    }
}

// fill hcat cols 256..287 with bf16(emb[fb]) + zero pad; 8 rows/block
__global__ __launch_bounds__(256) void fillemb(
    const float* __restrict__ emb, const int* __restrict__ fb,
    bf16* __restrict__ hcat)
{
    const long row = (long)blockIdx.x * 8 + (threadIdx.x >> 5);
    const int c = threadIdx.x & 31;
    bf16 v = (c < EMB_D) ? __float2bfloat16(emb[(long)fb[row] * EMB_D + c])
                         : __float2bfloat16(0.f);
    hcat[row * 288 + 256 + c] = v;
}

// ---------------------------------------------------------------------------
// cvtall: all weight conversions in ONE kernel (regions as round 13).
// ---------------------------------------------------------------------------
__global__ __launch_bounds__(256) void cvtall(
    const float* __restrict__ fc1_w, const float* __restrict__ proj_w,
    const float* __restrict__ slow_w, const float* __restrict__ out_w,
    const float* __restrict__ ff1_w, const float* __restrict__ ff2_w,
    const float* __restrict__ outl_w, bf16* __restrict__ dst)
{
    for (long i = (long)blockIdx.x * 256 + threadIdx.x; i < 4562944L;
         i += (long)gridDim.x * 256) {
        float v;
        if (i < 786432L) {
            v = fc1_w[i];
        } else if (i < 860160L) {
            const long j = i - 786432L;
            const int r = (int)(j / 288), c = (int)(j - (long)r * 288);
            v = (c < 266) ? proj_w[(long)r * 266 + c] : 0.f;
        } else if (i < 1777664L) {
            const long j = i - 860160L;
            const int l = (int)(j / 229376);
            const long m = j - (long)l * 229376;
            const int r = (int)(m >> 8), c = (int)(m & 255);
            v = (r < 784) ? slow_w[(long)l * 200704 + (long)r * 256 + c] : 0.f;
        } else if (i < 2039808L) {
            v = out_w[i - 1777664L];
        } else if (i < 3088384L) {
            v = ff1_w[i - 2039808L];
        } else if (i < 4136960L) {
            v = ff2_w[i - 3088384L];
        } else {
            const long j = i - 4136960L;
            const int r = (int)(j >> 8), c = (int)(j & 255);
            v = (r < 1623) ? outl_w[(long)r * 256 + c] : 0.f;
        }
        dst[i] = __float2bfloat16(v);
    }
}

// 16-dot of register array kr[16] with a row staged as 4 float4s
#define DOT16(dst, kr, s0, s1, s2, s3) do {                                    \
    float _pa = fmaf(kr[3],  (s0).w, fmaf(kr[2],  (s0).z, fmaf(kr[1],  (s0).y, kr[0]  * (s0).x))); \
    float _pb = fmaf(kr[7],  (s1).w, fmaf(kr[6],  (s1).z, fmaf(kr[5],  (s1).y, kr[4]  * (s1).x))); \
    float _pc = fmaf(kr[11], (s2).w, fmaf(kr[10], (s2).z, fmaf(kr[9],  (s2).y, kr[8]  * (s2).x))); \
    float _pd = fmaf(kr[15], (s3).w, fmaf(kr[14], (s3).z, fmaf(kr[13], (s3).y, kr[12] * (s3).x))); \
    dst = (_pa + _pb) + (_pc + _pd);                                           \
} while (0)

// ---------------------------------------------------------------------------
// coef_k: per-chunk coefficient precompute (one wave per T=16 chunk).
//   L[i][s] = beta_i (k_i . k_s) for s<i (softmaxed k); T = (I+L)^{-1}
//   A1 = tril(QK) @ T   (QK[i][s] = q_i . k_s for s<=i)
//   A2 = K^T @ T
// Solved WITHOUT forming T: A (I+L) = RHS -> backward column recurrence
//   for t=15..1: A[:,s] -= L[t][s] A[:,t] for all s<t (L[t][s]=0 for s>=t).
// Output per chunk: A1,A2 col-major (A[s*16+i]) fp32, 512 floats.
// Massively parallel (32768 waves) -> all serial latency hidden by TLP.
// ---------------------------------------------------------------------------
__global__ __launch_bounds__(256) void coef_k(
    const bf16* __restrict__ qkvb, float* __restrict__ cfb)
{
    __shared__ float wrkc[4][16 * 52];
    __shared__ float Gm[4][16 * 17];
    __shared__ float Mql[4][16 * 17];
    const int tid = threadIdx.x;
    const int w = tid >> 6, lane = tid & 63;
    const int cg = blockIdx.x * 4 + w;          // global chunk id
    const int chain = cg >> 6;
    const int ck = cg & 63;
    const bf16* rows = qkvb + ((long)chain * S_LEN + (long)ck * 16) * QROW;
    float* wk = wrkc[w];
    float* G  = Gm[w];
    float* M  = Mql[w];

    // phase A1: softmax q|k half-row per lane (lanes 0..31), beta copy
    if (lane < 32) {
        const int row = lane >> 1, hf = lane & 1;
        const short* ps = (const short*)(rows + (long)row * QROW) + hf * 16;
        const short8 r0 = *(const short8*)(ps);
        const short8 r1 = *(const short8*)(ps + 8);
        float f[16];
#pragma unroll
        for (int j = 0; j < 8; ++j) { f[j] = b2f(r0[j]); f[8 + j] = b2f(r1[j]); }
        float mx = f[0];
#pragma unroll
        for (int j = 1; j < 16; ++j) mx = fmaxf(mx, f[j]);
        float sum = 0.f;
#pragma unroll
        for (int j = 0; j < 16; ++j) { f[j] = __expf(f[j] - mx); sum += f[j]; }
        const float inv = 1.f / sum;
        float* pw = wk + row * 52 + hf * 16;
#pragma unroll
        for (int j = 0; j < 16; ++j) pw[j] = f[j] * inv;
        if (hf == 0)
            wk[row * 52 + 48] = b2f(((const short*)(rows + (long)row * QROW))[48]);
    }
    asm volatile("s_waitcnt lgkmcnt(0)" ::: "memory");

    // phase A2: G and tril(QK) tables (roles i4 = lane>>2, jq = lane&3)
    const int i4 = lane >> 2, jq = lane & 3;
    {
        const float* myrow = wk + i4 * 52;
        float ki[16], qi[16];
        const float4 kA = *(const float4*)(myrow + 16);
        const float4 kB = *(const float4*)(myrow + 20);
        const float4 kC = *(const float4*)(myrow + 24);
        const float4 kD = *(const float4*)(myrow + 28);
        ki[0]=kA.x; ki[1]=kA.y; ki[2]=kA.z; ki[3]=kA.w;
        ki[4]=kB.x; ki[5]=kB.y; ki[6]=kB.z; ki[7]=kB.w;
        ki[8]=kC.x; ki[9]=kC.y; ki[10]=kC.z; ki[11]=kC.w;
        ki[12]=kD.x; ki[13]=kD.y; ki[14]=kD.z; ki[15]=kD.w;
        const float4 qA = *(const float4*)(myrow);
        const float4 qB = *(const float4*)(myrow + 4);
        const float4 qC = *(const float4*)(myrow + 8);
        const float4 qD = *(const float4*)(myrow + 12);
        qi[0]=qA.x; qi[1]=qA.y; qi[2]=qA.z; qi[3]=qA.w;
        qi[4]=qB.x; qi[5]=qB.y; qi[6]=qB.z; qi[7]=qB.w;
        qi[8]=qC.x; qi[9]=qC.y; qi[10]=qC.z; qi[11]=qC.w;
        qi[12]=qD.x; qi[13]=qD.y; qi[14]=qD.z; qi[15]=qD.w;
        const float beta = myrow[48];
#pragma unroll
        for (int m = 0; m < 4; ++m) {
            const int s = jq * 4 + m;
            const float* sr = wk + s * 52 + 16;
            const float4 s0 = *(const float4*)(sr);
            const float4 s1 = *(const float4*)(sr + 4);
            const float4 s2 = *(const float4*)(sr + 8);
            const float4 s3 = *(const float4*)(sr + 12);
            float g, qk;
            DOT16(g, ki, s0, s1, s2, s3);
            DOT16(qk, qi, s0, s1, s2, s3);
            G[i4 * 17 + s] = (s < i4)  ? beta * g : 0.f;   // L[i][s]
            M[i4 * 17 + s] = (s <= i4) ? qk : 0.f;         // tril(QK)
        }
    }
    asm volatile("s_waitcnt lgkmcnt(0)" ::: "memory");

    // phase B: backward column solve (roles cs = i4, rq = jq; lane = cs*4+rq)
    {
        const int cs = i4, rq = jq;
        float A1r[4], A2r[4];
#pragma unroll
        for (int j = 0; j < 4; ++j)
            A1r[j] = M[(rq * 4 + j) * 17 + cs];
        const float4 kcol = *(const float4*)&wk[cs * 52 + 16 + rq * 4];
        A2r[0] = kcol.x; A2r[1] = kcol.y; A2r[2] = kcol.z; A2r[3] = kcol.w;
#pragma unroll
        for (int t = 15; t >= 1; --t) {
            const float Lc = G[t * 17 + cs];   // 0 for cs >= t
            const float b10 = __shfl(A1r[0], t * 4 + rq);
            const float b11 = __shfl(A1r[1], t * 4 + rq);
            const float b12 = __shfl(A1r[2], t * 4 + rq);
            const float b13 = __shfl(A1r[3], t * 4 + rq);
            const float b20 = __shfl(A2r[0], t * 4 + rq);
            const float b21 = __shfl(A2r[1], t * 4 + rq);
            const float b22 = __shfl(A2r[2], t * 4 + rq);
            const float b23 = __shfl(A2r[3], t * 4 + rq);
            A1r[0] = fmaf(-Lc, b10, A1r[0]); A1r[1] = fmaf(-Lc, b11, A1r[1]);
            A1r[2] = fmaf(-Lc, b12, A1r[2]); A1r[3] = fmaf(-Lc, b13, A1r[3]);
            A2r[0] = fmaf(-Lc, b20, A2r[0]); A2r[1] = fmaf(-Lc, b21, A2r[1]);
            A2r[2] = fmaf(-Lc, b22, A2r[2]); A2r[3] = fmaf(-Lc, b23, A2r[3]);
        }
        float* dst = cfb + (long)cg * 512;
        f32x4 o1; o1[0]=A1r[0]; o1[1]=A1r[1]; o1[2]=A1r[2]; o1[3]=A1r[3];
        f32x4 o2; o2[0]=A2r[0]; o2[1]=A2r[1]; o2[2]=A2r[2]; o2[3]=A2r[3];
        *(f32x4*)(dst + cs * 16 + rq * 4) = o1;          // A1 col-major
        *(f32x4*)(dst + 256 + cs * 16 + rq * 4) = o2;    // A2 col-major
    }
}

// ---------------------------------------------------------------------------
// Delta-rule scan v11: WY chunked with PRECOMPUTED A1/A2 (from coef_k).
// Per chunk serial core: P=W0^T k -> e=beta(v-P) -> publish e (1 drain) ->
// merged loop O += A1[i][s] e_s, dW += A2[i][s] e_s -> W0 RMW (1 drain).
// No substitution rounds, no G/QK dots in the serial chain.
// ---------------------------------------------------------------------------
__global__ __launch_bounds__(64) void scan11(
    const bf16* __restrict__ qkvb, const float* __restrict__ cfb,
    bf16* __restrict__ o)
{
    __shared__ short sbf[2][2048];       // staged bf16 qkvb: 32 rows x 56 +pad
    __shared__ float scf[2][1024];       // staged A1/A2: 2 chunks x 512 f32
    __shared__ float wrk[32 * 52];       // fp32 working rows
    __shared__ float W0l[16 * 20];
    __shared__ float EVl[16 * 20];
    const int lane = threadIdx.x;
    const int i4 = lane >> 2;
    const int jq = lane & 3;
    const int chain = blockIdx.x;
    const int b = chain >> 4, hh = chain & 15;
    const char* cbb = (const char*)(qkvb + (long)chain * S_LEN * QROW);
    bf16* po = o + (long)b * HID + hh * HDIM + jq * 4;

    for (int z = lane; z < 320; z += 64) W0l[z] = 0.f;

    // stage: 4 qkvb loads + 4 coef loads per 32-step buffer
    auto stage = [&](int buf, int nb2) {
#pragma unroll
        for (int iss = 0; iss < 4; ++iss) {
            const char* src = cbb + (long)nb2 * 3584 + (iss * 64 + lane) * 16;
            GLOAD16(src, &sbf[buf][(iss * 64 + lane) * 8]);
        }
        const float* csrc = cfb + ((long)chain * 64 + nb2 * 2) * 512;
#pragma unroll
        for (int iss = 0; iss < 4; ++iss)
            GLOAD16(csrc + (iss * 64 + lane) * 4, &scf[buf][(iss * 64 + lane) * 4]);
    };

    stage(0, 0);
    asm volatile("s_waitcnt vmcnt(0)" ::: "memory");
    for (int nb = 0; nb < 32; ++nb) {
        const int buf = nb & 1;
        // retire this buffer's 8 loads (oldest); <=2 newest o-stores may remain
        asm volatile("s_waitcnt vmcnt(2)" ::: "memory");
        if (nb + 1 < 32) stage(buf ^ 1, nb + 1);

        // ---- prep: cvt + softmax(q|k half-row per lane), v cvt, beta cvt ----
        {
            const int row = lane >> 1, hf = lane & 1;
            const short* ps = &sbf[buf][row * QROW + hf * 16];
            const short8 r0 = *(const short8*)(ps);
            const short8 r1 = *(const short8*)(ps + 8);
            float f[16];
#pragma unroll
            for (int j = 0; j < 8; ++j) { f[j] = b2f(r0[j]); f[8 + j] = b2f(r1[j]); }
            float mx = f[0];
#pragma unroll
            for (int j = 1; j < 16; ++j) mx = fmaxf(mx, f[j]);
            float sum = 0.f;
#pragma unroll
            for (int j = 0; j < 16; ++j) { f[j] = __expf(f[j] - mx); sum += f[j]; }
            const float inv = 1.f / sum;
            float* pw = wrk + row * 52 + hf * 16;
#pragma unroll
            for (int j = 0; j < 16; ++j) pw[j] = f[j] * inv;
            const short8 rv = *(const short8*)(&sbf[buf][row * QROW + 32 + hf * 8]);
            float* pv = wrk + row * 52 + 32 + hf * 8;
#pragma unroll
            for (int j = 0; j < 8; ++j) pv[j] = b2f(rv[j]);
            if (hf == 0)
                wrk[row * 52 + 48] = b2f(sbf[buf][row * QROW + 48]);
        }
        asm volatile("s_waitcnt lgkmcnt(0)" ::: "memory");

        // ---- two chunks of T=16 per staged buffer ----
#pragma unroll
        for (int t = 0; t < 2; ++t) {
            const float* rb = wrk + t * 16 * 52;
            const float* myrow = rb + i4 * 52;
            // coefficient rows (off the critical path; independent of W0/e)
            float QKTr[16], KT2r[16];
#pragma unroll
            for (int s = 0; s < 16; ++s) {
                QKTr[s] = scf[buf][t * 512 + s * 16 + i4];
                KT2r[s] = scf[buf][t * 512 + 256 + s * 16 + i4];
            }
            float ki[16], qi[16];
            {
                const float4 kA = *(const float4*)(myrow + 16);
                const float4 kB = *(const float4*)(myrow + 20);
                const float4 kC = *(const float4*)(myrow + 24);
                const float4 kD = *(const float4*)(myrow + 28);
                ki[0]=kA.x; ki[1]=kA.y; ki[2]=kA.z; ki[3]=kA.w;
                ki[4]=kB.x; ki[5]=kB.y; ki[6]=kB.z; ki[7]=kB.w;
                ki[8]=kC.x; ki[9]=kC.y; ki[10]=kC.z; ki[11]=kC.w;
                ki[12]=kD.x; ki[13]=kD.y; ki[14]=kD.z; ki[15]=kD.w;
                const float4 qA = *(const float4*)(myrow);
                const float4 qB = *(const float4*)(myrow + 4);
                const float4 qC = *(const float4*)(myrow + 8);
                const float4 qD = *(const float4*)(myrow + 12);
                qi[0]=qA.x; qi[1]=qA.y; qi[2]=qA.z; qi[3]=qA.w;
                qi[4]=qB.x; qi[5]=qB.y; qi[6]=qB.z; qi[7]=qB.w;
                qi[8]=qC.x; qi[9]=qC.y; qi[10]=qC.z; qi[11]=qC.w;
                qi[12]=qD.x; qi[13]=qD.y; qi[14]=qD.z; qi[15]=qD.w;
            }
            const float beta = myrow[48];
            // P = W0^T k_i, O1 = W0^T q_i
            float P0=0,P1=0,P2=0,P3=0, O0=0,O1=0,O2=0,O3=0;
#pragma unroll
            for (int x = 0; x < 16; ++x) {
                const float4 w = *(const float4*)&W0l[x * 20 + jq * 4];
                P0 = fmaf(ki[x], w.x, P0); P1 = fmaf(ki[x], w.y, P1);
                P2 = fmaf(ki[x], w.z, P2); P3 = fmaf(ki[x], w.w, P3);
                O0 = fmaf(qi[x], w.x, O0); O1 = fmaf(qi[x], w.y, O1);
                O2 = fmaf(qi[x], w.z, O2); O3 = fmaf(qi[x], w.w, O3);
            }
            // e = beta*(v - P); publish
            const float4 vv = *(const float4*)(myrow + 32 + jq * 4);
            f32x4 ev;
            ev[0] = beta * (vv.x - P0); ev[1] = beta * (vv.y - P1);
            ev[2] = beta * (vv.z - P2); ev[3] = beta * (vv.w - P3);
            *(f32x4*)&EVl[i4 * 20 + jq * 4] = ev;
            asm volatile("s_waitcnt lgkmcnt(0)" ::: "memory");
            // merged: O += A1[i4][s] e_s ; dW += A2[i4][s] e_s
            float a0=0,a1=0,a2=0,a3=0;
#pragma unroll
            for (int s = 0; s < 16; ++s) {
                const float4 es = *(const float4*)&EVl[s * 20 + jq * 4];
                O0 = fmaf(QKTr[s], es.x, O0); O1 = fmaf(QKTr[s], es.y, O1);
                O2 = fmaf(QKTr[s], es.z, O2); O3 = fmaf(QKTr[s], es.w, O3);
                a0 = fmaf(KT2r[s], es.x, a0); a1 = fmaf(KT2r[s], es.y, a1);
                a2 = fmaf(KT2r[s], es.z, a2); a3 = fmaf(KT2r[s], es.w, a3);
            }
            // store o (bf16, layout (s, b, h*16+j))
            {
                const int sg = nb * 32 + t * 16 + i4;
                alignas(8) bf16 tb[4];
                tb[0] = __float2bfloat16(O0); tb[1] = __float2bfloat16(O1);
                tb[2] = __float2bfloat16(O2); tb[3] = __float2bfloat16(O3);
                *(ushort4*)((unsigned short*)(po + (long)sg * (B_SZ * HID))) =
                    *(const ushort4*)tb;
            }
            // W0 += dW
            {
                float4 w = *(const float4*)&W0l[i4 * 20 + jq * 4];
                w.x += a0; w.y += a1; w.z += a2; w.w += a3;
                *(float4*)&W0l[i4 * 20 + jq * 4] = w;
            }
            asm volatile("s_waitcnt lgkmcnt(0)" ::: "memory");
        }
    }
}

// ---------------------------------------------------------------------------
extern "C" void kernel_launch(void* const* d_in, const int* in_sizes, int n_in,
                              void* d_out, int out_size, void* d_ws, size_t ws_size,
                              hipStream_t stream)
{
    const float* x      = (const float*)d_in[0];
    const int*   fb     = (const int*)  d_in[1];
    const float* fc1_w  = (const float*)d_in[2];
    const float* fc1_b  = (const float*)d_in[3];
    const float* emb    = (const float*)d_in[4];
    const float* proj_w = (const float*)d_in[5];
    const float* proj_b = (const float*)d_in[6];
    const float* ln1_g  = (const float*)d_in[7];
    const float* ln1_b  = (const float*)d_in[8];
    const float* slow_w = (const float*)d_in[9];
    const float* out_w  = (const float*)d_in[10];
    const float* ln2_g  = (const float*)d_in[11];
    const float* ln2_b  = (const float*)d_in[12];
    const float* ff1_w  = (const float*)d_in[13];
    const float* ff1_b  = (const float*)d_in[14];
    const float* ff2_w  = (const float*)d_in[15];
    const float* ff2_b  = (const float*)d_in[16];
    const float* outl_w = (const float*)d_in[17];
    const float* outl_b = (const float*)d_in[18];

    // ---- workspace layout (bf16 weight buffers CONTIGUOUS from fc1b) ----
    char* wp = (char*)d_ws;
    float* h    = (float*)wp;                 wp += (size_t)MROWS * HID * 4;
    bf16*  abuf = (bf16*)wp;                  wp += (size_t)MROWS * HID * 2;
    bf16*  fc1b = (bf16*)wp;                  wp += (size_t)HID * IN_DIM * 2;
    bf16*  projb= (bf16*)wp;                  wp += (size_t)HID * 288 * 2;
    bf16*  slowb= (bf16*)wp;                  wp += (size_t)NLAYER * 896 * HID * 2;
    bf16*  outwb= (bf16*)wp;                  wp += (size_t)NLAYER * HID * HID * 2;
    bf16*  ff1b = (bf16*)wp;                  wp += (size_t)NLAYER * DFF * HID * 2;
    bf16*  ff2b = (bf16*)wp;                  wp += (size_t)NLAYER * HID * DFF * 2;
    bf16*  outlb= (bf16*)wp;                  wp += (size_t)1664 * HID * 2;

    // ---- d_out scratch, sequentially reused ----
    bf16*  hcat = (bf16*)d_out;               // 18.9MB, dead after proj
    bf16*  qkvb = (bf16*)d_out;               // 58.7MB, dead after scan
    float* cfb  = (float*)((bf16*)d_out + (size_t)512 * 1024 * QROW); // 64MB coef
    bf16*  hff  = (bf16*)d_out;               // 67.1MB, dead after ff2

    const dim3 blk(256);

    // ---- all weight conversions in one dispatch ----
    cvtall<<<dim3(1024), blk, 0, stream>>>(fc1_w, proj_w, slow_w, out_w,
                                           ff1_w, ff2_w, outl_w, fc1b);

    // fc1 writes directly into hcat (cols 0..255); fillemb fills 256..287
    fc1_k<<<dim3(256, 2), blk, 0, stream>>>(x, fc1b, fc1_b, hcat);
    fillemb<<<dim3(MROWS / 8), blk, 0, stream>>>(emb, fb, hcat);
    // proj + fused LN1_0: h = hcat@proj^T + b; abuf = LN(h)
    gemm_ln<1><<<dim3(512), blk, 0, stream>>>(hcat, projb, proj_b,
                                              ln1_g, ln1_b, h, abuf, 288);

    for (int l = 0; l < NLAYER; ++l) {
        // qkvb (permuted (b,h,s,56) bf16, sigmoid(beta) fused)
        mgemm<16><<<dim3(256, 7), blk, 0, stream>>>(abuf, slowb + (size_t)l * 896 * HID,
                                                    nullptr, qkvb, 784, HID, HID);
        // per-chunk WY coefficients (A1, A2), massively parallel
        coef_k<<<dim3(8192), blk, 0, stream>>>(qkvb, cfb);
        // serial scan with precomputed coefficients
        scan11<<<dim3(B_SZ * NHEAD), dim3(64), 0, stream>>>(qkvb, cfb, abuf);
        // out-GEMM + residual + fused LN2: h += o@out^T; abuf = LN2(h)
        gemm_ln<4><<<dim3(512), blk, 0, stream>>>(abuf, outwb + (size_t)l * HID * HID,
                                                  nullptr, ln2_g + l * HID,
                                                  ln2_b + l * HID, h, abuf, HID);
        // hff = bf16(relu(abuf @ ff1^T + b1))  N=1024 K=256
        mgemm<11><<<dim3(256, 8), blk, 0, stream>>>(abuf, ff1b + (size_t)l * DFF * HID,
                                                    ff1_b + l * DFF, hff, DFF, HID, HID);
        // ff2 + residual + bias; abuf = LN1_{l+1}(h) or plain bf16(h) on last
        if (l + 1 < NLAYER)
            gemm_ln<5><<<dim3(512), blk, 0, stream>>>(hff, ff2b + (size_t)l * HID * DFF,
                                                      ff2_b + l * HID,
                                                      ln1_g + (l + 1) * HID,
                                                      ln1_b + (l + 1) * HID, h, abuf, DFF);
        else
            gemm_ln<13><<<dim3(512), blk, 0, stream>>>(hff, ff2b + (size_t)l * HID * DFF,
                                                       ff2_b + l * HID,
                                                       nullptr, nullptr, h, abuf, DFF);
    }
    // final: out = abuf @ outl_w^T + b  (fp32, N=1623 K=256)
    mgemm<1><<<dim3(256, 13), blk, 0, stream>>>(abuf, outlb, outl_b, d_out,
                                                NCLS, HID, HID);
}

// Round 16
// 1532.601 us; speedup vs baseline: 1.7025x; 1.0253x over previous
//
#include <hip/hip_runtime.h>
#include <hip/hip_bf16.h>

// Problem constants
#define S_LEN  1024
#define B_SZ   32
#define IN_DIM 3072
#define HID    256
#define NHEAD  16
#define HDIM   16
#define DFF    1024
#define NLAYER 4
#define NCLS   1623
#define EMB_D  10
#define MROWS  (S_LEN * B_SZ)   // 32768
#define QROW   56                // bf16 elems per qkvb row (112 B, 16B-aligned)

using bf16   = __hip_bfloat16;
using short8 = __attribute__((ext_vector_type(8))) short;
using f32x4  = __attribute__((ext_vector_type(4))) float;

#define GLOAD16(g, l) __builtin_amdgcn_global_load_lds(                        \
    (const __attribute__((address_space(1))) void*)(g),                        \
    (__attribute__((address_space(3))) void*)(l), 16, 0, 0)

__device__ __forceinline__ float b2f(short s) {
    union { float f; unsigned u; } x;
    x.u = ((unsigned)(unsigned short)s) << 16;
    return x.f;
}

// ---------------------------------------------------------------------------
// bf16 MFMA GEMM: C[M,N] = A[M,K]@W[N,K]^T.  BM=BN=128, BK=32, 256 thr/4 waves.
// FLAGS: 1 bias, 2 relu, 8 bf16-out, 16 permuted bf16 qkvb store (sigmoid on
// col 48 of each 49-group). Used for qkvb (16), ff1 (11), outl (1).
// ---------------------------------------------------------------------------
template<int FLAGS>
__global__ __launch_bounds__(256) void mgemm(
    const bf16* __restrict__ A, const bf16* __restrict__ W,
    const float* __restrict__ bias, void* C, int N, int K, int Wld)
{
    __shared__ bf16 sA[2][128 * 32];
    __shared__ bf16 sB[2][128 * 32];
    const int t    = threadIdx.x;
    const int lane = t & 63;
    const int wid  = t >> 6;
    const int wr   = wid >> 1, wc = wid & 1;
    const long bm  = (long)blockIdx.x * 128;
    const int  bn  = blockIdx.y * 128;
    const int  fr  = lane & 15;
    const int  fg  = lane >> 4;
    const int  row0 = t >> 2;
    const int  kq0  = (t & 3) << 3;

    f32x4 acc[4][4];
#pragma unroll
    for (int m = 0; m < 4; ++m)
#pragma unroll
        for (int n = 0; n < 4; ++n)
#pragma unroll
            for (int r = 0; r < 4; ++r) acc[m][n][r] = 0.f;

    const int nkt = K >> 5;

    auto stage = [&](int buf, int kt) {
        const int k0 = kt << 5;
        GLOAD16(A + (bm + row0)      * (long)K   + k0 + kq0, &sA[buf][(t      ) * 8]);
        GLOAD16(A + (bm + row0 + 64) * (long)K   + k0 + kq0, &sA[buf][(t + 256) * 8]);
        GLOAD16(W + (long)(bn + row0)      * Wld + k0 + kq0, &sB[buf][(t      ) * 8]);
        GLOAD16(W + (long)(bn + row0 + 64) * Wld + k0 + kq0, &sB[buf][(t + 256) * 8]);
    };

    stage(0, 0);
    __syncthreads();
    for (int kt = 0; kt < nkt; ++kt) {
        const int cur = kt & 1;
        if (kt + 1 < nkt) stage(cur ^ 1, kt + 1);
        short8 af[4], bg[4];
#pragma unroll
        for (int m = 0; m < 4; ++m)
            af[m] = *(const short8*)&sA[cur][(wr * 64 + m * 16 + fr) * 32 + fg * 8];
#pragma unroll
        for (int n = 0; n < 4; ++n)
            bg[n] = *(const short8*)&sB[cur][(wc * 64 + n * 16 + fr) * 32 + fg * 8];
#pragma unroll
        for (int m = 0; m < 4; ++m)
#pragma unroll
            for (int n = 0; n < 4; ++n)
                acc[m][n] = __builtin_amdgcn_mfma_f32_16x16x32_bf16(
                    af[m], bg[n], acc[m][n], 0, 0, 0);
        __syncthreads();
    }

    float bs[4];
#pragma unroll
    for (int n = 0; n < 4; ++n) {
        const int c = bn + wc * 64 + n * 16 + fr;
        bs[n] = ((FLAGS & 1) && c < N) ? bias[c] : 0.f;
    }
#pragma unroll
    for (int m = 0; m < 4; ++m) {
#pragma unroll
        for (int n = 0; n < 4; ++n) {
            const int c = bn + wc * 64 + n * 16 + fr;
            if (c < N) {
#pragma unroll
                for (int r = 0; r < 4; ++r) {
                    const long rw = bm + wr * 64 + m * 16 + fg * 4 + r;
                    float v = acc[m][n][r] + bs[n];
                    if (FLAGS & 2) v = fmaxf(v, 0.f);
                    if (FLAGS & 16) {
                        const int s = (int)(rw >> 5), b = (int)(rw & 31);
                        const int hh = c / 49, cc = c - hh * 49;
                        if (cc == 48) v = 1.f / (1.f + __expf(-v));   // sigmoid(beta)
                        ((bf16*)C)[((long)(b * 16 + hh) * 1024 + s) * QROW + cc] =
                            __float2bfloat16(v);
                    } else if (FLAGS & 8) {
                        ((bf16*)C)[rw * N + c] = __float2bfloat16(v);
                    } else {
                        ((float*)C)[rw * N + c] = v;
                    }
                }
            }
        }
    }
}

// ---------------------------------------------------------------------------
// gemm_ln: C = A[M,K]@W[256,K]^T (+bias)(+residual via H), writes H (fp32) and
// Y (bf16) where Y = LayerNorm(row)(g,b) unless FLAGS&8 (plain bf16).
// BM=64, BN=256 (full rows in one block) -> LN in epilogue.
// FLAGS: 1 bias, 4 residual (H += ), 8 plain bf16 out (no LN).
// ---------------------------------------------------------------------------
template<int FLAGS>
__global__ __launch_bounds__(256) void gemm_ln(
    const bf16* __restrict__ A, const bf16* __restrict__ W,
    const float* __restrict__ bias, const float* __restrict__ lg,
    const float* __restrict__ lb, float* H, bf16* __restrict__ Y, int K)
{
    __shared__ bf16 sA[2][64 * 32];
    __shared__ bf16 sB[2][256 * 32];
    __shared__ float rsum[64][4];
    __shared__ float rsq[64][4];
    const int t    = threadIdx.x;
    const int lane = t & 63;
    const int w    = t >> 6;
    const int fr   = lane & 15;
    const int fg   = lane >> 4;
    const long bm  = (long)blockIdx.x * 64;

    f32x4 acc[4][4];
#pragma unroll
    for (int m = 0; m < 4; ++m)
#pragma unroll
        for (int n = 0; n < 4; ++n)
#pragma unroll
            for (int r = 0; r < 4; ++r) acc[m][n][r] = 0.f;

    const int nkt = K >> 5;
    auto stage = [&](int buf, int kt) {
        const int k0 = kt << 5;
        GLOAD16(A + (bm + (t >> 2)) * (long)K + k0 + ((t & 3) << 3),
                &sA[buf][t * 8]);
#pragma unroll
        for (int i = 0; i < 4; ++i)
            GLOAD16(W + (long)((i << 6) + (t >> 2)) * K + k0 + ((t & 3) << 3),
                    &sB[buf][(i * 256 + t) * 8]);
    };

    stage(0, 0);
    __syncthreads();
    for (int kt = 0; kt < nkt; ++kt) {
        const int cur = kt & 1;
        if (kt + 1 < nkt) stage(cur ^ 1, kt + 1);
        short8 af[4], bg[4];
#pragma unroll
        for (int m = 0; m < 4; ++m)
            af[m] = *(const short8*)&sA[cur][(m * 16 + fr) * 32 + fg * 8];
#pragma unroll
        for (int n = 0; n < 4; ++n)
            bg[n] = *(const short8*)&sB[cur][(w * 64 + n * 16 + fr) * 32 + fg * 8];
#pragma unroll
        for (int m = 0; m < 4; ++m)
#pragma unroll
            for (int n = 0; n < 4; ++n)
                acc[m][n] = __builtin_amdgcn_mfma_f32_16x16x32_bf16(
                    af[m], bg[n], acc[m][n], 0, 0, 0);
        __syncthreads();
    }

    float bs[4];
#pragma unroll
    for (int n = 0; n < 4; ++n) {
        const int c = w * 64 + n * 16 + fr;
        bs[n] = (FLAGS & 1) ? bias[c] : 0.f;
    }
    float ps[4][4], pq[4][4];
#pragma unroll
    for (int m = 0; m < 4; ++m)
#pragma unroll
        for (int r = 0; r < 4; ++r) { ps[m][r] = 0.f; pq[m][r] = 0.f; }
#pragma unroll
    for (int m = 0; m < 4; ++m)
#pragma unroll
        for (int n = 0; n < 4; ++n)
#pragma unroll
            for (int r = 0; r < 4; ++r) {
                const long rw = bm + m * 16 + fg * 4 + r;
                const int c = w * 64 + n * 16 + fr;
                float v = acc[m][n][r] + bs[n];
                if (FLAGS & 4) v += H[rw * HID + c];
                H[rw * HID + c] = v;
                acc[m][n][r] = v;
                ps[m][r] += v;
                pq[m][r] += v * v;
            }
    if (FLAGS & 8) {
#pragma unroll
        for (int m = 0; m < 4; ++m)
#pragma unroll
            for (int n = 0; n < 4; ++n)
#pragma unroll
                for (int r = 0; r < 4; ++r) {
                    const long rw = bm + m * 16 + fg * 4 + r;
                    const int c = w * 64 + n * 16 + fr;
                    Y[rw * HID + c] = __float2bfloat16(acc[m][n][r]);
                }
    } else {
#pragma unroll
        for (int m = 0; m < 4; ++m)
#pragma unroll
            for (int r = 0; r < 4; ++r) {
                float s = ps[m][r], q = pq[m][r];
                s += __shfl_xor(s, 1); q += __shfl_xor(q, 1);
                s += __shfl_xor(s, 2); q += __shfl_xor(q, 2);
                s += __shfl_xor(s, 4); q += __shfl_xor(q, 4);
                s += __shfl_xor(s, 8); q += __shfl_xor(q, 8);
                ps[m][r] = s; pq[m][r] = q;
            }
        if (fr == 0) {
#pragma unroll
            for (int m = 0; m < 4; ++m)
#pragma unroll
                for (int r = 0; r < 4; ++r) {
                    const int row = m * 16 + fg * 4 + r;
                    rsum[row][w] = ps[m][r];
                    rsq[row][w]  = pq[m][r];
                }
        }
        __syncthreads();
#pragma unroll
        for (int m = 0; m < 4; ++m)
#pragma unroll
            for (int r = 0; r < 4; ++r) {
                const int row = m * 16 + fg * 4 + r;
                const float4 s4 = *(const float4*)&rsum[row][0];
                const float4 q4 = *(const float4*)&rsq[row][0];
                const float S = (s4.x + s4.y) + (s4.z + s4.w);
                const float Q = (q4.x + q4.y) + (q4.z + q4.w);
                const float mean = S * (1.f / 256.f);
                const float inv  = rsqrtf(Q * (1.f / 256.f) - mean * mean + 1e-5f);
                const long rw = bm + row;
#pragma unroll
                for (int n = 0; n < 4; ++n) {
                    const int c = w * 64 + n * 16 + fr;
                    const float y = (acc[m][n][r] - mean) * inv * lg[c] + lb[c];
                    Y[rw * HID + c] = __float2bfloat16(y);
                }
            }
    }
}

// ---------------------------------------------------------------------------
// fc1 GEMM, fused fp32->bf16 A-staging; epilogue writes DIRECTLY into hcat
// (row stride 288). N=256 fixed, K=3072.
// ---------------------------------------------------------------------------
__global__ __launch_bounds__(256) void fc1_k(
    const float* __restrict__ A, const bf16* __restrict__ W,
    const float* __restrict__ bias, bf16* __restrict__ hcat)
{
    __shared__ bf16 sA[2][128 * 32];
    __shared__ bf16 sB[2][128 * 32];
    const int t    = threadIdx.x;
    const int lane = t & 63;
    const int wid  = t >> 6;
    const int wr   = wid >> 1, wc = wid & 1;
    const long bm  = (long)blockIdx.x * 128;
    const int  bn  = blockIdx.y * 128;
    const int  fr  = lane & 15;
    const int  fg  = lane >> 4;
    const int  row0 = t >> 2;
    const int  kq0  = (t & 3) << 3;
    const int  arow = t >> 3;
    const int  ac4  = (t & 7) << 2;

    f32x4 acc[4][4];
#pragma unroll
    for (int m = 0; m < 4; ++m)
#pragma unroll
        for (int n = 0; n < 4; ++n)
#pragma unroll
            for (int r = 0; r < 4; ++r) acc[m][n][r] = 0.f;

    auto stageB = [&](int buf, int kt) {
        const int k0 = kt << 5;
        GLOAD16(W + (long)(bn + row0)      * IN_DIM + k0 + kq0, &sB[buf][(t      ) * 8]);
        GLOAD16(W + (long)(bn + row0 + 64) * IN_DIM + k0 + kq0, &sB[buf][(t + 256) * 8]);
    };
    float4 va[4];
    auto loadA = [&](int kt) {
        const int k0 = kt << 5;
#pragma unroll
        for (int rep = 0; rep < 4; ++rep)
            va[rep] = *(const float4*)(A + (bm + arow + rep * 32) * (long)IN_DIM + k0 + ac4);
    };
    auto writeA = [&](int buf) {
#pragma unroll
        for (int rep = 0; rep < 4; ++rep) {
            alignas(8) bf16 tb[4];
            tb[0] = __float2bfloat16(va[rep].x);
            tb[1] = __float2bfloat16(va[rep].y);
            tb[2] = __float2bfloat16(va[rep].z);
            tb[3] = __float2bfloat16(va[rep].w);
            *(ushort4*)&sA[buf][(arow + rep * 32) * 32 + ac4] = *(const ushort4*)tb;
        }
    };

    loadA(0);
    stageB(0, 0);
    writeA(0);
    __syncthreads();
    const int nkt = IN_DIM >> 5;   // 96
    for (int kt = 0; kt < nkt; ++kt) {
        const int cur = kt & 1;
        if (kt + 1 < nkt) { stageB(cur ^ 1, kt + 1); loadA(kt + 1); }
        short8 af[4], bg[4];
#pragma unroll
        for (int m = 0; m < 4; ++m)
            af[m] = *(const short8*)&sA[cur][(wr * 64 + m * 16 + fr) * 32 + fg * 8];
#pragma unroll
        for (int n = 0; n < 4; ++n)
            bg[n] = *(const short8*)&sB[cur][(wc * 64 + n * 16 + fr) * 32 + fg * 8];
#pragma unroll
        for (int m = 0; m < 4; ++m)
#pragma unroll
            for (int n = 0; n < 4; ++n)
                acc[m][n] = __builtin_amdgcn_mfma_f32_16x16x32_bf16(
                    af[m], bg[n], acc[m][n], 0, 0, 0);
        if (kt + 1 < nkt) writeA(cur ^ 1);
        __syncthreads();
    }

#pragma unroll
    for (int n = 0; n < 4; ++n) {
        const int c = bn + wc * 64 + n * 16 + fr;
        const float bsn = bias[c];
#pragma unroll
        for (int m = 0; m < 4; ++m)
#pragma unroll
            for (int r = 0; r < 4; ++r) {
                const long rw = bm + wr * 64 + m * 16 + fg * 4 + r;
                hcat[rw * 288 + c] = __float2bfloat16(acc[m][n][r] + bsn);
            }
    }
}

// fill hcat cols 256..287 with bf16(emb[fb]) + zero pad; 8 rows/block
__global__ __launch_bounds__(256) void fillemb(
    const float* __restrict__ emb, const int* __restrict__ fb,
    bf16* __restrict__ hcat)
{
    const long row = (long)blockIdx.x * 8 + (threadIdx.x >> 5);
    const int c = threadIdx.x & 31;
    bf16 v = (c < EMB_D) ? __float2bfloat16(emb[(long)fb[row] * EMB_D + c])
                         : __float2bfloat16(0.f);
    hcat[row * 288 + 256 + c] = v;
}

// ---------------------------------------------------------------------------
// cvtall: all weight conversions in ONE kernel (regions as round 13).
// ---------------------------------------------------------------------------
__global__ __launch_bounds__(256) void cvtall(
    const float* __restrict__ fc1_w, const float* __restrict__ proj_w,
    const float* __restrict__ slow_w, const float* __restrict__ out_w,
    const float* __restrict__ ff1_w, const float* __restrict__ ff2_w,
    const float* __restrict__ outl_w, bf16* __restrict__ dst)
{
    for (long i = (long)blockIdx.x * 256 + threadIdx.x; i < 4562944L;
         i += (long)gridDim.x * 256) {
        float v;
        if (i < 786432L) {
            v = fc1_w[i];
        } else if (i < 860160L) {
            const long j = i - 786432L;
            const int r = (int)(j / 288), c = (int)(j - (long)r * 288);
            v = (c < 266) ? proj_w[(long)r * 266 + c] : 0.f;
        } else if (i < 1777664L) {
            const long j = i - 860160L;
            const int l = (int)(j / 229376);
            const long m = j - (long)l * 229376;
            const int r = (int)(m >> 8), c = (int)(m & 255);
            v = (r < 784) ? slow_w[(long)l * 200704 + (long)r * 256 + c] : 0.f;
        } else if (i < 2039808L) {
            v = out_w[i - 1777664L];
        } else if (i < 3088384L) {
            v = ff1_w[i - 2039808L];
        } else if (i < 4136960L) {
            v = ff2_w[i - 3088384L];
        } else {
            const long j = i - 4136960L;
            const int r = (int)(j >> 8), c = (int)(j & 255);
            v = (r < 1623) ? outl_w[(long)r * 256 + c] : 0.f;
        }
        dst[i] = __float2bfloat16(v);
    }
}

// 16-dot of register array kr[16] with a row staged as 4 float4s
#define DOT16(dst, kr, s0, s1, s2, s3) do {                                    \
    float _pa = fmaf(kr[3],  (s0).w, fmaf(kr[2],  (s0).z, fmaf(kr[1],  (s0).y, kr[0]  * (s0).x))); \
    float _pb = fmaf(kr[7],  (s1).w, fmaf(kr[6],  (s1).z, fmaf(kr[5],  (s1).y, kr[4]  * (s1).x))); \
    float _pc = fmaf(kr[11], (s2).w, fmaf(kr[10], (s2).z, fmaf(kr[9],  (s2).y, kr[8]  * (s2).x))); \
    float _pd = fmaf(kr[15], (s3).w, fmaf(kr[14], (s3).z, fmaf(kr[13], (s3).y, kr[12] * (s3).x))); \
    dst = (_pa + _pb) + (_pc + _pd);                                           \
} while (0)

// ---------------------------------------------------------------------------
// coef2_k: per-chunk affine-recursion coefficients (one wave per T=16 chunk).
// From softmaxed q,k, v, beta:
//   L[t][s]=beta_t(k_t.k_s) s<t;  A1 = tril(QK)(I+L)^-1;  A2 = K^T (I+L)^-1
//   A1b/A2b = columns scaled by beta_s
//   M  = I - A2b K   (16k x 16k)     N  = A2b V   (16k x 16v)
//   C1 = Q - A1b K   (16t x 16k)     D1 = A1b V   (16t x 16v)
// Chunk semantics: W_{c+1} = M W_c + N ;  O_c = C1 W_c + D1.
// Output layout per chunk (1024 fp32): [M | C1 | N | D1], each row-major 16x16.
// ---------------------------------------------------------------------------
__global__ __launch_bounds__(256) void coef2_k(
    const bf16* __restrict__ qkvb, float* __restrict__ cfb)
{
    __shared__ float wrkc[4][16 * 52];
    __shared__ float Gm[4][16 * 17];
    __shared__ float Mql[4][16 * 17];
    __shared__ float A1l[4][16 * 17];
    __shared__ float A2l[4][16 * 17];
    const int tid = threadIdx.x;
    const int w = tid >> 6, lane = tid & 63;
    const int cg = blockIdx.x * 4 + w;          // global chunk id
    const int chain = cg >> 6;
    const int ck = cg & 63;
    const bf16* rows = qkvb + ((long)chain * S_LEN + (long)ck * 16) * QROW;
    float* wk = wrkc[w];
    float* G  = Gm[w];
    float* M  = Mql[w];
    float* A1 = A1l[w];
    float* A2 = A2l[w];

    // phase A: softmax q|k half-row per lane (lanes 0..31), v cvt not needed
    // here beyond LDS copy (we keep full rows for the matmuls), beta copy.
    if (lane < 32) {
        const int row = lane >> 1, hf = lane & 1;
        const short* ps = (const short*)(rows + (long)row * QROW) + hf * 16;
        const short8 r0 = *(const short8*)(ps);
        const short8 r1 = *(const short8*)(ps + 8);
        float f[16];
#pragma unroll
        for (int j = 0; j < 8; ++j) { f[j] = b2f(r0[j]); f[8 + j] = b2f(r1[j]); }
        float mx = f[0];
#pragma unroll
        for (int j = 1; j < 16; ++j) mx = fmaxf(mx, f[j]);
        float sum = 0.f;
#pragma unroll
        for (int j = 0; j < 16; ++j) { f[j] = __expf(f[j] - mx); sum += f[j]; }
        const float inv = 1.f / sum;
        float* pw = wk + row * 52 + hf * 16;
#pragma unroll
        for (int j = 0; j < 16; ++j) pw[j] = f[j] * inv;
        // v (bf16 -> fp32), 16 per row handled by hf halves
        const short8 rv = *(const short8*)((const short*)(rows + (long)row * QROW) + 32 + hf * 8);
        float* pv = wk + row * 52 + 32 + hf * 8;
#pragma unroll
        for (int j = 0; j < 8; ++j) pv[j] = b2f(rv[j]);
        if (hf == 0)
            wk[row * 52 + 48] = b2f(((const short*)(rows + (long)row * QROW))[48]);
    }
    asm volatile("s_waitcnt lgkmcnt(0)" ::: "memory");

    // phase B1: G (=L) and tril(QK) tables (roles i4 = lane>>2, jq = lane&3)
    const int i4 = lane >> 2, jq = lane & 3;
    {
        const float* myrow = wk + i4 * 52;
        float ki[16], qi[16];
        const float4 kA = *(const float4*)(myrow + 16);
        const float4 kB = *(const float4*)(myrow + 20);
        const float4 kC = *(const float4*)(myrow + 24);
        const float4 kD = *(const float4*)(myrow + 28);
        ki[0]=kA.x; ki[1]=kA.y; ki[2]=kA.z; ki[3]=kA.w;
        ki[4]=kB.x; ki[5]=kB.y; ki[6]=kB.z; ki[7]=kB.w;
        ki[8]=kC.x; ki[9]=kC.y; ki[10]=kC.z; ki[11]=kC.w;
        ki[12]=kD.x; ki[13]=kD.y; ki[14]=kD.z; ki[15]=kD.w;
        const float4 qA = *(const float4*)(myrow);
        const float4 qB = *(const float4*)(myrow + 4);
        const float4 qC = *(const float4*)(myrow + 8);
        const float4 qD = *(const float4*)(myrow + 12);
        qi[0]=qA.x; qi[1]=qA.y; qi[2]=qA.z; qi[3]=qA.w;
        qi[4]=qB.x; qi[5]=qB.y; qi[6]=qB.z; qi[7]=qB.w;
        qi[8]=qC.x; qi[9]=qC.y; qi[10]=qC.z; qi[11]=qC.w;
        qi[12]=qD.x; qi[13]=qD.y; qi[14]=qD.z; qi[15]=qD.w;
        const float beta = myrow[48];
#pragma unroll
        for (int m = 0; m < 4; ++m) {
            const int s = jq * 4 + m;
            const float* sr = wk + s * 52 + 16;
            const float4 s0 = *(const float4*)(sr);
            const float4 s1 = *(const float4*)(sr + 4);
            const float4 s2 = *(const float4*)(sr + 8);
            const float4 s3 = *(const float4*)(sr + 12);
            float g, qk;
            DOT16(g, ki, s0, s1, s2, s3);
            DOT16(qk, qi, s0, s1, s2, s3);
            G[i4 * 17 + s] = (s < i4)  ? beta * g : 0.f;   // L[i][s]
            M[i4 * 17 + s] = (s <= i4) ? qk : 0.f;         // tril(QK)
        }
    }
    asm volatile("s_waitcnt lgkmcnt(0)" ::: "memory");

    // phase B2: backward column solve; publish beta-scaled A1b/A2b to LDS.
    {
        const int cs = i4, rq = jq;
        float A1r[4], A2r[4];
#pragma unroll
        for (int j = 0; j < 4; ++j)
            A1r[j] = M[(rq * 4 + j) * 17 + cs];
        const float4 kcol = *(const float4*)&wk[cs * 52 + 16 + rq * 4];
        A2r[0] = kcol.x; A2r[1] = kcol.y; A2r[2] = kcol.z; A2r[3] = kcol.w;
#pragma unroll
        for (int t = 15; t >= 1; --t) {
            const float Lc = G[t * 17 + cs];   // 0 for cs >= t
            const float b10 = __shfl(A1r[0], t * 4 + rq);
            const float b11 = __shfl(A1r[1], t * 4 + rq);
            const float b12 = __shfl(A1r[2], t * 4 + rq);
            const float b13 = __shfl(A1r[3], t * 4 + rq);
            const float b20 = __shfl(A2r[0], t * 4 + rq);
            const float b21 = __shfl(A2r[1], t * 4 + rq);
            const float b22 = __shfl(A2r[2], t * 4 + rq);
            const float b23 = __shfl(A2r[3], t * 4 + rq);
            A1r[0] = fmaf(-Lc, b10, A1r[0]); A1r[1] = fmaf(-Lc, b11, A1r[1]);
            A1r[2] = fmaf(-Lc, b12, A1r[2]); A1r[3] = fmaf(-Lc, b13, A1r[3]);
            A2r[0] = fmaf(-Lc, b20, A2r[0]); A2r[1] = fmaf(-Lc, b21, A2r[1]);
            A2r[2] = fmaf(-Lc, b22, A2r[2]); A2r[3] = fmaf(-Lc, b23, A2r[3]);
        }
        const float bcs = wk[cs * 52 + 48];
#pragma unroll
        for (int j = 0; j < 4; ++j) {
            A1[(rq * 4 + j) * 17 + cs] = A1r[j] * bcs;
            A2[(rq * 4 + j) * 17 + cs] = A2r[j] * bcs;
        }
    }
    asm volatile("s_waitcnt lgkmcnt(0)" ::: "memory");

    // phase C: M = I - A2b K, N = A2b V, C1 = Q - A1b K, D1 = A1b V; store.
    {
        const int x = i4;
        float mM[4] = {0,0,0,0}, mN[4] = {0,0,0,0};
        float mC[4] = {0,0,0,0}, mD[4] = {0,0,0,0};
#pragma unroll
        for (int s = 0; s < 16; ++s) {
            const float a2 = A2[x * 17 + s];
            const float a1 = A1[x * 17 + s];
            const float4 k4 = *(const float4*)&wk[s * 52 + 16 + jq * 4];
            const float4 v4 = *(const float4*)&wk[s * 52 + 32 + jq * 4];
            mM[0] = fmaf(a2, k4.x, mM[0]); mM[1] = fmaf(a2, k4.y, mM[1]);
            mM[2] = fmaf(a2, k4.z, mM[2]); mM[3] = fmaf(a2, k4.w, mM[3]);
            mN[0] = fmaf(a2, v4.x, mN[0]); mN[1] = fmaf(a2, v4.y, mN[1]);
            mN[2] = fmaf(a2, v4.z, mN[2]); mN[3] = fmaf(a2, v4.w, mN[3]);
            mC[0] = fmaf(a1, k4.x, mC[0]); mC[1] = fmaf(a1, k4.y, mC[1]);
            mC[2] = fmaf(a1, k4.z, mC[2]); mC[3] = fmaf(a1, k4.w, mC[3]);
            mD[0] = fmaf(a1, v4.x, mD[0]); mD[1] = fmaf(a1, v4.y, mD[1]);
            mD[2] = fmaf(a1, v4.z, mD[2]); mD[3] = fmaf(a1, v4.w, mD[3]);
        }
        const float4 qx = *(const float4*)&wk[x * 52 + jq * 4];
        float* dst = cfb + (long)cg * 1024;
        f32x4 oM, oC, oN, oD;
#pragma unroll
        for (int m = 0; m < 4; ++m)
            oM[m] = ((jq * 4 + m) == x ? 1.f : 0.f) - mM[m];
        oC[0] = qx.x - mC[0]; oC[1] = qx.y - mC[1];
        oC[2] = qx.z - mC[2]; oC[3] = qx.w - mC[3];
        oN[0] = mN[0]; oN[1] = mN[1]; oN[2] = mN[2]; oN[3] = mN[3];
        oD[0] = mD[0]; oD[1] = mD[1]; oD[2] = mD[2]; oD[3] = mD[3];
        *(f32x4*)(dst +       x * 16 + jq * 4) = oM;
        *(f32x4*)(dst + 256 + x * 16 + jq * 4) = oC;
        *(f32x4*)(dst + 512 + x * 16 + jq * 4) = oN;
        *(f32x4*)(dst + 768 + x * 16 + jq * 4) = oD;
    }
}

// ---------------------------------------------------------------------------
// prefix_k: per-chain affine prefix over 64 chunks, all in registers.
// Lane (x = lane>>2, jq = lane&3) holds W[x][jq*4..+3].
//   Wn = N + M W ;  O = D1 + C1 W  -- both share the 16 shfl gathers of W.
// One wave per chain (512 blocks); coefficients streamed via global_load_lds
// (4KB/chunk, double-buffered, counted vmcnt).
// ---------------------------------------------------------------------------
__global__ __launch_bounds__(64) void prefix_k(
    const float* __restrict__ cfb, bf16* __restrict__ o)
{
    __shared__ float scf[2][1024];
    const int lane = threadIdx.x;
    const int x = lane >> 2, jq = lane & 3;
    const int chain = blockIdx.x;
    const int b = chain >> 4, hh = chain & 15;
    bf16* po = o + (long)b * HID + hh * HDIM + jq * 4;
    const float* cb = cfb + (long)chain * 64 * 1024;

    auto stage = [&](int buf, int c) {
#pragma unroll
        for (int i = 0; i < 4; ++i)
            GLOAD16(cb + (long)c * 1024 + (i * 64 + lane) * 4,
                    &scf[buf][(i * 64 + lane) * 4]);
    };

    float W0r = 0.f, W1r = 0.f, W2r = 0.f, W3r = 0.f;
    stage(0, 0);
    asm volatile("s_waitcnt vmcnt(0)" ::: "memory");
    for (int c = 0; c < 64; ++c) {
        const int buf = c & 1;
        // retire this chunk's 4 loads (oldest); 1 o-store may stay in flight
        asm volatile("s_waitcnt vmcnt(1)" ::: "memory");
        if (c + 1 < 64) stage(buf ^ 1, c + 1);

        float Mrow[16], Crow[16];
#pragma unroll
        for (int t = 0; t < 16; ++t) {
            Mrow[t] = scf[buf][x * 16 + t];
            Crow[t] = scf[buf][256 + x * 16 + t];
        }
        const float4 N4 = *(const float4*)&scf[buf][512 + x * 16 + jq * 4];
        const float4 D4 = *(const float4*)&scf[buf][768 + x * 16 + jq * 4];
        float Wn0 = N4.x, Wn1 = N4.y, Wn2 = N4.z, Wn3 = N4.w;
        float On0 = D4.x, On1 = D4.y, On2 = D4.z, On3 = D4.w;
#pragma unroll
        for (int t = 0; t < 16; ++t) {
            const float g0 = __shfl(W0r, t * 4 + jq);
            const float g1 = __shfl(W1r, t * 4 + jq);
            const float g2 = __shfl(W2r, t * 4 + jq);
            const float g3 = __shfl(W3r, t * 4 + jq);
            Wn0 = fmaf(Mrow[t], g0, Wn0); Wn1 = fmaf(Mrow[t], g1, Wn1);
            Wn2 = fmaf(Mrow[t], g2, Wn2); Wn3 = fmaf(Mrow[t], g3, Wn3);
            On0 = fmaf(Crow[t], g0, On0); On1 = fmaf(Crow[t], g1, On1);
            On2 = fmaf(Crow[t], g2, On2); On3 = fmaf(Crow[t], g3, On3);
        }
        W0r = Wn0; W1r = Wn1; W2r = Wn2; W3r = Wn3;
        const int sg = c * 16 + x;
        alignas(8) bf16 tb[4];
        tb[0] = __float2bfloat16(On0); tb[1] = __float2bfloat16(On1);
        tb[2] = __float2bfloat16(On2); tb[3] = __float2bfloat16(On3);
        *(ushort4*)((unsigned short*)(po + (long)sg * (B_SZ * HID))) =
            *(const ushort4*)tb;
    }
}

// ---------------------------------------------------------------------------
extern "C" void kernel_launch(void* const* d_in, const int* in_sizes, int n_in,
                              void* d_out, int out_size, void* d_ws, size_t ws_size,
                              hipStream_t stream)
{
    const float* x      = (const float*)d_in[0];
    const int*   fb     = (const int*)  d_in[1];
    const float* fc1_w  = (const float*)d_in[2];
    const float* fc1_b  = (const float*)d_in[3];
    const float* emb    = (const float*)d_in[4];
    const float* proj_w = (const float*)d_in[5];
    const float* proj_b = (const float*)d_in[6];
    const float* ln1_g  = (const float*)d_in[7];
    const float* ln1_b  = (const float*)d_in[8];
    const float* slow_w = (const float*)d_in[9];
    const float* out_w  = (const float*)d_in[10];
    const float* ln2_g  = (const float*)d_in[11];
    const float* ln2_b  = (const float*)d_in[12];
    const float* ff1_w  = (const float*)d_in[13];
    const float* ff1_b  = (const float*)d_in[14];
    const float* ff2_w  = (const float*)d_in[15];
    const float* ff2_b  = (const float*)d_in[16];
    const float* outl_w = (const float*)d_in[17];
    const float* outl_b = (const float*)d_in[18];

    // ---- workspace layout (bf16 weight buffers CONTIGUOUS from fc1b) ----
    char* wp = (char*)d_ws;
    float* h    = (float*)wp;                 wp += (size_t)MROWS * HID * 4;
    bf16*  abuf = (bf16*)wp;                  wp += (size_t)MROWS * HID * 2;
    bf16*  fc1b = (bf16*)wp;                  wp += (size_t)HID * IN_DIM * 2;
    bf16*  projb= (bf16*)wp;                  wp += (size_t)HID * 288 * 2;
    bf16*  slowb= (bf16*)wp;                  wp += (size_t)NLAYER * 896 * HID * 2;
    bf16*  outwb= (bf16*)wp;                  wp += (size_t)NLAYER * HID * HID * 2;
    bf16*  ff1b = (bf16*)wp;                  wp += (size_t)NLAYER * DFF * HID * 2;
    bf16*  ff2b = (bf16*)wp;                  wp += (size_t)NLAYER * HID * DFF * 2;
    bf16*  outlb= (bf16*)wp;                  wp += (size_t)1664 * HID * 2;

    // ---- d_out scratch, sequentially reused ----
    bf16*  hcat = (bf16*)d_out;               // 18.9MB, dead after proj
    bf16*  qkvb = (bf16*)d_out;               // 58.7MB, dead after coef2
    float* cfb  = (float*)((bf16*)d_out + (size_t)512 * 1024 * QROW); // 128MB coef
    bf16*  hff  = (bf16*)d_out;               // 67.1MB, dead after ff2

    const dim3 blk(256);

    // ---- all weight conversions in one dispatch ----
    cvtall<<<dim3(1024), blk, 0, stream>>>(fc1_w, proj_w, slow_w, out_w,
                                           ff1_w, ff2_w, outl_w, fc1b);

    // fc1 writes directly into hcat (cols 0..255); fillemb fills 256..287
    fc1_k<<<dim3(256, 2), blk, 0, stream>>>(x, fc1b, fc1_b, hcat);
    fillemb<<<dim3(MROWS / 8), blk, 0, stream>>>(emb, fb, hcat);
    // proj + fused LN1_0: h = hcat@proj^T + b; abuf = LN(h)
    gemm_ln<1><<<dim3(512), blk, 0, stream>>>(hcat, projb, proj_b,
                                              ln1_g, ln1_b, h, abuf, 288);

    for (int l = 0; l < NLAYER; ++l) {
        // qkvb (permuted (b,h,s,56) bf16, sigmoid(beta) fused)
        mgemm<16><<<dim3(256, 7), blk, 0, stream>>>(abuf, slowb + (size_t)l * 896 * HID,
                                                    nullptr, qkvb, 784, HID, HID);
        // per-chunk affine coefficients M/C1/N/D1 (massively parallel)
        coef2_k<<<dim3(8192), blk, 0, stream>>>(qkvb, cfb);
        // register-resident affine prefix -> o
        prefix_k<<<dim3(B_SZ * NHEAD), dim3(64), 0, stream>>>(cfb, abuf);
        // out-GEMM + residual + fused LN2: h += o@out^T; abuf = LN2(h)
        gemm_ln<4><<<dim3(512), blk, 0, stream>>>(abuf, outwb + (size_t)l * HID * HID,
                                                  nullptr, ln2_g + l * HID,
                                                  ln2_b + l * HID, h, abuf, HID);
        // hff = bf16(relu(abuf @ ff1^T + b1))  N=1024 K=256
        mgemm<11><<<dim3(256, 8), blk, 0, stream>>>(abuf, ff1b + (size_t)l * DFF * HID,
                                                    ff1_b + l * DFF, hff, DFF, HID, HID);
        // ff2 + residual + bias; abuf = LN1_{l+1}(h) or plain bf16(h) on last
        if (l + 1 < NLAYER)
            gemm_ln<5><<<dim3(512), blk, 0, stream>>>(hff, ff2b + (size_t)l * HID * DFF,
                                                      ff2_b + l * HID,
                                                      ln1_g + (l + 1) * HID,
                                                      ln1_b + (l + 1) * HID, h, abuf, DFF);
        else
            gemm_ln<13><<<dim3(512), blk, 0, stream>>>(hff, ff2b + (size_t)l * HID * DFF,
                                                       ff2_b + l * HID,
                                                       nullptr, nullptr, h, abuf, DFF);
    }
    // final: out = abuf @ outl_w^T + b  (fp32, N=1623 K=256)
    mgemm<1><<<dim3(256, 13), blk, 0, stream>>>(abuf, outlb, outl_b, d_out,
                                                NCLS, HID, HID);
}

// Round 17
// 1517.078 us; speedup vs baseline: 1.7200x; 1.0102x over previous
//
#include <hip/hip_runtime.h>
#include <hip/hip_bf16.h>

// Problem constants
#define S_LEN  1024
#define B_SZ   32
#define IN_DIM 3072
#define HID    256
#define NHEAD  16
#define HDIM   16
#define DFF    1024
#define NLAYER 4
#define NCLS   1623
#define EMB_D  10
#define MROWS  (S_LEN * B_SZ)   // 32768
#define QROW   56                // bf16 elems per qkvb row (112 B, 16B-aligned)

using bf16   = __hip_bfloat16;
using short8 = __attribute__((ext_vector_type(8))) short;
using f32x4  = __attribute__((ext_vector_type(4))) float;

#define GLOAD16(g, l) __builtin_amdgcn_global_load_lds(                        \
    (const __attribute__((address_space(1))) void*)(g),                        \
    (__attribute__((address_space(3))) void*)(l), 16, 0, 0)

__device__ __forceinline__ float b2f(short s) {
    union { float f; unsigned u; } x;
    x.u = ((unsigned)(unsigned short)s) << 16;
    return x.f;
}

// ---------------------------------------------------------------------------
// bf16 MFMA GEMM: C[M,N] = A[M,K]@W[N,K]^T.  BM=BN=128, BK=32, 256 thr/4 waves.
// FLAGS: 1 bias, 2 relu, 8 bf16-out, 16 permuted bf16 qkvb store (sigmoid on
// col 48 of each 49-group). Used for qkvb (16), ff1 (11), outl (1).
// ---------------------------------------------------------------------------
template<int FLAGS>
__global__ __launch_bounds__(256) void mgemm(
    const bf16* __restrict__ A, const bf16* __restrict__ W,
    const float* __restrict__ bias, void* C, int N, int K, int Wld)
{
    __shared__ bf16 sA[2][128 * 32];
    __shared__ bf16 sB[2][128 * 32];
    const int t    = threadIdx.x;
    const int lane = t & 63;
    const int wid  = t >> 6;
    const int wr   = wid >> 1, wc = wid & 1;
    const long bm  = (long)blockIdx.x * 128;
    const int  bn  = blockIdx.y * 128;
    const int  fr  = lane & 15;
    const int  fg  = lane >> 4;
    const int  row0 = t >> 2;
    const int  kq0  = (t & 3) << 3;

    f32x4 acc[4][4];
#pragma unroll
    for (int m = 0; m < 4; ++m)
#pragma unroll
        for (int n = 0; n < 4; ++n)
#pragma unroll
            for (int r = 0; r < 4; ++r) acc[m][n][r] = 0.f;

    const int nkt = K >> 5;

    auto stage = [&](int buf, int kt) {
        const int k0 = kt << 5;
        GLOAD16(A + (bm + row0)      * (long)K   + k0 + kq0, &sA[buf][(t      ) * 8]);
        GLOAD16(A + (bm + row0 + 64) * (long)K   + k0 + kq0, &sA[buf][(t + 256) * 8]);
        GLOAD16(W + (long)(bn + row0)      * Wld + k0 + kq0, &sB[buf][(t      ) * 8]);
        GLOAD16(W + (long)(bn + row0 + 64) * Wld + k0 + kq0, &sB[buf][(t + 256) * 8]);
    };

    stage(0, 0);
    __syncthreads();
    for (int kt = 0; kt < nkt; ++kt) {
        const int cur = kt & 1;
        if (kt + 1 < nkt) stage(cur ^ 1, kt + 1);
        short8 af[4], bg[4];
#pragma unroll
        for (int m = 0; m < 4; ++m)
            af[m] = *(const short8*)&sA[cur][(wr * 64 + m * 16 + fr) * 32 + fg * 8];
#pragma unroll
        for (int n = 0; n < 4; ++n)
            bg[n] = *(const short8*)&sB[cur][(wc * 64 + n * 16 + fr) * 32 + fg * 8];
#pragma unroll
        for (int m = 0; m < 4; ++m)
#pragma unroll
            for (int n = 0; n < 4; ++n)
                acc[m][n] = __builtin_amdgcn_mfma_f32_16x16x32_bf16(
                    af[m], bg[n], acc[m][n], 0, 0, 0);
        __syncthreads();
    }

    float bs[4];
#pragma unroll
    for (int n = 0; n < 4; ++n) {
        const int c = bn + wc * 64 + n * 16 + fr;
        bs[n] = ((FLAGS & 1) && c < N) ? bias[c] : 0.f;
    }
#pragma unroll
    for (int m = 0; m < 4; ++m) {
#pragma unroll
        for (int n = 0; n < 4; ++n) {
            const int c = bn + wc * 64 + n * 16 + fr;
            if (c < N) {
#pragma unroll
                for (int r = 0; r < 4; ++r) {
                    const long rw = bm + wr * 64 + m * 16 + fg * 4 + r;
                    float v = acc[m][n][r] + bs[n];
                    if (FLAGS & 2) v = fmaxf(v, 0.f);
                    if (FLAGS & 16) {
                        const int s = (int)(rw >> 5), b = (int)(rw & 31);
                        const int hh = c / 49, cc = c - hh * 49;
                        if (cc == 48) v = 1.f / (1.f + __expf(-v));   // sigmoid(beta)
                        ((bf16*)C)[((long)(b * 16 + hh) * 1024 + s) * QROW + cc] =
                            __float2bfloat16(v);
                    } else if (FLAGS & 8) {
                        ((bf16*)C)[rw * N + c] = __float2bfloat16(v);
                    } else {
                        ((float*)C)[rw * N + c] = v;
                    }
                }
            }
        }
    }
}

// ---------------------------------------------------------------------------
// gemm_ln: C = A[M,K]@W[256,K]^T (+bias)(+residual via H), writes H (bf16) and
// Y (bf16) where Y = LayerNorm(row)(g,b) unless FLAGS&8 (plain bf16).
// BM=64, BN=256 (full rows in one block) -> LN in epilogue. LN stats computed
// in fp32 from accumulator values BEFORE the bf16 store rounds them.
// FLAGS: 1 bias, 4 residual (H += ), 8 plain bf16 out (no LN).
// ---------------------------------------------------------------------------
template<int FLAGS>
__global__ __launch_bounds__(256) void gemm_ln(
    const bf16* __restrict__ A, const bf16* __restrict__ W,
    const float* __restrict__ bias, const float* __restrict__ lg,
    const float* __restrict__ lb, bf16* H, bf16* __restrict__ Y, int K)
{
    __shared__ bf16 sA[2][64 * 32];
    __shared__ bf16 sB[2][256 * 32];
    __shared__ float rsum[64][4];
    __shared__ float rsq[64][4];
    const int t    = threadIdx.x;
    const int lane = t & 63;
    const int w    = t >> 6;
    const int fr   = lane & 15;
    const int fg   = lane >> 4;
    const long bm  = (long)blockIdx.x * 64;

    f32x4 acc[4][4];
#pragma unroll
    for (int m = 0; m < 4; ++m)
#pragma unroll
        for (int n = 0; n < 4; ++n)
#pragma unroll
            for (int r = 0; r < 4; ++r) acc[m][n][r] = 0.f;

    const int nkt = K >> 5;
    auto stage = [&](int buf, int kt) {
        const int k0 = kt << 5;
        GLOAD16(A + (bm + (t >> 2)) * (long)K + k0 + ((t & 3) << 3),
                &sA[buf][t * 8]);
#pragma unroll
        for (int i = 0; i < 4; ++i)
            GLOAD16(W + (long)((i << 6) + (t >> 2)) * K + k0 + ((t & 3) << 3),
                    &sB[buf][(i * 256 + t) * 8]);
    };

    stage(0, 0);
    __syncthreads();
    for (int kt = 0; kt < nkt; ++kt) {
        const int cur = kt & 1;
        if (kt + 1 < nkt) stage(cur ^ 1, kt + 1);
        short8 af[4], bg[4];
#pragma unroll
        for (int m = 0; m < 4; ++m)
            af[m] = *(const short8*)&sA[cur][(m * 16 + fr) * 32 + fg * 8];
#pragma unroll
        for (int n = 0; n < 4; ++n)
            bg[n] = *(const short8*)&sB[cur][(w * 64 + n * 16 + fr) * 32 + fg * 8];
#pragma unroll
        for (int m = 0; m < 4; ++m)
#pragma unroll
            for (int n = 0; n < 4; ++n)
                acc[m][n] = __builtin_amdgcn_mfma_f32_16x16x32_bf16(
                    af[m], bg[n], acc[m][n], 0, 0, 0);
        __syncthreads();
    }

    float bs[4];
#pragma unroll
    for (int n = 0; n < 4; ++n) {
        const int c = w * 64 + n * 16 + fr;
        bs[n] = (FLAGS & 1) ? bias[c] : 0.f;
    }
    float ps[4][4], pq[4][4];
#pragma unroll
    for (int m = 0; m < 4; ++m)
#pragma unroll
        for (int r = 0; r < 4; ++r) { ps[m][r] = 0.f; pq[m][r] = 0.f; }
#pragma unroll
    for (int m = 0; m < 4; ++m)
#pragma unroll
        for (int n = 0; n < 4; ++n)
#pragma unroll
            for (int r = 0; r < 4; ++r) {
                const long rw = bm + m * 16 + fg * 4 + r;
                const int c = w * 64 + n * 16 + fr;
                float v = acc[m][n][r] + bs[n];
                if (FLAGS & 4) v += __bfloat162float(H[rw * HID + c]);
                H[rw * HID + c] = __float2bfloat16(v);
                acc[m][n][r] = v;
                ps[m][r] += v;
                pq[m][r] += v * v;
            }
    if (FLAGS & 8) {
#pragma unroll
        for (int m = 0; m < 4; ++m)
#pragma unroll
            for (int n = 0; n < 4; ++n)
#pragma unroll
                for (int r = 0; r < 4; ++r) {
                    const long rw = bm + m * 16 + fg * 4 + r;
                    const int c = w * 64 + n * 16 + fr;
                    Y[rw * HID + c] = __float2bfloat16(acc[m][n][r]);
                }
    } else {
#pragma unroll
        for (int m = 0; m < 4; ++m)
#pragma unroll
            for (int r = 0; r < 4; ++r) {
                float s = ps[m][r], q = pq[m][r];
                s += __shfl_xor(s, 1); q += __shfl_xor(q, 1);
                s += __shfl_xor(s, 2); q += __shfl_xor(q, 2);
                s += __shfl_xor(s, 4); q += __shfl_xor(q, 4);
                s += __shfl_xor(s, 8); q += __shfl_xor(q, 8);
                ps[m][r] = s; pq[m][r] = q;
            }
        if (fr == 0) {
#pragma unroll
            for (int m = 0; m < 4; ++m)
#pragma unroll
                for (int r = 0; r < 4; ++r) {
                    const int row = m * 16 + fg * 4 + r;
                    rsum[row][w] = ps[m][r];
                    rsq[row][w]  = pq[m][r];
                }
        }
        __syncthreads();
#pragma unroll
        for (int m = 0; m < 4; ++m)
#pragma unroll
            for (int r = 0; r < 4; ++r) {
                const int row = m * 16 + fg * 4 + r;
                const float4 s4 = *(const float4*)&rsum[row][0];
                const float4 q4 = *(const float4*)&rsq[row][0];
                const float S = (s4.x + s4.y) + (s4.z + s4.w);
                const float Q = (q4.x + q4.y) + (q4.z + q4.w);
                const float mean = S * (1.f / 256.f);
                const float inv  = rsqrtf(Q * (1.f / 256.f) - mean * mean + 1e-5f);
                const long rw = bm + row;
#pragma unroll
                for (int n = 0; n < 4; ++n) {
                    const int c = w * 64 + n * 16 + fr;
                    const float y = (acc[m][n][r] - mean) * inv * lg[c] + lb[c];
                    Y[rw * HID + c] = __float2bfloat16(y);
                }
            }
    }
}

// ---------------------------------------------------------------------------
// fc1 GEMM, fused fp32->bf16 A-staging; epilogue writes DIRECTLY into hcat
// (row stride 288); bn==0 blocks also fill cols 256..287 from emb[fb].
// N=256 fixed, K=3072.
// ---------------------------------------------------------------------------
__global__ __launch_bounds__(256) void fc1_k(
    const float* __restrict__ A, const bf16* __restrict__ W,
    const float* __restrict__ bias, const float* __restrict__ emb,
    const int* __restrict__ fb, bf16* __restrict__ hcat)
{
    __shared__ bf16 sA[2][128 * 32];
    __shared__ bf16 sB[2][128 * 32];
    const int t    = threadIdx.x;
    const int lane = t & 63;
    const int wid  = t >> 6;
    const int wr   = wid >> 1, wc = wid & 1;
    const long bm  = (long)blockIdx.x * 128;
    const int  bn  = blockIdx.y * 128;
    const int  fr  = lane & 15;
    const int  fg  = lane >> 4;
    const int  row0 = t >> 2;
    const int  kq0  = (t & 3) << 3;
    const int  arow = t >> 3;
    const int  ac4  = (t & 7) << 2;

    f32x4 acc[4][4];
#pragma unroll
    for (int m = 0; m < 4; ++m)
#pragma unroll
        for (int n = 0; n < 4; ++n)
#pragma unroll
            for (int r = 0; r < 4; ++r) acc[m][n][r] = 0.f;

    auto stageB = [&](int buf, int kt) {
        const int k0 = kt << 5;
        GLOAD16(W + (long)(bn + row0)      * IN_DIM + k0 + kq0, &sB[buf][(t      ) * 8]);
        GLOAD16(W + (long)(bn + row0 + 64) * IN_DIM + k0 + kq0, &sB[buf][(t + 256) * 8]);
    };
    float4 va[4];
    auto loadA = [&](int kt) {
        const int k0 = kt << 5;
#pragma unroll
        for (int rep = 0; rep < 4; ++rep)
            va[rep] = *(const float4*)(A + (bm + arow + rep * 32) * (long)IN_DIM + k0 + ac4);
    };
    auto writeA = [&](int buf) {
#pragma unroll
        for (int rep = 0; rep < 4; ++rep) {
            alignas(8) bf16 tb[4];
            tb[0] = __float2bfloat16(va[rep].x);
            tb[1] = __float2bfloat16(va[rep].y);
            tb[2] = __float2bfloat16(va[rep].z);
            tb[3] = __float2bfloat16(va[rep].w);
            *(ushort4*)&sA[buf][(arow + rep * 32) * 32 + ac4] = *(const ushort4*)tb;
        }
    };

    loadA(0);
    stageB(0, 0);
    writeA(0);
    __syncthreads();
    const int nkt = IN_DIM >> 5;   // 96
    for (int kt = 0; kt < nkt; ++kt) {
        const int cur = kt & 1;
        if (kt + 1 < nkt) { stageB(cur ^ 1, kt + 1); loadA(kt + 1); }
        short8 af[4], bg[4];
#pragma unroll
        for (int m = 0; m < 4; ++m)
            af[m] = *(const short8*)&sA[cur][(wr * 64 + m * 16 + fr) * 32 + fg * 8];
#pragma unroll
        for (int n = 0; n < 4; ++n)
            bg[n] = *(const short8*)&sB[cur][(wc * 64 + n * 16 + fr) * 32 + fg * 8];
#pragma unroll
        for (int m = 0; m < 4; ++m)
#pragma unroll
            for (int n = 0; n < 4; ++n)
                acc[m][n] = __builtin_amdgcn_mfma_f32_16x16x32_bf16(
                    af[m], bg[n], acc[m][n], 0, 0, 0);
        if (kt + 1 < nkt) writeA(cur ^ 1);
        __syncthreads();
    }

#pragma unroll
    for (int n = 0; n < 4; ++n) {
        const int c = bn + wc * 64 + n * 16 + fr;
        const float bsn = bias[c];
#pragma unroll
        for (int m = 0; m < 4; ++m)
#pragma unroll
            for (int r = 0; r < 4; ++r) {
                const long rw = bm + wr * 64 + m * 16 + fg * 4 + r;
                hcat[rw * 288 + c] = __float2bfloat16(acc[m][n][r] + bsn);
            }
    }
    // fused fillemb: cols 256..287 for this block's 128 rows (bn==0 only)
    if (bn == 0) {
#pragma unroll
        for (int it = 0; it < 16; ++it) {
            const int idx = t * 16 + it;          // 0..4095
            const int rr = idx >> 5, cc = idx & 31;
            const long row = bm + rr;
            bf16 val = (cc < EMB_D)
                ? __float2bfloat16(emb[(long)fb[row] * EMB_D + cc])
                : __float2bfloat16(0.f);
            hcat[row * 288 + 256 + cc] = val;
        }
    }
}

// ---------------------------------------------------------------------------
// cvtall: all weight conversions in ONE kernel (regions as round 13).
// ---------------------------------------------------------------------------
__global__ __launch_bounds__(256) void cvtall(
    const float* __restrict__ fc1_w, const float* __restrict__ proj_w,
    const float* __restrict__ slow_w, const float* __restrict__ out_w,
    const float* __restrict__ ff1_w, const float* __restrict__ ff2_w,
    const float* __restrict__ outl_w, bf16* __restrict__ dst)
{
    for (long i = (long)blockIdx.x * 256 + threadIdx.x; i < 4562944L;
         i += (long)gridDim.x * 256) {
        float v;
        if (i < 786432L) {
            v = fc1_w[i];
        } else if (i < 860160L) {
            const long j = i - 786432L;
            const int r = (int)(j / 288), c = (int)(j - (long)r * 288);
            v = (c < 266) ? proj_w[(long)r * 266 + c] : 0.f;
        } else if (i < 1777664L) {
            const long j = i - 860160L;
            const int l = (int)(j / 229376);
            const long m = j - (long)l * 229376;
            const int r = (int)(m >> 8), c = (int)(m & 255);
            v = (r < 784) ? slow_w[(long)l * 200704 + (long)r * 256 + c] : 0.f;
        } else if (i < 2039808L) {
            v = out_w[i - 1777664L];
        } else if (i < 3088384L) {
            v = ff1_w[i - 2039808L];
        } else if (i < 4136960L) {
            v = ff2_w[i - 3088384L];
        } else {
            const long j = i - 4136960L;
            const int r = (int)(j >> 8), c = (int)(j & 255);
            v = (r < 1623) ? outl_w[(long)r * 256 + c] : 0.f;
        }
        dst[i] = __float2bfloat16(v);
    }
}

// 16-dot of register array kr[16] with a row staged as 4 float4s
#define DOT16(dst, kr, s0, s1, s2, s3) do {                                    \
    float _pa = fmaf(kr[3],  (s0).w, fmaf(kr[2],  (s0).z, fmaf(kr[1],  (s0).y, kr[0]  * (s0).x))); \
    float _pb = fmaf(kr[7],  (s1).w, fmaf(kr[6],  (s1).z, fmaf(kr[5],  (s1).y, kr[4]  * (s1).x))); \
    float _pc = fmaf(kr[11], (s2).w, fmaf(kr[10], (s2).z, fmaf(kr[9],  (s2).y, kr[8]  * (s2).x))); \
    float _pd = fmaf(kr[15], (s3).w, fmaf(kr[14], (s3).z, fmaf(kr[13], (s3).y, kr[12] * (s3).x))); \
    dst = (_pa + _pb) + (_pc + _pd);                                           \
} while (0)

// ---------------------------------------------------------------------------
// coef2_k: per-chunk affine-recursion coefficients (one wave per T=16 chunk).
//   L[t][s]=beta_t(k_t.k_s) s<t;  A1 = tril(QK)(I+L)^-1;  A2 = K^T (I+L)^-1
//   A1b/A2b = columns scaled by beta_s
//   M  = I - A2b K      N  = A2b V      C1 = Q - A1b K      D1 = A1b V
// Chunk semantics: W_{c+1} = M W_c + N ;  O_c = C1 W_c + D1.
// Output layout per chunk (1024 fp32): [M | C1 | N | D1], each row-major 16x16.
// ---------------------------------------------------------------------------
__global__ __launch_bounds__(256) void coef2_k(
    const bf16* __restrict__ qkvb, float* __restrict__ cfb)
{
    __shared__ float wrkc[4][16 * 52];
    __shared__ float Gm[4][16 * 17];
    __shared__ float Mql[4][16 * 17];
    __shared__ float A1l[4][16 * 17];
    __shared__ float A2l[4][16 * 17];
    const int tid = threadIdx.x;
    const int w = tid >> 6, lane = tid & 63;
    const int cg = blockIdx.x * 4 + w;          // global chunk id
    const int chain = cg >> 6;
    const int ck = cg & 63;
    const bf16* rows = qkvb + ((long)chain * S_LEN + (long)ck * 16) * QROW;
    float* wk = wrkc[w];
    float* G  = Gm[w];
    float* M  = Mql[w];
    float* A1 = A1l[w];
    float* A2 = A2l[w];

    // phase A: softmax q|k half-row per lane (lanes 0..31), v cvt, beta copy
    if (lane < 32) {
        const int row = lane >> 1, hf = lane & 1;
        const short* ps = (const short*)(rows + (long)row * QROW) + hf * 16;
        const short8 r0 = *(const short8*)(ps);
        const short8 r1 = *(const short8*)(ps + 8);
        float f[16];
#pragma unroll
        for (int j = 0; j < 8; ++j) { f[j] = b2f(r0[j]); f[8 + j] = b2f(r1[j]); }
        float mx = f[0];
#pragma unroll
        for (int j = 1; j < 16; ++j) mx = fmaxf(mx, f[j]);
        float sum = 0.f;
#pragma unroll
        for (int j = 0; j < 16; ++j) { f[j] = __expf(f[j] - mx); sum += f[j]; }
        const float inv = 1.f / sum;
        float* pw = wk + row * 52 + hf * 16;
#pragma unroll
        for (int j = 0; j < 16; ++j) pw[j] = f[j] * inv;
        const short8 rv = *(const short8*)((const short*)(rows + (long)row * QROW) + 32 + hf * 8);
        float* pv = wk + row * 52 + 32 + hf * 8;
#pragma unroll
        for (int j = 0; j < 8; ++j) pv[j] = b2f(rv[j]);
        if (hf == 0)
            wk[row * 52 + 48] = b2f(((const short*)(rows + (long)row * QROW))[48]);
    }
    asm volatile("s_waitcnt lgkmcnt(0)" ::: "memory");

    // phase B1: G (=L) and tril(QK) tables (roles i4 = lane>>2, jq = lane&3)
    const int i4 = lane >> 2, jq = lane & 3;
    {
        const float* myrow = wk + i4 * 52;
        float ki[16], qi[16];
        const float4 kA = *(const float4*)(myrow + 16);
        const float4 kB = *(const float4*)(myrow + 20);
        const float4 kC = *(const float4*)(myrow + 24);
        const float4 kD = *(const float4*)(myrow + 28);
        ki[0]=kA.x; ki[1]=kA.y; ki[2]=kA.z; ki[3]=kA.w;
        ki[4]=kB.x; ki[5]=kB.y; ki[6]=kB.z; ki[7]=kB.w;
        ki[8]=kC.x; ki[9]=kC.y; ki[10]=kC.z; ki[11]=kC.w;
        ki[12]=kD.x; ki[13]=kD.y; ki[14]=kD.z; ki[15]=kD.w;
        const float4 qA = *(const float4*)(myrow);
        const float4 qB = *(const float4*)(myrow + 4);
        const float4 qC = *(const float4*)(myrow + 8);
        const float4 qD = *(const float4*)(myrow + 12);
        qi[0]=qA.x; qi[1]=qA.y; qi[2]=qA.z; qi[3]=qA.w;
        qi[4]=qB.x; qi[5]=qB.y; qi[6]=qB.z; qi[7]=qB.w;
        qi[8]=qC.x; qi[9]=qC.y; qi[10]=qC.z; qi[11]=qC.w;
        qi[12]=qD.x; qi[13]=qD.y; qi[14]=qD.z; qi[15]=qD.w;
        const float beta = myrow[48];
#pragma unroll
        for (int m = 0; m < 4; ++m) {
            const int s = jq * 4 + m;
            const float* sr = wk + s * 52 + 16;
            const float4 s0 = *(const float4*)(sr);
            const float4 s1 = *(const float4*)(sr + 4);
            const float4 s2 = *(const float4*)(sr + 8);
            const float4 s3 = *(const float4*)(sr + 12);
            float g, qk;
            DOT16(g, ki, s0, s1, s2, s3);
            DOT16(qk, qi, s0, s1, s2, s3);
            G[i4 * 17 + s] = (s < i4)  ? beta * g : 0.f;   // L[i][s]
            M[i4 * 17 + s] = (s <= i4) ? qk : 0.f;         // tril(QK)
        }
    }
    asm volatile("s_waitcnt lgkmcnt(0)" ::: "memory");

    // phase B2: backward column solve; publish beta-scaled A1b/A2b to LDS.
    {
        const int cs = i4, rq = jq;
        float A1r[4], A2r[4];
#pragma unroll
        for (int j = 0; j < 4; ++j)
            A1r[j] = M[(rq * 4 + j) * 17 + cs];
        const float4 kcol = *(const float4*)&wk[cs * 52 + 16 + rq * 4];
        A2r[0] = kcol.x; A2r[1] = kcol.y; A2r[2] = kcol.z; A2r[3] = kcol.w;
#pragma unroll
        for (int t = 15; t >= 1; --t) {
            const float Lc = G[t * 17 + cs];   // 0 for cs >= t
            const float b10 = __shfl(A1r[0], t * 4 + rq);
            const float b11 = __shfl(A1r[1], t * 4 + rq);
            const float b12 = __shfl(A1r[2], t * 4 + rq);
            const float b13 = __shfl(A1r[3], t * 4 + rq);
            const float b20 = __shfl(A2r[0], t * 4 + rq);
            const float b21 = __shfl(A2r[1], t * 4 + rq);
            const float b22 = __shfl(A2r[2], t * 4 + rq);
            const float b23 = __shfl(A2r[3], t * 4 + rq);
            A1r[0] = fmaf(-Lc, b10, A1r[0]); A1r[1] = fmaf(-Lc, b11, A1r[1]);
            A1r[2] = fmaf(-Lc, b12, A1r[2]); A1r[3] = fmaf(-Lc, b13, A1r[3]);
            A2r[0] = fmaf(-Lc, b20, A2r[0]); A2r[1] = fmaf(-Lc, b21, A2r[1]);
            A2r[2] = fmaf(-Lc, b22, A2r[2]); A2r[3] = fmaf(-Lc, b23, A2r[3]);
        }
        const float bcs = wk[cs * 52 + 48];
#pragma unroll
        for (int j = 0; j < 4; ++j) {
            A1[(rq * 4 + j) * 17 + cs] = A1r[j] * bcs;
            A2[(rq * 4 + j) * 17 + cs] = A2r[j] * bcs;
        }
    }
    asm volatile("s_waitcnt lgkmcnt(0)" ::: "memory");

    // phase C: M = I - A2b K, N = A2b V, C1 = Q - A1b K, D1 = A1b V; store.
    {
        const int x = i4;
        float mM[4] = {0,0,0,0}, mN[4] = {0,0,0,0};
        float mC[4] = {0,0,0,0}, mD[4] = {0,0,0,0};
#pragma unroll
        for (int s = 0; s < 16; ++s) {
            const float a2 = A2[x * 17 + s];
            const float a1 = A1[x * 17 + s];
            const float4 k4 = *(const float4*)&wk[s * 52 + 16 + jq * 4];
            const float4 v4 = *(const float4*)&wk[s * 52 + 32 + jq * 4];
            mM[0] = fmaf(a2, k4.x, mM[0]); mM[1] = fmaf(a2, k4.y, mM[1]);
            mM[2] = fmaf(a2, k4.z, mM[2]); mM[3] = fmaf(a2, k4.w, mM[3]);
            mN[0] = fmaf(a2, v4.x, mN[0]); mN[1] = fmaf(a2, v4.y, mN[1]);
            mN[2] = fmaf(a2, v4.z, mN[2]); mN[3] = fmaf(a2, v4.w, mN[3]);
            mC[0] = fmaf(a1, k4.x, mC[0]); mC[1] = fmaf(a1, k4.y, mC[1]);
            mC[2] = fmaf(a1, k4.z, mC[2]); mC[3] = fmaf(a1, k4.w, mC[3]);
            mD[0] = fmaf(a1, v4.x, mD[0]); mD[1] = fmaf(a1, v4.y, mD[1]);
            mD[2] = fmaf(a1, v4.z, mD[2]); mD[3] = fmaf(a1, v4.w, mD[3]);
        }
        const float4 qx = *(const float4*)&wk[x * 52 + jq * 4];
        float* dst = cfb + (long)cg * 1024;
        f32x4 oM, oC, oN, oD;
#pragma unroll
        for (int m = 0; m < 4; ++m)
            oM[m] = ((jq * 4 + m) == x ? 1.f : 0.f) - mM[m];
        oC[0] = qx.x - mC[0]; oC[1] = qx.y - mC[1];
        oC[2] = qx.z - mC[2]; oC[3] = qx.w - mC[3];
        oN[0] = mN[0]; oN[1] = mN[1]; oN[2] = mN[2]; oN[3] = mN[3];
        oD[0] = mD[0]; oD[1] = mD[1]; oD[2] = mD[2]; oD[3] = mD[3];
        *(f32x4*)(dst +       x * 16 + jq * 4) = oM;
        *(f32x4*)(dst + 256 + x * 16 + jq * 4) = oC;
        *(f32x4*)(dst + 512 + x * 16 + jq * 4) = oN;
        *(f32x4*)(dst + 768 + x * 16 + jq * 4) = oD;
    }
}

// ---------------------------------------------------------------------------
// prefix_k: per-chain affine prefix over 64 chunks, all in registers.
// Lane (x = lane>>2, jq = lane&3) holds W[x][jq*4..+3].
//   Wn = N + M W ;  O = D1 + C1 W  -- both share the 16 shfl gathers of W.
// ---------------------------------------------------------------------------
__global__ __launch_bounds__(64) void prefix_k(
    const float* __restrict__ cfb, bf16* __restrict__ o)
{
    __shared__ float scf[2][1024];
    const int lane = threadIdx.x;
    const int x = lane >> 2, jq = lane & 3;
    const int chain = blockIdx.x;
    const int b = chain >> 4, hh = chain & 15;
    bf16* po = o + (long)b * HID + hh * HDIM + jq * 4;
    const float* cb = cfb + (long)chain * 64 * 1024;

    auto stage = [&](int buf, int c) {
#pragma unroll
        for (int i = 0; i < 4; ++i)
            GLOAD16(cb + (long)c * 1024 + (i * 64 + lane) * 4,
                    &scf[buf][(i * 64 + lane) * 4]);
    };

    float W0r = 0.f, W1r = 0.f, W2r = 0.f, W3r = 0.f;
    stage(0, 0);
    asm volatile("s_waitcnt vmcnt(0)" ::: "memory");
    for (int c = 0; c < 64; ++c) {
        const int buf = c & 1;
        asm volatile("s_waitcnt vmcnt(1)" ::: "memory");
        if (c + 1 < 64) stage(buf ^ 1, c + 1);

        float Mrow[16], Crow[16];
#pragma unroll
        for (int t = 0; t < 16; ++t) {
            Mrow[t] = scf[buf][x * 16 + t];
            Crow[t] = scf[buf][256 + x * 16 + t];
        }
        const float4 N4 = *(const float4*)&scf[buf][512 + x * 16 + jq * 4];
        const float4 D4 = *(const float4*)&scf[buf][768 + x * 16 + jq * 4];
        float Wn0 = N4.x, Wn1 = N4.y, Wn2 = N4.z, Wn3 = N4.w;
        float On0 = D4.x, On1 = D4.y, On2 = D4.z, On3 = D4.w;
#pragma unroll
        for (int t = 0; t < 16; ++t) {
            const float g0 = __shfl(W0r, t * 4 + jq);
            const float g1 = __shfl(W1r, t * 4 + jq);
            const float g2 = __shfl(W2r, t * 4 + jq);
            const float g3 = __shfl(W3r, t * 4 + jq);
            Wn0 = fmaf(Mrow[t], g0, Wn0); Wn1 = fmaf(Mrow[t], g1, Wn1);
            Wn2 = fmaf(Mrow[t], g2, Wn2); Wn3 = fmaf(Mrow[t], g3, Wn3);
            On0 = fmaf(Crow[t], g0, On0); On1 = fmaf(Crow[t], g1, On1);
            On2 = fmaf(Crow[t], g2, On2); On3 = fmaf(Crow[t], g3, On3);
        }
        W0r = Wn0; W1r = Wn1; W2r = Wn2; W3r = Wn3;
        const int sg = c * 16 + x;
        alignas(8) bf16 tb[4];
        tb[0] = __float2bfloat16(On0); tb[1] = __float2bfloat16(On1);
        tb[2] = __float2bfloat16(On2); tb[3] = __float2bfloat16(On3);
        *(ushort4*)((unsigned short*)(po + (long)sg * (B_SZ * HID))) =
            *(const ushort4*)tb;
    }
}

// ---------------------------------------------------------------------------
extern "C" void kernel_launch(void* const* d_in, const int* in_sizes, int n_in,
                              void* d_out, int out_size, void* d_ws, size_t ws_size,
                              hipStream_t stream)
{
    const float* x      = (const float*)d_in[0];
    const int*   fb     = (const int*)  d_in[1];
    const float* fc1_w  = (const float*)d_in[2];
    const float* fc1_b  = (const float*)d_in[3];
    const float* emb    = (const float*)d_in[4];
    const float* proj_w = (const float*)d_in[5];
    const float* proj_b = (const float*)d_in[6];
    const float* ln1_g  = (const float*)d_in[7];
    const float* ln1_b  = (const float*)d_in[8];
    const float* slow_w = (const float*)d_in[9];
    const float* out_w  = (const float*)d_in[10];
    const float* ln2_g  = (const float*)d_in[11];
    const float* ln2_b  = (const float*)d_in[12];
    const float* ff1_w  = (const float*)d_in[13];
    const float* ff1_b  = (const float*)d_in[14];
    const float* ff2_w  = (const float*)d_in[15];
    const float* ff2_b  = (const float*)d_in[16];
    const float* outl_w = (const float*)d_in[17];
    const float* outl_b = (const float*)d_in[18];

    // ---- workspace layout (bf16 weight buffers CONTIGUOUS from fc1b) ----
    char* wp = (char*)d_ws;
    bf16*  h    = (bf16*)wp;                  wp += (size_t)MROWS * HID * 2;   // bf16 residual
    bf16*  abuf = (bf16*)wp;                  wp += (size_t)MROWS * HID * 2;
    bf16*  fc1b = (bf16*)wp;                  wp += (size_t)HID * IN_DIM * 2;
    bf16*  projb= (bf16*)wp;                  wp += (size_t)HID * 288 * 2;
    bf16*  slowb= (bf16*)wp;                  wp += (size_t)NLAYER * 896 * HID * 2;
    bf16*  outwb= (bf16*)wp;                  wp += (size_t)NLAYER * HID * HID * 2;
    bf16*  ff1b = (bf16*)wp;                  wp += (size_t)NLAYER * DFF * HID * 2;
    bf16*  ff2b = (bf16*)wp;                  wp += (size_t)NLAYER * HID * DFF * 2;
    bf16*  outlb= (bf16*)wp;                  wp += (size_t)1664 * HID * 2;

    // ---- d_out scratch, sequentially reused ----
    bf16*  hcat = (bf16*)d_out;               // 18.9MB, dead after proj
    bf16*  qkvb = (bf16*)d_out;               // 58.7MB, dead after coef2
    float* cfb  = (float*)((bf16*)d_out + (size_t)512 * 1024 * QROW); // 128MB coef
    bf16*  hff  = (bf16*)d_out;               // 67.1MB, dead after ff2

    const dim3 blk(256);

    // ---- all weight conversions in one dispatch ----
    cvtall<<<dim3(1024), blk, 0, stream>>>(fc1_w, proj_w, slow_w, out_w,
                                           ff1_w, ff2_w, outl_w, fc1b);

    // fc1 writes directly into hcat (cols 0..255 + fused emb fill 256..287)
    fc1_k<<<dim3(256, 2), blk, 0, stream>>>(x, fc1b, fc1_b, emb, fb, hcat);
    // proj + fused LN1_0: h = hcat@proj^T + b; abuf = LN(h)
    gemm_ln<1><<<dim3(512), blk, 0, stream>>>(hcat, projb, proj_b,
                                              ln1_g, ln1_b, h, abuf, 288);

    for (int l = 0; l < NLAYER; ++l) {
        // qkvb (permuted (b,h,s,56) bf16, sigmoid(beta) fused)
        mgemm<16><<<dim3(256, 7), blk, 0, stream>>>(abuf, slowb + (size_t)l * 896 * HID,
                                                    nullptr, qkvb, 784, HID, HID);
        // per-chunk affine coefficients M/C1/N/D1 (massively parallel)
        coef2_k<<<dim3(8192), blk, 0, stream>>>(qkvb, cfb);
        // register-resident affine prefix -> o
        prefix_k<<<dim3(B_SZ * NHEAD), dim3(64), 0, stream>>>(cfb, abuf);
        // out-GEMM + residual + fused LN2: h += o@out^T; abuf = LN2(h)
        gemm_ln<4><<<dim3(512), blk, 0, stream>>>(abuf, outwb + (size_t)l * HID * HID,
                                                  nullptr, ln2_g + l * HID,
                                                  ln2_b + l * HID, h, abuf, HID);
        // hff = bf16(relu(abuf @ ff1^T + b1))  N=1024 K=256
        mgemm<11><<<dim3(256, 8), blk, 0, stream>>>(abuf, ff1b + (size_t)l * DFF * HID,
                                                    ff1_b + l * DFF, hff, DFF, HID, HID);
        // ff2 + residual + bias; abuf = LN1_{l+1}(h) or plain bf16(h) on last
        if (l + 1 < NLAYER)
            gemm_ln<5><<<dim3(512), blk, 0, stream>>>(hff, ff2b + (size_t)l * HID * DFF,
                                                      ff2_b + l * HID,
                                                      ln1_g + (l + 1) * HID,
                                                      ln1_b + (l + 1) * HID, h, abuf, DFF);
        else
            gemm_ln<13><<<dim3(512), blk, 0, stream>>>(hff, ff2b + (size_t)l * HID * DFF,
                                                       ff2_b + l * HID,
                                                       nullptr, nullptr, h, abuf, DFF);
    }
    // final: out = abuf @ outl_w^T + b  (fp32, N=1623 K=256)
    mgemm<1><<<dim3(256, 13), blk, 0, stream>>>(abuf, outlb, outl_b, d_out,
                                                NCLS, HID, HID);
}